// Round 7
// baseline (1645.018 us; speedup 1.0000x reference)
//
#include <hip/hip_runtime.h>
#include <math.h>

#define DD 48
#define HH 64
#define WW 128
#define VOL (DD*HH*WW)     // 393216 real voxels
#define PW 130             // padded W
#define PROWS (DD*HH)      // 3072 rows
#define PVOL (PROWS*PW)    // 399360 padded voxels
#define PVBYTES (PVOL*64*2) // 51,118,080 bytes per padded bf16 volume
#define NC 64

typedef __attribute__((ext_vector_type(8))) short bf16x8;
typedef __attribute__((ext_vector_type(4))) float f32x4;
typedef __attribute__((ext_vector_type(4))) unsigned int u32x4v;
typedef __attribute__((ext_vector_type(2))) unsigned int u32x2v;

__device__ __forceinline__ float bflo(unsigned int u){
    union { unsigned int i; float f; } x; x.i = u<<16; return x.f; }
__device__ __forceinline__ float bfhi(unsigned int u){
    union { unsigned int i; float f; } x; x.i = u & 0xffff0000u; return x.f; }
__device__ __forceinline__ float bf2f(unsigned short u){
    union { unsigned int i; float f; } x; x.i = ((unsigned int)u)<<16; return x.f; }
__device__ __forceinline__ unsigned short f2bf(float f){
    union { float f; unsigned int i; } x; x.f = f;
    unsigned int i = x.i;
    return (unsigned short)((i + 0x7fffu + ((i>>16)&1u)) >> 16);  // RNE
}

// ================= weight prep =================

// src [co=64][ci=64][k=27] fp32 -> dst [k=27][co=64][ci=64] bf16
__global__ void k_wprep3(const float* __restrict__ src, unsigned short* __restrict__ dst){
    int idx = blockIdx.x*256 + threadIdx.x;
    if (idx >= 27*64*64) return;
    int ci = idx & 63; int t = idx >> 6; int co = t & 63; int k = t >> 6;
    dst[idx] = f2bf(src[(co*64+ci)*27 + k]);
}

__global__ void k_wprep1(const float* __restrict__ src, unsigned short* __restrict__ dst){
    int idx = blockIdx.x*256 + threadIdx.x;
    if (idx >= 4096) return;
    dst[idx] = f2bf(src[idx]);
}

// wc2 [co=64][tap=27] fp32 -> dst [taprow=32][co=64] bf16 (taps >=27 zero)
__global__ void k_wprep2(const float* __restrict__ src, unsigned short* __restrict__ dst){
    int idx = blockIdx.x*256 + threadIdx.x;
    if (idx >= 32*64) return;
    int co = idx & 63; int row = idx >> 6;
    float v = (row < 27) ? src[co*27 + row] : 0.f;
    dst[row*64 + co] = f2bf(v);
}

// M_i = W1_i + W2_i @ W1_i, output bf16 [i][co][ci]
__global__ void k_fuse_res(const float* __restrict__ w1, const float* __restrict__ w2,
                           unsigned short* __restrict__ mt){
    int idx = blockIdx.x*256 + threadIdx.x;
    if (idx >= 5*4096) return;
    int i = idx >> 12; int r = idx & 4095;
    int co = r >> 6; int ci = r & 63;
    const float* W1 = w1 + i*4096;
    const float* W2 = w2 + i*4096;
    float m = W1[co*64+ci];
    for (int k=0;k<64;++k) m += W2[co*64+k]*W1[k*64+ci];
    mt[idx] = f2bf(m);
}

// dst[ci*64+co] = src[co*64+ci]  (fp32, for pool 1x1 convs)
__global__ void k_transpose1(const float* __restrict__ src, float* __restrict__ dst){
    int idx = blockIdx.x*256 + threadIdx.x;
    if (idx >= 4096) return;
    int ci = idx >> 6; int co = idx & 63;
    dst[idx] = src[co*64+ci];
}

// ============ fvl [64][VOL] fp32 -> padded [PVOL][64] bf16 (LDS transpose) ============
__global__ __launch_bounds__(256) void k_tobf16v(const float* __restrict__ src,
                                                 unsigned short* __restrict__ dst){
    __shared__ unsigned short lds[64*66];
    int tid = threadIdx.x;
    long vbase = (long)blockIdx.x*64;           // 64 consecutive real voxels, same (d,h)
    int d = (int)(vbase >> 13);
    int h = (int)((vbase >> 7) & 63);
    int w0 = (int)(vbase & 127);                // 0 or 64
    long pbase = ((long)(d*64+h)*PW + w0 + 1);  // padded voxel index of vbase
    int v = tid & 63;
    int cg = tid >> 6;
#pragma unroll
    for (int k=0;k<16;++k){
        int ci = cg*16 + k;
        lds[v*66 + ci] = f2bf(src[(long)ci*VOL + vbase + v]);
    }
    __syncthreads();
#pragma unroll
    for (int it=0; it<2; ++it){
        int chunk = it*256 + tid;       // 512 chunks = 64v x 8 groups
        int vv = chunk >> 3, gp = chunk & 7;
        const unsigned short* s = lds + vv*66 + gp*8;
        unsigned int w0_ = (unsigned)s[0] | ((unsigned)s[1]<<16);
        unsigned int w1_ = (unsigned)s[2] | ((unsigned)s[3]<<16);
        unsigned int w2_ = (unsigned)s[4] | ((unsigned)s[5]<<16);
        unsigned int w3_ = (unsigned)s[6] | ((unsigned)s[7]<<16);
        u32x4v q = {w0_,w1_,w2_,w3_};
        *(u32x4v*)(dst + (pbase+vv)*64 + gp*8) = q;
    }
}

// ============ MFMA conv3x3x3 on PADDED layout: pure loads, wave-uniform edge skip ============
// in/out padded [PVOL][64] bf16, wt [27][co][ci] bf16
// block: 4 waves = 256 real voxels (2 h-rows); wave: 64co x 64vox (one half w-row)
template<bool AUX, bool RELU>
__global__ __launch_bounds__(256,3) void k_conv3m(
    const unsigned short* __restrict__ in, const unsigned short* __restrict__ wt,
    const unsigned short* __restrict__ aux, const unsigned short* __restrict__ auxw,
    unsigned short* __restrict__ out)
{
    const int lane = threadIdx.x & 63;
    const int wave = threadIdx.x >> 6;
    const int ll = lane & 15;
    const int kg = lane >> 4;
    // XCD-aware swizzle: 1536 blocks, 8 XCDs -> 192 contiguous ids per XCD
    const int bid = blockIdx.x;
    const int wid = ((bid & 7) * 192) + (bid >> 3);
    const int vbr = wid*256;                    // real voxel base of block
    const int d  = vbr >> 13;
    const int h0 = (vbr >> 7) & 63;
    const int my_h  = h0 + (wave >> 1);
    const int my_w0 = (wave & 1) * 64;
    const long pvb = (long)(d*64 + my_h)*PW + my_w0 + 1;   // padded index of wave's voxel 0

    f32x4 acc[4][4];
#pragma unroll
    for (int a=0;a<4;++a)
#pragma unroll
        for (int b=0;b<4;++b) acc[a][b] = (f32x4){0.f,0.f,0.f,0.f};

#pragma unroll
    for (int kd=0; kd<3; ++kd){
#pragma unroll
        for (int kh=0; kh<3; ++kh){
            const int dd = d + kd - 1;
            const int hh = my_h + kh - 1;
            if (((unsigned)dd < 48u) && ((unsigned)hh < 64u)){   // wave-uniform skip
                const long prow = (long)(dd*64 + hh)*PW + my_w0; // w = -1 is +0 in padded
                const unsigned short* wk = wt + (kd*3+kh)*3*4096;
                bf16x8 A[2][4], B[2][4];
                // group g in [0,6): kw=g>>1, khalf=g&1
                auto ldg = [&](int g, bf16x8* Ad, bf16x8* Bd){
                    const int kw = g >> 1; const int ko = (g & 1)*32 + kg*8;
                    const unsigned short* wkk = wk + kw*4096 + ko;
#pragma unroll
                    for (int t=0;t<4;++t) Ad[t] = *(const bf16x8*)(wkk + (t*16+ll)*64);
#pragma unroll
                    for (int vt=0; vt<4; ++vt)
                        Bd[vt] = *(const bf16x8*)(in + (prow + kw + vt*16 + ll)*64 + ko);
                };
                ldg(0, A[0], B[0]);
#pragma unroll
                for (int g=0; g<6; ++g){
                    const int cb = g & 1, nb = cb ^ 1;
                    if (g < 5) ldg(g+1, A[nb], B[nb]);    // pure-load prefetch
#pragma unroll
                    for (int vt=0; vt<4; ++vt)
#pragma unroll
                        for (int t=0; t<4; ++t)
                            acc[t][vt] = __builtin_amdgcn_mfma_f32_16x16x32_bf16(A[cb][t], B[cb][vt], acc[t][vt], 0,0,0);
                }
            }
        }
    }

    if (AUX){
        bf16x8 Aa[2][4], Ba[2][4];
#pragma unroll
        for (int half=0; half<2; ++half){
            const int ko = half*32 + kg*8;
#pragma unroll
            for (int t=0;t<4;++t)
                Aa[half][t] = *(const bf16x8*)(auxw + (t*16+ll)*64 + ko);
#pragma unroll
            for (int vt=0; vt<4; ++vt)
                Ba[half][vt] = *(const bf16x8*)(aux + (pvb + vt*16 + ll)*64 + ko);
        }
#pragma unroll
        for (int half=0; half<2; ++half)
#pragma unroll
            for (int vt=0; vt<4; ++vt)
#pragma unroll
                for (int t=0;t<4;++t)
                    acc[t][vt] = __builtin_amdgcn_mfma_f32_16x16x32_bf16(Aa[half][t], Ba[half][vt], acc[t][vt], 0,0,0);
    }

#pragma unroll
    for (int vt=0; vt<4; ++vt){
        unsigned short* op = out + (pvb + vt*16 + ll)*64 + kg*4;
#pragma unroll
        for (int t=0;t<4;++t){
            float r0 = acc[t][vt][0], r1 = acc[t][vt][1], r2 = acc[t][vt][2], r3 = acc[t][vt][3];
            if (RELU){ r0=fmaxf(r0,0.f); r1=fmaxf(r1,0.f); r2=fmaxf(r2,0.f); r3=fmaxf(r3,0.f); }
            unsigned int lo = (unsigned)f2bf(r0) | ((unsigned)f2bf(r1)<<16);
            unsigned int hi = (unsigned)f2bf(r2) | ((unsigned)f2bf(r3)<<16);
            u32x2v q = {lo, hi};
            *(u32x2v*)(op + t*16) = q;
        }
    }
}

// ============ MFMA 1x1 conv on PADDED linear space (halo: relu(M*0)=0 preserved) ============
__global__ __launch_bounds__(256,3) void k_conv1m(const unsigned short* __restrict__ in,
        const unsigned short* __restrict__ wt, unsigned short* __restrict__ out){
    const int lane = threadIdx.x & 63;
    const int wave = threadIdx.x >> 6;
    const int ll = lane & 15;
    const int kg = lane >> 4;
    const long vb = (long)blockIdx.x*256 + wave*64;

    bf16x8 A[2][4], B[2][4];
#pragma unroll
    for (int half=0; half<2; ++half){
        const int ko = half*32 + kg*8;
#pragma unroll
        for (int t=0;t<4;++t)
            A[half][t] = *(const bf16x8*)(wt + (t*16+ll)*64 + ko);
#pragma unroll
        for (int vt=0; vt<4; ++vt)
            B[half][vt] = *(const bf16x8*)(in + (vb+vt*16+ll)*64 + ko);
    }

    f32x4 acc[4][4];
#pragma unroll
    for (int a=0;a<4;++a)
#pragma unroll
        for (int b=0;b<4;++b) acc[a][b] = (f32x4){0.f,0.f,0.f,0.f};

#pragma unroll
    for (int half=0; half<2; ++half)
#pragma unroll
        for (int vt=0; vt<4; ++vt)
#pragma unroll
            for (int t=0;t<4;++t)
                acc[t][vt] = __builtin_amdgcn_mfma_f32_16x16x32_bf16(A[half][t], B[half][vt], acc[t][vt], 0,0,0);

#pragma unroll
    for (int vt=0; vt<4; ++vt){
        unsigned short* op = out + (vb+vt*16+ll)*64 + kg*4;
#pragma unroll
        for (int t=0;t<4;++t){
            float r0 = fmaxf(acc[t][vt][0],0.f), r1 = fmaxf(acc[t][vt][1],0.f);
            float r2 = fmaxf(acc[t][vt][2],0.f), r3 = fmaxf(acc[t][vt][3],0.f);
            unsigned int lo = (unsigned)f2bf(r0) | ((unsigned)f2bf(r1)<<16);
            unsigned int hi = (unsigned)f2bf(r2) | ((unsigned)f2bf(r3)<<16);
            u32x2v q = {lo, hi};
            *(u32x2v*)(op + t*16) = q;
        }
    }
}

// ============ head stage 1: t[tap][pv] = sum_co in[pv][co]*wc2[co][tap]  (padded space) ============
__global__ __launch_bounds__(256) void k_headt(const unsigned short* __restrict__ in,
        const unsigned short* __restrict__ wt2, float* __restrict__ t){
    const int lane = threadIdx.x & 63;
    const int wave = threadIdx.x >> 6;
    const int ll = lane & 15;
    const int kg = lane >> 4;
    const long vb = (long)blockIdx.x*256 + wave*64;

    f32x4 acc[2][4];
#pragma unroll
    for (int a=0;a<2;++a)
#pragma unroll
        for (int b=0;b<4;++b) acc[a][b] = (f32x4){0.f,0.f,0.f,0.f};

#pragma unroll
    for (int khalf=0; khalf<2; ++khalf){
        const int ko = khalf*32 + kg*8;
        bf16x8 afr[2];
#pragma unroll
        for (int tl=0;tl<2;++tl)
            afr[tl] = *(const bf16x8*)(wt2 + (tl*16+ll)*64 + ko);
#pragma unroll
        for (int vt=0; vt<4; ++vt){
            bf16x8 bfr = *(const bf16x8*)(in + (vb+vt*16+ll)*64 + ko);
#pragma unroll
            for (int tl=0;tl<2;++tl)
                acc[tl][vt] = __builtin_amdgcn_mfma_f32_16x16x32_bf16(afr[tl], bfr, acc[tl][vt], 0,0,0);
        }
    }
#pragma unroll
    for (int vt=0; vt<4; ++vt){
        long vx = vb + vt*16 + ll;
#pragma unroll
        for (int tl=0;tl<2;++tl){
#pragma unroll
            for (int r=0;r<4;++r){
                int tap = tl*16 + kg*4 + r;
                if (tap < 27) t[(long)tap*PVOL + vx] = acc[tl][vt][r];
            }
        }
    }
}

// ============ head stage 2: out[v] = bias + sum_tap t[tap][p + dv_p(tap)] ============
__global__ __launch_bounds__(256) void k_heads(const float* __restrict__ t,
        const float* __restrict__ bias, float* __restrict__ out){
    int v = blockIdx.x*256 + threadIdx.x;
    int ww = v & 127; int h = (v>>7)&63; int d = v>>13;
    long p = (long)(d*64+h)*PW + ww + 1;
    float s = bias[0];
#pragma unroll
    for (int kd=0;kd<3;++kd){
#pragma unroll
      for (int kh=0;kh<3;++kh){
#pragma unroll
        for (int kw=0;kw<3;++kw){
            const int tap = (kd*3+kh)*3+kw;
            const long dvp = (long)((kd-1)*64 + (kh-1))*PW + (kw-1);
            bool ok = ((unsigned)(d+kd-1)<48u) && ((unsigned)(h+kh-1)<64u);  // w safe via pad
            long va = ok ? (p + dvp) : p;
            float x = t[(long)tap*PVOL + va];
            s += ok ? x : 0.f;
        }
      }
    }
    out[v] = s;
}

// ============ global pool partials over real voxels: 384 blocks x 1024 vox ============
__global__ __launch_bounds__(256) void k_gpool(const unsigned short* __restrict__ in,
                                               float* __restrict__ part){
    __shared__ float sm[32][64];
    int cg = threadIdx.x & 7;
    int r  = threadIdx.x >> 3;
    long vb = (long)blockIdx.x*1024;          // 8 h-rows, same d
    int d  = (int)(vb >> 13);
    int h0 = (int)((vb >> 7) & 63);
    float a[8];
#pragma unroll
    for (int j=0;j<8;++j) a[j]=0.f;
    for (int v = r; v < 1024; v += 32){
        int h = h0 + (v >> 7); int w = v & 127;
        long p = (long)(d*64+h)*PW + w + 1;
        u32x4v q = *(const u32x4v*)(in + p*64 + cg*8);
#pragma unroll
        for (int e=0;e<4;++e){
            a[e*2]   += bflo(q[e]);
            a[e*2+1] += bfhi(q[e]);
        }
    }
#pragma unroll
    for (int j=0;j<8;++j) sm[r][cg*8+j] = a[j];
    __syncthreads();
    if (threadIdx.x < 64){
        float s=0.f;
        for (int rr=0;rr<32;++rr) s += sm[rr][threadIdx.x];
        part[blockIdx.x*64 + threadIdx.x] = s;
    }
}

__global__ void k_gfin(const float* __restrict__ part, const float* __restrict__ wp0,
                       float* __restrict__ gc){
    __shared__ float sg[64];
    int t = threadIdx.x;
    if (t < 64){
        float s=0.f;
        for (int b=0;b<384;++b) s += part[b*64 + t];
        sg[t] = s * (1.0f/(float)VOL);
    }
    __syncthreads();
    if (t < 64){
        float s=0.f;
        for (int ci=0;ci<64;++ci) s += wp0[t*64+ci]*sg[ci];
        gc[t] = s;
    }
}

// ============ avg pool (VALID, stride=ksize), padded bf16 in, fp32 [c][cells] out ============
__global__ void k_avgpool(const unsigned short* __restrict__ in, float* __restrict__ out,
                          int od,int oh,int ow,int kd,int kh,int kw){
    int ovol = od*oh*ow;
    int idx = blockIdx.x*256 + threadIdx.x;
    if (idx >= 64*ovol) return;
    int c = idx & 63; int cell = idx >> 6;
    int z = cell/(oh*ow); int rem = cell - z*(oh*ow); int y = rem/ow; int x = rem - y*ow;
    float s = 0.f;
    for (int a=0;a<kd;++a)
        for (int b=0;b<kh;++b)
            for (int e=0;e<kw;++e){
                long p = (long)((z*kd+a)*64 + (y*kh+b))*PW + (x*kw+e) + 1;
                s += bf2f(in[p*64 + c]);
            }
    out[c*ovol + cell] = s / (float)(kd*kh*kw);
}

// ============ 1x1 conv fp32 on pooled grids; wt [ci][co], OUT voxel-major [cell][64] ============
__global__ void k_conv1(const float* __restrict__ in, const float* __restrict__ wt,
                        float* __restrict__ out, int vol){
    int v = blockIdx.x*256 + threadIdx.x;
    if (v >= vol) return;
    float acc[64];
#pragma unroll
    for (int i=0;i<64;++i) acc[i]=0.f;
    for (int ci=0; ci<64; ++ci){
        float xv = in[ci*vol + v];
        const float* wr = wt + ci*64;
#pragma unroll
        for (int co=0; co<64; ++co) acc[co] = fmaf(wr[co], xv, acc[co]);
    }
    float* op = out + (long)v*64;
#pragma unroll
    for (int q=0;q<16;++q){
        f32x4 t = {acc[q*4], acc[q*4+1], acc[q*4+2], acc[q*4+3]};
        *(f32x4*)(op + q*4) = t;
    }
}

// ============ trilinear gather ============
__device__ __forceinline__ void tri_setup(int d,int h,int w,int gd,int gh,int gw,
                                          int* o, float* wt){
    float fz = (d+0.5f)*((float)gd/(float)DD) - 0.5f;
    float fy = (h+0.5f)*((float)gh/(float)HH) - 0.5f;
    float fx = (w+0.5f)*((float)gw/(float)WW) - 0.5f;
    float z0f = floorf(fz), y0f = floorf(fy), x0f = floorf(fx);
    float tz = fz - z0f, ty = fy - y0f, tx = fx - x0f;
    int z0 = (int)z0f, y0 = (int)y0f, x0 = (int)x0f;
    int z1 = z0+1, y1 = y0+1, x1 = x0+1;
    z0 = min(max(z0,0),gd-1); z1 = min(max(z1,0),gd-1);
    y0 = min(max(y0,0),gh-1); y1 = min(max(y1,0),gh-1);
    x0 = min(max(x0,0),gw-1); x1 = min(max(x1,0),gw-1);
    o[0] = (z0*gh+y0)*gw+x0; wt[0] = (1-tz)*(1-ty)*(1-tx);
    o[1] = (z0*gh+y0)*gw+x1; wt[1] = (1-tz)*(1-ty)*tx;
    o[2] = (z0*gh+y1)*gw+x0; wt[2] = (1-tz)*ty*(1-tx);
    o[3] = (z0*gh+y1)*gw+x1; wt[3] = (1-tz)*ty*tx;
    o[4] = (z1*gh+y0)*gw+x0; wt[4] = tz*(1-ty)*(1-tx);
    o[5] = (z1*gh+y0)*gw+x1; wt[5] = tz*(1-ty)*tx;
    o[6] = (z1*gh+y1)*gw+x0; wt[6] = tz*ty*(1-tx);
    o[7] = (z1*gh+y1)*gw+x1; wt[7] = tz*ty*tx;
}

// out = relu((xc + 0.25*(gc + up(p2)+up(p3)+up(p4)))/2)
// xc padded bf16; writes xout fp32 [64][VOL] (real) and xv padded bf16
__global__ __launch_bounds__(256) void k_combine(
        const unsigned short* __restrict__ xc, const float* __restrict__ gc,
        const float* __restrict__ p2, const float* __restrict__ p3,
        const float* __restrict__ p4, float* __restrict__ xout,
        unsigned short* __restrict__ xv){
    int tid = threadIdx.x;
    long v = (long)blockIdx.x*256 + tid;
    int w = v & 127; int h = (v>>7)&63; int d = v>>13;
    long p = (long)(d*64+h)*PW + w + 1;
    int o2[8], o3[8], o4[8];
    float w2_[8], w3_[8], w4_[8];
    tri_setup(d,h,w, 8,8,8,    o2, w2_);
    tri_setup(d,h,w, 16,16,16, o3, w3_);
    tri_setup(d,h,w, 24,32,25, o4, w4_);
#pragma unroll
    for (int half=0; half<2; ++half){
        float res[32];
#pragma unroll
        for (int j=0;j<32;++j) res[j] = gc[half*32+j];
#pragma unroll
        for (int t=0;t<8;++t){
            const float* b2 = p2 + (long)o2[t]*64 + half*32;
#pragma unroll
            for (int q=0;q<8;++q){
                f32x4 x4 = *(const f32x4*)(b2 + q*4);
                res[q*4+0] = fmaf(w2_[t], x4[0], res[q*4+0]);
                res[q*4+1] = fmaf(w2_[t], x4[1], res[q*4+1]);
                res[q*4+2] = fmaf(w2_[t], x4[2], res[q*4+2]);
                res[q*4+3] = fmaf(w2_[t], x4[3], res[q*4+3]);
            }
        }
#pragma unroll
        for (int t=0;t<8;++t){
            const float* b3 = p3 + (long)o3[t]*64 + half*32;
#pragma unroll
            for (int q=0;q<8;++q){
                f32x4 x4 = *(const f32x4*)(b3 + q*4);
                res[q*4+0] = fmaf(w3_[t], x4[0], res[q*4+0]);
                res[q*4+1] = fmaf(w3_[t], x4[1], res[q*4+1]);
                res[q*4+2] = fmaf(w3_[t], x4[2], res[q*4+2]);
                res[q*4+3] = fmaf(w3_[t], x4[3], res[q*4+3]);
            }
        }
#pragma unroll
        for (int t=0;t<8;++t){
            const float* b4 = p4 + (long)o4[t]*64 + half*32;
#pragma unroll
            for (int q=0;q<8;++q){
                f32x4 x4 = *(const f32x4*)(b4 + q*4);
                res[q*4+0] = fmaf(w4_[t], x4[0], res[q*4+0]);
                res[q*4+1] = fmaf(w4_[t], x4[1], res[q*4+1]);
                res[q*4+2] = fmaf(w4_[t], x4[2], res[q*4+2]);
                res[q*4+3] = fmaf(w4_[t], x4[3], res[q*4+3]);
            }
        }
        const u32x4v* xq = (const u32x4v*)(xc + p*64 + half*32);
#pragma unroll
        for (int q=0;q<4;++q){
            u32x4v qv = xq[q];
            unsigned int pk[4];
#pragma unroll
            for (int e=0;e<4;++e){
                int j = q*8 + e*2;
                float r0 = fmaxf((bflo(qv[e]) + 0.25f*res[j])*0.5f, 0.f);
                float r1 = fmaxf((bfhi(qv[e]) + 0.25f*res[j+1])*0.5f, 0.f);
                xout[(long)(half*32+j)*VOL + v]   = r0;
                xout[(long)(half*32+j+1)*VOL + v] = r1;
                pk[e] = (unsigned)f2bf(r0) | ((unsigned)f2bf(r1)<<16);
            }
            u32x4v pq = {pk[0],pk[1],pk[2],pk[3]};
            *(u32x4v*)(xv + p*64 + half*32 + q*8) = pq;
        }
    }
}

// ================= workspace layout (bytes) =================
constexpr long OFF_PV0 = 0;                        // padded bf16 vol (51,118,080)
constexpr long OFF_PV1 = 51118080;                 // padded bf16 vol
constexpr long OFF_WA1 = 102236160;                // 221,184
constexpr long OFF_WA2 = OFF_WA1 + 221184;
constexpr long OFF_WC1 = OFF_WA2 + 221184;
constexpr long OFF_NIN = OFF_WC1 + 221184;         // 8,192
constexpr long OFF_MT  = OFF_NIN + 8192;           // 40,960
constexpr long OFF_WT2 = OFF_MT + 40960;           // 4,096
constexpr long OFF_WPT = OFF_WT2 + 4096;           // 49,152
constexpr long OFF_GP  = OFF_WPT + 49152;          // 98,304
constexpr long OFF_GC  = OFF_GP + 98304;           // 256
constexpr long OFF_P2  = OFF_GC + 256;             // 131,072
constexpr long OFF_P2C = OFF_P2 + 131072;
constexpr long OFF_P3  = OFF_P2C + 131072;         // 1,048,576
constexpr long OFF_P3C = OFF_P3 + 1048576;
constexpr long OFF_P4  = OFF_P3C + 1048576;        // 4,915,200
constexpr long OFF_P4C = OFF_P4 + 4915200;
// end = 115,290,368 bytes (~115.3 MB)

extern "C" void kernel_launch(void* const* d_in, const int* in_sizes, int n_in,
                              void* d_out, int out_size, void* d_ws, size_t ws_size,
                              hipStream_t stream) {
    const float* fvl  = (const float*)d_in[0];
    const float* w_a1 = (const float*)d_in[1];
    const float* w_a2 = (const float*)d_in[2];
    const float* wnin = (const float*)d_in[3];
    const float* w1s  = (const float*)d_in[4];
    const float* w2s  = (const float*)d_in[5];
    const float* wp0  = (const float*)d_in[6];
    const float* wp1  = (const float*)d_in[7];
    const float* wp2  = (const float*)d_in[8];
    const float* wp3  = (const float*)d_in[9];
    const float* wc1  = (const float*)d_in[10];
    const float* wc2  = (const float*)d_in[11];
    const float* bc   = (const float*)d_in[12];

    char* ws = (char*)d_ws;
    unsigned short* PV0  = (unsigned short*)(ws + OFF_PV0);
    unsigned short* PV1  = (unsigned short*)(ws + OFF_PV1);
    unsigned short* wa1t = (unsigned short*)(ws + OFF_WA1);
    unsigned short* wa2t = (unsigned short*)(ws + OFF_WA2);
    unsigned short* wc1t = (unsigned short*)(ws + OFF_WC1);
    unsigned short* nint = (unsigned short*)(ws + OFF_NIN);
    unsigned short* Mt   = (unsigned short*)(ws + OFF_MT);
    unsigned short* wt2  = (unsigned short*)(ws + OFF_WT2);
    float* wpt  = (float*)(ws + OFF_WPT);
    float* gp   = (float*)(ws + OFF_GP);
    float* gc   = (float*)(ws + OFF_GC);
    float* p2   = (float*)(ws + OFF_P2);
    float* p2c  = (float*)(ws + OFF_P2C);
    float* p3   = (float*)(ws + OFF_P3);
    float* p3c  = (float*)(ws + OFF_P3C);
    float* p4   = (float*)(ws + OFF_P4);
    float* p4c  = (float*)(ws + OFF_P4C);

    float* Xout = (float*)d_out;                       // [64][VOL] fp32 (final x)
    float* Cout = Xout + (long)NC*VOL;                 // [VOL] fp32 (final c)
    float* Tbuf = (float*)(ws + OFF_PV0);              // head t fp32 [27][PVOL] aliases PV0 (43.1MB<=51.1MB)

    const int GBR = VOL/256;     // 1536 blocks (real-voxel kernels)
    const int GBP = PVOL/256;    // 1560 blocks (padded-linear kernels)

    // --- zero padded volumes (halo invariant; deterministic each call) ---
    hipMemsetAsync(PV0, 0, PVBYTES, stream);
    hipMemsetAsync(PV1, 0, PVBYTES, stream);

    // --- prep ---
    k_wprep3<<<(27*64*64+255)/256,256,0,stream>>>(w_a1, wa1t);
    k_wprep3<<<(27*64*64+255)/256,256,0,stream>>>(w_a2, wa2t);
    k_wprep3<<<(27*64*64+255)/256,256,0,stream>>>(wc1, wc1t);
    k_wprep1<<<16,256,0,stream>>>(wnin, nint);
    k_wprep2<<<8,256,0,stream>>>(wc2, wt2);
    k_fuse_res<<<80,256,0,stream>>>(w1s, w2s, Mt);
    k_transpose1<<<16,256,0,stream>>>(wp1, wpt + 0*4096);
    k_transpose1<<<16,256,0,stream>>>(wp2, wpt + 1*4096);
    k_transpose1<<<16,256,0,stream>>>(wp3, wpt + 2*4096);
    k_tobf16v<<<VOL/64,256,0,stream>>>(fvl, PV0);

    // --- stage A: PV1 = conv3(PV0, wa1) ---
    k_conv3m<false,false><<<GBR,256,0,stream>>>(PV0, wa1t, nullptr, nullptr, PV1);
    // --- stage B: PV0 = conv3(PV1, wa2) + conv1(PV0, nin)  (aux in-place per-voxel: safe) ---
    k_conv3m<true,false><<<GBR,256,0,stream>>>(PV1, wa2t, PV0, nint, PV0);

    // --- stage C: 5x fused residual 1x1 (relu), padded-linear, ping-pong; ends in PV1 ---
    unsigned short* cur = PV0; unsigned short* nxt = PV1;
    for (int i=0;i<5;++i){
        k_conv1m<<<GBP,256,0,stream>>>(cur, Mt + i*4096, nxt);
        unsigned short* t = cur; cur = nxt; nxt = t;
    }
    // cur == PV1

    // --- stage D: pool pyramid (reads padded chain output) ---
    k_gpool<<<384,256,0,stream>>>(cur, gp);
    k_gfin<<<1,64,0,stream>>>(gp, wp0, gc);

    k_avgpool<<<(64*512+255)/256,256,0,stream>>>(cur, p2, 8,8,8,   6,8,16);
    k_conv1<<<2,256,0,stream>>>(p2, wpt + 0*4096, p2c, 512);

    k_avgpool<<<(64*4096+255)/256,256,0,stream>>>(cur, p3, 16,16,16, 3,4,8);
    k_conv1<<<16,256,0,stream>>>(p3, wpt + 1*4096, p3c, 4096);

    k_avgpool<<<(64*19200+255)/256,256,0,stream>>>(cur, p4, 24,32,25, 2,2,5);
    k_conv1<<<75,256,0,stream>>>(p4, wpt + 2*4096, p4c, 19200);

    // --- combine: Xout (fp32 real, final) + padded bf16 x into PV0 ---
    k_combine<<<GBR,256,0,stream>>>(cur, gc, p2c, p3c, p4c, Xout, PV0);

    // --- head: PV1 = relu(conv3(PV0, wc1)); t = PV1 @ wc2-taps (padded); Cout = gather-sum + bc ---
    k_conv3m<false,true><<<GBR,256,0,stream>>>(PV0, wc1t, nullptr, nullptr, PV1);
    k_headt<<<GBP,256,0,stream>>>(PV1, wt2, Tbuf);   // PV0 region free now
    k_heads<<<GBR,256,0,stream>>>(Tbuf, bc, Cout);
}

// Round 8
// 989.986 us; speedup vs baseline: 1.6617x; 1.6617x over previous
//
#include <hip/hip_runtime.h>
#include <math.h>

#define DD 48
#define HH 64
#define WW 128
#define VOL (DD*HH*WW)     // 393216 real voxels
#define PW 130             // padded W
#define PROWS (DD*HH)      // 3072 rows
#define PVOL (PROWS*PW)    // 399360 padded voxels
#define PVBYTES ((long)PVOL*64*2) // 51,118,080 bytes per padded bf16 volume
#define GUARD 16640L       // one padded row (130 vox * 128 B) guard each side
#define NC 64

typedef __attribute__((ext_vector_type(8))) short bf16x8;
typedef __attribute__((ext_vector_type(4))) float f32x4;
typedef __attribute__((ext_vector_type(4))) unsigned int u32x4v;
typedef __attribute__((ext_vector_type(2))) unsigned int u32x2v;

__device__ __forceinline__ float bflo(unsigned int u){
    union { unsigned int i; float f; } x; x.i = u<<16; return x.f; }
__device__ __forceinline__ float bfhi(unsigned int u){
    union { unsigned int i; float f; } x; x.i = u & 0xffff0000u; return x.f; }
__device__ __forceinline__ float bf2f(unsigned short u){
    union { unsigned int i; float f; } x; x.i = ((unsigned int)u)<<16; return x.f; }
__device__ __forceinline__ unsigned short f2bf(float f){
    union { float f; unsigned int i; } x; x.f = f;
    unsigned int i = x.i;
    return (unsigned short)((i + 0x7fffu + ((i>>16)&1u)) >> 16);  // RNE
}

// async global->LDS, 16B per lane, no VGPR destination (cannot be re-serialized)
__device__ __forceinline__ void gload16(const void* g, void* l){
    __builtin_amdgcn_global_load_lds(
        (const __attribute__((address_space(1))) void*)g,
        (__attribute__((address_space(3))) void*)l, 16, 0, 0);
}

// ================= weight prep =================

// src [co=64][ci=64][k=27] fp32 -> dst [k=27][co=64][ci=64] bf16
__global__ void k_wprep3(const float* __restrict__ src, unsigned short* __restrict__ dst){
    int idx = blockIdx.x*256 + threadIdx.x;
    if (idx >= 27*64*64) return;
    int ci = idx & 63; int t = idx >> 6; int co = t & 63; int k = t >> 6;
    dst[idx] = f2bf(src[(co*64+ci)*27 + k]);
}

__global__ void k_wprep1(const float* __restrict__ src, unsigned short* __restrict__ dst){
    int idx = blockIdx.x*256 + threadIdx.x;
    if (idx >= 4096) return;
    dst[idx] = f2bf(src[idx]);
}

// wc2 [co=64][tap=27] fp32 -> dst [taprow=32][co=64] bf16 (taps >=27 zero)
__global__ void k_wprep2(const float* __restrict__ src, unsigned short* __restrict__ dst){
    int idx = blockIdx.x*256 + threadIdx.x;
    if (idx >= 32*64) return;
    int co = idx & 63; int row = idx >> 6;
    float v = (row < 27) ? src[co*27 + row] : 0.f;
    dst[row*64 + co] = f2bf(v);
}

// M_i = W1_i + W2_i @ W1_i, output bf16 [i][co][ci]
__global__ void k_fuse_res(const float* __restrict__ w1, const float* __restrict__ w2,
                           unsigned short* __restrict__ mt){
    int idx = blockIdx.x*256 + threadIdx.x;
    if (idx >= 5*4096) return;
    int i = idx >> 12; int r = idx & 4095;
    int co = r >> 6; int ci = r & 63;
    const float* W1 = w1 + i*4096;
    const float* W2 = w2 + i*4096;
    float m = W1[co*64+ci];
    for (int k=0;k<64;++k) m += W2[co*64+k]*W1[k*64+ci];
    mt[idx] = f2bf(m);
}

// dst[ci*64+co] = src[co*64+ci]  (fp32, for pool 1x1 convs)
__global__ void k_transpose1(const float* __restrict__ src, float* __restrict__ dst){
    int idx = blockIdx.x*256 + threadIdx.x;
    if (idx >= 4096) return;
    int ci = idx >> 6; int co = idx & 63;
    dst[idx] = src[co*64+ci];
}

// ============ fvl [64][VOL] fp32 -> padded [PVOL][64] bf16 (LDS transpose) ============
__global__ __launch_bounds__(256) void k_tobf16v(const float* __restrict__ src,
                                                 unsigned short* __restrict__ dst){
    __shared__ unsigned short lds[64*66];
    int tid = threadIdx.x;
    long vbase = (long)blockIdx.x*64;           // 64 consecutive real voxels, same (d,h)
    int d = (int)(vbase >> 13);
    int h = (int)((vbase >> 7) & 63);
    int w0 = (int)(vbase & 127);                // 0 or 64
    long pbase = ((long)(d*64+h)*PW + w0 + 1);  // padded voxel index of vbase
    int v = tid & 63;
    int cg = tid >> 6;
#pragma unroll
    for (int k=0;k<16;++k){
        int ci = cg*16 + k;
        lds[v*66 + ci] = f2bf(src[(long)ci*VOL + vbase + v]);
    }
    __syncthreads();
#pragma unroll
    for (int it=0; it<2; ++it){
        int chunk = it*256 + tid;       // 512 chunks = 64v x 8 groups
        int vv = chunk >> 3, gp = chunk & 7;
        const unsigned short* s = lds + vv*66 + gp*8;
        unsigned int w0_ = (unsigned)s[0] | ((unsigned)s[1]<<16);
        unsigned int w1_ = (unsigned)s[2] | ((unsigned)s[3]<<16);
        unsigned int w2_ = (unsigned)s[4] | ((unsigned)s[5]<<16);
        unsigned int w3_ = (unsigned)s[6] | ((unsigned)s[7]<<16);
        u32x4v q = {w0_,w1_,w2_,w3_};
        *(u32x4v*)(dst + (pbase+vv)*64 + gp*8) = q;
    }
}

// ============ MFMA conv3x3x3: LDS-staged via global_load_lds ============
// in/out padded [PVOL][64] bf16 (with GUARD bytes before/after), wt [27][co][ci] bf16
// block: 4 waves = 256 real voxels (2 h-rows); wave: 64co x 64vox (one half w-row)
// Per (kd,khalf) stage: A-tile 36,864 B (9 taps x 64co x 32ci) + B-tile 33,280 B
// (4 halo rows x 130 vox x 32ci). XOR swizzle q^=((q>>7)&3)<<4 on source+read.
template<bool AUX, bool RELU>
__global__ __launch_bounds__(256,2) void k_conv3m(
    const unsigned short* __restrict__ in, const unsigned short* __restrict__ wt,
    const unsigned short* __restrict__ aux, const unsigned short* __restrict__ auxw,
    unsigned short* __restrict__ out)
{
    __shared__ __align__(16) char sA[36864];
    __shared__ __align__(16) char sB[33280];

    const int tid  = threadIdx.x;
    const int lane = tid & 63;
    const int wave = tid >> 6;
    const int ll = lane & 15;
    const int kg = lane >> 4;
    // XCD-aware swizzle: 1536 blocks, 8 XCDs -> 192 contiguous ids per XCD
    const int bid = blockIdx.x;
    const int wid = ((bid & 7) * 192) + (bid >> 3);
    const int vbr = wid*256;
    const int d  = vbr >> 13;
    const int h0 = (vbr >> 7) & 63;
    const int my_h  = h0 + (wave >> 1);
    const int my_w0 = (wave & 1) * 64;
    const long pvb = (long)(d*64 + my_h)*PW + my_w0 + 1;

    const char* inb = (const char*)in;   // padded volume base (pvox 0)
    const char* wtb = (const char*)wt;

    f32x4 acc[4][4];
#pragma unroll
    for (int a=0;a<4;++a)
#pragma unroll
        for (int b=0;b<4;++b) acc[a][b] = (f32x4){0.f,0.f,0.f,0.f};

#pragma unroll
    for (int kd=0; kd<3; ++kd){
        const int dd = d + kd - 1;
        if ((unsigned)dd >= 48u) continue;                 // block-uniform skip
        const long rowstart = ((long)(dd*64 + h0 - 1)) * 130;  // pvox; may hit guard
#pragma unroll
        for (int khalf=0; khalf<2; ++khalf){
            __syncthreads();   // previous compute done before overwrite
            // --- stage A: 9 rounds x 4096 B ---
#pragma unroll
            for (int rnd=0; rnd<9; ++rnd){
                int j = rnd*4096 + tid*16;
                int q = j ^ (((j>>7)&3)<<4);
                const char* src = wtb + (long)(kd*9 + (q>>12))*8192
                                      + (long)((q>>6)&63)*128 + khalf*64 + (q&63);
                gload16(src, sA + j);
            }
            // --- stage B: 8 full rounds + 1 half round ---
#pragma unroll
            for (int rnd=0; rnd<8; ++rnd){
                int j = rnd*4096 + tid*16;
                int q = j ^ (((j>>7)&3)<<4);
                const char* src = inb + (rowstart + (q>>6))*128 + khalf*64 + (q&63);
                gload16(src, sB + j);
            }
            if (tid < 32){
                int j = 32768 + tid*16;
                int q = j ^ (((j>>7)&3)<<4);
                const char* src = inb + (rowstart + (q>>6))*128 + khalf*64 + (q&63);
                gload16(src, sB + j);
            }
            __syncthreads();   // drains vmcnt -> all staged data visible
            // --- compute 27 (kh,kw) groups from LDS ---
#pragma unroll
            for (int kh=0; kh<3; ++kh){
                const int hh = my_h + kh - 1;
                if ((unsigned)hh >= 64u) continue;          // wave-uniform skip
                const int rr = (wave>>1) + kh;              // LDS row 0..3
#pragma unroll
                for (int kw=0; kw<3; ++kw){
                    const int tap_rel = kh*3 + kw;
                    bf16x8 Af[4], Bf[4];
#pragma unroll
                    for (int t=0;t<4;++t){
                        int qa = tap_rel*4096 + (t*16+ll)*64 + kg*16;
                        Af[t] = *(const bf16x8*)(sA + (qa ^ (((qa>>7)&3)<<4)));
                    }
#pragma unroll
                    for (int vt=0; vt<4; ++vt){
                        int vrel = rr*130 + my_w0 + vt*16 + ll + kw;
                        int qb = vrel*64 + kg*16;
                        Bf[vt] = *(const bf16x8*)(sB + (qb ^ (((qb>>7)&3)<<4)));
                    }
#pragma unroll
                    for (int vt=0; vt<4; ++vt)
#pragma unroll
                        for (int t=0; t<4; ++t)
                            acc[t][vt] = __builtin_amdgcn_mfma_f32_16x16x32_bf16(Af[t], Bf[vt], acc[t][vt], 0,0,0);
                }
            }
        }
    }

    if (AUX){
        bf16x8 Aa[2][4], Ba[2][4];
#pragma unroll
        for (int half=0; half<2; ++half){
            const int ko = half*32 + kg*8;
#pragma unroll
            for (int t=0;t<4;++t)
                Aa[half][t] = *(const bf16x8*)(auxw + (t*16+ll)*64 + ko);
#pragma unroll
            for (int vt=0; vt<4; ++vt)
                Ba[half][vt] = *(const bf16x8*)(aux + (pvb + vt*16 + ll)*64 + ko);
        }
#pragma unroll
        for (int half=0; half<2; ++half)
#pragma unroll
            for (int vt=0; vt<4; ++vt)
#pragma unroll
                for (int t=0;t<4;++t)
                    acc[t][vt] = __builtin_amdgcn_mfma_f32_16x16x32_bf16(Aa[half][t], Ba[half][vt], acc[t][vt], 0,0,0);
    }

#pragma unroll
    for (int vt=0; vt<4; ++vt){
        unsigned short* op = out + (pvb + vt*16 + ll)*64 + kg*4;
#pragma unroll
        for (int t=0;t<4;++t){
            float r0 = acc[t][vt][0], r1 = acc[t][vt][1], r2 = acc[t][vt][2], r3 = acc[t][vt][3];
            if (RELU){ r0=fmaxf(r0,0.f); r1=fmaxf(r1,0.f); r2=fmaxf(r2,0.f); r3=fmaxf(r3,0.f); }
            unsigned int lo = (unsigned)f2bf(r0) | ((unsigned)f2bf(r1)<<16);
            unsigned int hi = (unsigned)f2bf(r2) | ((unsigned)f2bf(r3)<<16);
            u32x2v q = {lo, hi};
            *(u32x2v*)(op + t*16) = q;
        }
    }
}

// ============ MFMA 1x1 conv on PADDED linear space (halo: relu(M*0)=0 preserved) ============
__global__ __launch_bounds__(256,3) void k_conv1m(const unsigned short* __restrict__ in,
        const unsigned short* __restrict__ wt, unsigned short* __restrict__ out){
    const int lane = threadIdx.x & 63;
    const int wave = threadIdx.x >> 6;
    const int ll = lane & 15;
    const int kg = lane >> 4;
    const long vb = (long)blockIdx.x*256 + wave*64;

    bf16x8 A[2][4], B[2][4];
#pragma unroll
    for (int half=0; half<2; ++half){
        const int ko = half*32 + kg*8;
#pragma unroll
        for (int t=0;t<4;++t)
            A[half][t] = *(const bf16x8*)(wt + (t*16+ll)*64 + ko);
#pragma unroll
        for (int vt=0; vt<4; ++vt)
            B[half][vt] = *(const bf16x8*)(in + (vb+vt*16+ll)*64 + ko);
    }

    f32x4 acc[4][4];
#pragma unroll
    for (int a=0;a<4;++a)
#pragma unroll
        for (int b=0;b<4;++b) acc[a][b] = (f32x4){0.f,0.f,0.f,0.f};

#pragma unroll
    for (int half=0; half<2; ++half)
#pragma unroll
        for (int vt=0; vt<4; ++vt)
#pragma unroll
            for (int t=0;t<4;++t)
                acc[t][vt] = __builtin_amdgcn_mfma_f32_16x16x32_bf16(A[half][t], B[half][vt], acc[t][vt], 0,0,0);

#pragma unroll
    for (int vt=0; vt<4; ++vt){
        unsigned short* op = out + (vb+vt*16+ll)*64 + kg*4;
#pragma unroll
        for (int t=0;t<4;++t){
            float r0 = fmaxf(acc[t][vt][0],0.f), r1 = fmaxf(acc[t][vt][1],0.f);
            float r2 = fmaxf(acc[t][vt][2],0.f), r3 = fmaxf(acc[t][vt][3],0.f);
            unsigned int lo = (unsigned)f2bf(r0) | ((unsigned)f2bf(r1)<<16);
            unsigned int hi = (unsigned)f2bf(r2) | ((unsigned)f2bf(r3)<<16);
            u32x2v q = {lo, hi};
            *(u32x2v*)(op + t*16) = q;
        }
    }
}

// ============ head stage 1: t[tap][pv] = sum_co in[pv][co]*wc2[co][tap]  (padded space) ============
__global__ __launch_bounds__(256) void k_headt(const unsigned short* __restrict__ in,
        const unsigned short* __restrict__ wt2, float* __restrict__ t){
    const int lane = threadIdx.x & 63;
    const int wave = threadIdx.x >> 6;
    const int ll = lane & 15;
    const int kg = lane >> 4;
    const long vb = (long)blockIdx.x*256 + wave*64;

    f32x4 acc[2][4];
#pragma unroll
    for (int a=0;a<2;++a)
#pragma unroll
        for (int b=0;b<4;++b) acc[a][b] = (f32x4){0.f,0.f,0.f,0.f};

#pragma unroll
    for (int khalf=0; khalf<2; ++khalf){
        const int ko = khalf*32 + kg*8;
        bf16x8 afr[2];
#pragma unroll
        for (int tl=0;tl<2;++tl)
            afr[tl] = *(const bf16x8*)(wt2 + (tl*16+ll)*64 + ko);
#pragma unroll
        for (int vt=0; vt<4; ++vt){
            bf16x8 bfr = *(const bf16x8*)(in + (vb+vt*16+ll)*64 + ko);
#pragma unroll
            for (int tl=0;tl<2;++tl)
                acc[tl][vt] = __builtin_amdgcn_mfma_f32_16x16x32_bf16(afr[tl], bfr, acc[tl][vt], 0,0,0);
        }
    }
#pragma unroll
    for (int vt=0; vt<4; ++vt){
        long vx = vb + vt*16 + ll;
#pragma unroll
        for (int tl=0;tl<2;++tl){
#pragma unroll
            for (int r=0;r<4;++r){
                int tap = tl*16 + kg*4 + r;
                if (tap < 27) t[(long)tap*PVOL + vx] = acc[tl][vt][r];
            }
        }
    }
}

// ============ head stage 2: out[v] = bias + sum_tap t[tap][p + dv_p(tap)] ============
__global__ __launch_bounds__(256) void k_heads(const float* __restrict__ t,
        const float* __restrict__ bias, float* __restrict__ out){
    int v = blockIdx.x*256 + threadIdx.x;
    int ww = v & 127; int h = (v>>7)&63; int d = v>>13;
    long p = (long)(d*64+h)*PW + ww + 1;
    float s = bias[0];
#pragma unroll
    for (int kd=0;kd<3;++kd){
#pragma unroll
      for (int kh=0;kh<3;++kh){
#pragma unroll
        for (int kw=0;kw<3;++kw){
            const int tap = (kd*3+kh)*3+kw;
            const long dvp = (long)((kd-1)*64 + (kh-1))*PW + (kw-1);
            bool ok = ((unsigned)(d+kd-1)<48u) && ((unsigned)(h+kh-1)<64u);  // w safe via pad
            long va = ok ? (p + dvp) : p;
            float x = t[(long)tap*PVOL + va];
            s += ok ? x : 0.f;
        }
      }
    }
    out[v] = s;
}

// ============ global pool partials over real voxels: 384 blocks x 1024 vox ============
__global__ __launch_bounds__(256) void k_gpool(const unsigned short* __restrict__ in,
                                               float* __restrict__ part){
    __shared__ float sm[32][64];
    int cg = threadIdx.x & 7;
    int r  = threadIdx.x >> 3;
    long vb = (long)blockIdx.x*1024;          // 8 h-rows, same d
    int d  = (int)(vb >> 13);
    int h0 = (int)((vb >> 7) & 63);
    float a[8];
#pragma unroll
    for (int j=0;j<8;++j) a[j]=0.f;
    for (int v = r; v < 1024; v += 32){
        int h = h0 + (v >> 7); int w = v & 127;
        long p = (long)(d*64+h)*PW + w + 1;
        u32x4v q = *(const u32x4v*)(in + p*64 + cg*8);
#pragma unroll
        for (int e=0;e<4;++e){
            a[e*2]   += bflo(q[e]);
            a[e*2+1] += bfhi(q[e]);
        }
    }
#pragma unroll
    for (int j=0;j<8;++j) sm[r][cg*8+j] = a[j];
    __syncthreads();
    if (threadIdx.x < 64){
        float s=0.f;
        for (int rr=0;rr<32;++rr) s += sm[rr][threadIdx.x];
        part[blockIdx.x*64 + threadIdx.x] = s;
    }
}

__global__ void k_gfin(const float* __restrict__ part, const float* __restrict__ wp0,
                       float* __restrict__ gc){
    __shared__ float sg[64];
    int t = threadIdx.x;
    if (t < 64){
        float s=0.f;
        for (int b=0;b<384;++b) s += part[b*64 + t];
        sg[t] = s * (1.0f/(float)VOL);
    }
    __syncthreads();
    if (t < 64){
        float s=0.f;
        for (int ci=0;ci<64;++ci) s += wp0[t*64+ci]*sg[ci];
        gc[t] = s;
    }
}

// ============ avg pool (VALID, stride=ksize), padded bf16 in, fp32 [c][cells] out ============
__global__ void k_avgpool(const unsigned short* __restrict__ in, float* __restrict__ out,
                          int od,int oh,int ow,int kd,int kh,int kw){
    int ovol = od*oh*ow;
    int idx = blockIdx.x*256 + threadIdx.x;
    if (idx >= 64*ovol) return;
    int c = idx & 63; int cell = idx >> 6;
    int z = cell/(oh*ow); int rem = cell - z*(oh*ow); int y = rem/ow; int x = rem - y*ow;
    float s = 0.f;
    for (int a=0;a<kd;++a)
        for (int b=0;b<kh;++b)
            for (int e=0;e<kw;++e){
                long p = (long)((z*kd+a)*64 + (y*kh+b))*PW + (x*kw+e) + 1;
                s += bf2f(in[p*64 + c]);
            }
    out[c*ovol + cell] = s / (float)(kd*kh*kw);
}

// ============ 1x1 conv fp32 on pooled grids; wt [ci][co], OUT voxel-major [cell][64] ============
__global__ void k_conv1(const float* __restrict__ in, const float* __restrict__ wt,
                        float* __restrict__ out, int vol){
    int v = blockIdx.x*256 + threadIdx.x;
    if (v >= vol) return;
    float acc[64];
#pragma unroll
    for (int i=0;i<64;++i) acc[i]=0.f;
    for (int ci=0; ci<64; ++ci){
        float xv = in[ci*vol + v];
        const float* wr = wt + ci*64;
#pragma unroll
        for (int co=0; co<64; ++co) acc[co] = fmaf(wr[co], xv, acc[co]);
    }
    float* op = out + (long)v*64;
#pragma unroll
    for (int q=0;q<16;++q){
        f32x4 t = {acc[q*4], acc[q*4+1], acc[q*4+2], acc[q*4+3]};
        *(f32x4*)(op + q*4) = t;
    }
}

// ============ trilinear gather ============
__device__ __forceinline__ void tri_setup(int d,int h,int w,int gd,int gh,int gw,
                                          int* o, float* wt){
    float fz = (d+0.5f)*((float)gd/(float)DD) - 0.5f;
    float fy = (h+0.5f)*((float)gh/(float)HH) - 0.5f;
    float fx = (w+0.5f)*((float)gw/(float)WW) - 0.5f;
    float z0f = floorf(fz), y0f = floorf(fy), x0f = floorf(fx);
    float tz = fz - z0f, ty = fy - y0f, tx = fx - x0f;
    int z0 = (int)z0f, y0 = (int)y0f, x0 = (int)x0f;
    int z1 = z0+1, y1 = y0+1, x1 = x0+1;
    z0 = min(max(z0,0),gd-1); z1 = min(max(z1,0),gd-1);
    y0 = min(max(y0,0),gh-1); y1 = min(max(y1,0),gh-1);
    x0 = min(max(x0,0),gw-1); x1 = min(max(x1,0),gw-1);
    o[0] = (z0*gh+y0)*gw+x0; wt[0] = (1-tz)*(1-ty)*(1-tx);
    o[1] = (z0*gh+y0)*gw+x1; wt[1] = (1-tz)*(1-ty)*tx;
    o[2] = (z0*gh+y1)*gw+x0; wt[2] = (1-tz)*ty*(1-tx);
    o[3] = (z0*gh+y1)*gw+x1; wt[3] = (1-tz)*ty*tx;
    o[4] = (z1*gh+y0)*gw+x0; wt[4] = tz*(1-ty)*(1-tx);
    o[5] = (z1*gh+y0)*gw+x1; wt[5] = tz*(1-ty)*tx;
    o[6] = (z1*gh+y1)*gw+x0; wt[6] = tz*ty*(1-tx);
    o[7] = (z1*gh+y1)*gw+x1; wt[7] = tz*ty*tx;
}

// out = relu((xc + 0.25*(gc + up(p2)+up(p3)+up(p4)))/2)
__global__ __launch_bounds__(256) void k_combine(
        const unsigned short* __restrict__ xc, const float* __restrict__ gc,
        const float* __restrict__ p2, const float* __restrict__ p3,
        const float* __restrict__ p4, float* __restrict__ xout,
        unsigned short* __restrict__ xv){
    int tid = threadIdx.x;
    long v = (long)blockIdx.x*256 + tid;
    int w = v & 127; int h = (v>>7)&63; int d = v>>13;
    long p = (long)(d*64+h)*PW + w + 1;
    int o2[8], o3[8], o4[8];
    float w2_[8], w3_[8], w4_[8];
    tri_setup(d,h,w, 8,8,8,    o2, w2_);
    tri_setup(d,h,w, 16,16,16, o3, w3_);
    tri_setup(d,h,w, 24,32,25, o4, w4_);
#pragma unroll
    for (int half=0; half<2; ++half){
        float res[32];
#pragma unroll
        for (int j=0;j<32;++j) res[j] = gc[half*32+j];
#pragma unroll
        for (int t=0;t<8;++t){
            const float* b2 = p2 + (long)o2[t]*64 + half*32;
#pragma unroll
            for (int q=0;q<8;++q){
                f32x4 x4 = *(const f32x4*)(b2 + q*4);
                res[q*4+0] = fmaf(w2_[t], x4[0], res[q*4+0]);
                res[q*4+1] = fmaf(w2_[t], x4[1], res[q*4+1]);
                res[q*4+2] = fmaf(w2_[t], x4[2], res[q*4+2]);
                res[q*4+3] = fmaf(w2_[t], x4[3], res[q*4+3]);
            }
        }
#pragma unroll
        for (int t=0;t<8;++t){
            const float* b3 = p3 + (long)o3[t]*64 + half*32;
#pragma unroll
            for (int q=0;q<8;++q){
                f32x4 x4 = *(const f32x4*)(b3 + q*4);
                res[q*4+0] = fmaf(w3_[t], x4[0], res[q*4+0]);
                res[q*4+1] = fmaf(w3_[t], x4[1], res[q*4+1]);
                res[q*4+2] = fmaf(w3_[t], x4[2], res[q*4+2]);
                res[q*4+3] = fmaf(w3_[t], x4[3], res[q*4+3]);
            }
        }
#pragma unroll
        for (int t=0;t<8;++t){
            const float* b4 = p4 + (long)o4[t]*64 + half*32;
#pragma unroll
            for (int q=0;q<8;++q){
                f32x4 x4 = *(const f32x4*)(b4 + q*4);
                res[q*4+0] = fmaf(w4_[t], x4[0], res[q*4+0]);
                res[q*4+1] = fmaf(w4_[t], x4[1], res[q*4+1]);
                res[q*4+2] = fmaf(w4_[t], x4[2], res[q*4+2]);
                res[q*4+3] = fmaf(w4_[t], x4[3], res[q*4+3]);
            }
        }
        const u32x4v* xq = (const u32x4v*)(xc + p*64 + half*32);
#pragma unroll
        for (int q=0;q<4;++q){
            u32x4v qv = xq[q];
            unsigned int pk[4];
#pragma unroll
            for (int e=0;e<4;++e){
                int j = q*8 + e*2;
                float r0 = fmaxf((bflo(qv[e]) + 0.25f*res[j])*0.5f, 0.f);
                float r1 = fmaxf((bfhi(qv[e]) + 0.25f*res[j+1])*0.5f, 0.f);
                xout[(long)(half*32+j)*VOL + v]   = r0;
                xout[(long)(half*32+j+1)*VOL + v] = r1;
                pk[e] = (unsigned)f2bf(r0) | ((unsigned)f2bf(r1)<<16);
            }
            u32x4v pq = {pk[0],pk[1],pk[2],pk[3]};
            *(u32x4v*)(xv + p*64 + half*32 + q*8) = pq;
        }
    }
}

// ================= workspace layout (bytes) =================
constexpr long RPV = GUARD + PVBYTES + GUARD;       // guarded padded volume region
constexpr long OFF_PV0R = 0;
constexpr long OFF_PV1R = RPV;                      // 51,151,360
constexpr long OFF_WA1 = 2*RPV;                     // 102,302,720
constexpr long OFF_WA2 = OFF_WA1 + 221184;
constexpr long OFF_WC1 = OFF_WA2 + 221184;
constexpr long OFF_NIN = OFF_WC1 + 221184;          // 8,192
constexpr long OFF_MT  = OFF_NIN + 8192;            // 40,960
constexpr long OFF_WT2 = OFF_MT + 40960;            // 4,096
constexpr long OFF_WPT = OFF_WT2 + 4096;            // 49,152
constexpr long OFF_GP  = OFF_WPT + 49152;           // 98,304
constexpr long OFF_GC  = OFF_GP + 98304;            // 256
constexpr long OFF_P2  = OFF_GC + 256;              // 131,072
constexpr long OFF_P2C = OFF_P2 + 131072;
constexpr long OFF_P3  = OFF_P2C + 131072;          // 1,048,576
constexpr long OFF_P3C = OFF_P3 + 1048576;
constexpr long OFF_P4  = OFF_P3C + 1048576;         // 4,915,200
constexpr long OFF_P4C = OFF_P4 + 4915200;
// end ~= 115.4 MB

extern "C" void kernel_launch(void* const* d_in, const int* in_sizes, int n_in,
                              void* d_out, int out_size, void* d_ws, size_t ws_size,
                              hipStream_t stream) {
    const float* fvl  = (const float*)d_in[0];
    const float* w_a1 = (const float*)d_in[1];
    const float* w_a2 = (const float*)d_in[2];
    const float* wnin = (const float*)d_in[3];
    const float* w1s  = (const float*)d_in[4];
    const float* w2s  = (const float*)d_in[5];
    const float* wp0  = (const float*)d_in[6];
    const float* wp1  = (const float*)d_in[7];
    const float* wp2  = (const float*)d_in[8];
    const float* wp3  = (const float*)d_in[9];
    const float* wc1  = (const float*)d_in[10];
    const float* wc2  = (const float*)d_in[11];
    const float* bc   = (const float*)d_in[12];

    char* ws = (char*)d_ws;
    unsigned short* PV0  = (unsigned short*)(ws + OFF_PV0R + GUARD);
    unsigned short* PV1  = (unsigned short*)(ws + OFF_PV1R + GUARD);
    unsigned short* wa1t = (unsigned short*)(ws + OFF_WA1);
    unsigned short* wa2t = (unsigned short*)(ws + OFF_WA2);
    unsigned short* wc1t = (unsigned short*)(ws + OFF_WC1);
    unsigned short* nint = (unsigned short*)(ws + OFF_NIN);
    unsigned short* Mt   = (unsigned short*)(ws + OFF_MT);
    unsigned short* wt2  = (unsigned short*)(ws + OFF_WT2);
    float* wpt  = (float*)(ws + OFF_WPT);
    float* gp   = (float*)(ws + OFF_GP);
    float* gc   = (float*)(ws + OFF_GC);
    float* p2   = (float*)(ws + OFF_P2);
    float* p2c  = (float*)(ws + OFF_P2C);
    float* p3   = (float*)(ws + OFF_P3);
    float* p3c  = (float*)(ws + OFF_P3C);
    float* p4   = (float*)(ws + OFF_P4);
    float* p4c  = (float*)(ws + OFF_P4C);

    float* Xout = (float*)d_out;                       // [64][VOL] fp32 (final x)
    float* Cout = Xout + (long)NC*VOL;                 // [VOL] fp32 (final c)
    float* Tbuf = (float*)PV0;                         // head t fp32 [27][PVOL] aliases PV0 (43.1MB<=51.1MB)

    const int GBR = VOL/256;     // 1536 blocks (real-voxel kernels)
    const int GBP = PVOL/256;    // 1560 blocks (padded-linear kernels)

    // --- zero padded volumes (halo invariant; deterministic each call) ---
    hipMemsetAsync(PV0, 0, PVBYTES, stream);
    hipMemsetAsync(PV1, 0, PVBYTES, stream);

    // --- prep ---
    k_wprep3<<<(27*64*64+255)/256,256,0,stream>>>(w_a1, wa1t);
    k_wprep3<<<(27*64*64+255)/256,256,0,stream>>>(w_a2, wa2t);
    k_wprep3<<<(27*64*64+255)/256,256,0,stream>>>(wc1, wc1t);
    k_wprep1<<<16,256,0,stream>>>(wnin, nint);
    k_wprep2<<<8,256,0,stream>>>(wc2, wt2);
    k_fuse_res<<<80,256,0,stream>>>(w1s, w2s, Mt);
    k_transpose1<<<16,256,0,stream>>>(wp1, wpt + 0*4096);
    k_transpose1<<<16,256,0,stream>>>(wp2, wpt + 1*4096);
    k_transpose1<<<16,256,0,stream>>>(wp3, wpt + 2*4096);
    k_tobf16v<<<VOL/64,256,0,stream>>>(fvl, PV0);

    // --- stage A: PV1 = conv3(PV0, wa1) ---
    k_conv3m<false,false><<<GBR,256,0,stream>>>(PV0, wa1t, nullptr, nullptr, PV1);
    // --- stage B: PV0 = conv3(PV1, wa2) + conv1(PV0, nin)  (aux in-place per-voxel: safe) ---
    k_conv3m<true,false><<<GBR,256,0,stream>>>(PV1, wa2t, PV0, nint, PV0);

    // --- stage C: 5x fused residual 1x1 (relu), padded-linear, ping-pong; ends in PV1 ---
    unsigned short* cur = PV0; unsigned short* nxt = PV1;
    for (int i=0;i<5;++i){
        k_conv1m<<<GBP,256,0,stream>>>(cur, Mt + i*4096, nxt);
        unsigned short* t = cur; cur = nxt; nxt = t;
    }
    // cur == PV1

    // --- stage D: pool pyramid (reads padded chain output) ---
    k_gpool<<<384,256,0,stream>>>(cur, gp);
    k_gfin<<<1,64,0,stream>>>(gp, wp0, gc);

    k_avgpool<<<(64*512+255)/256,256,0,stream>>>(cur, p2, 8,8,8,   6,8,16);
    k_conv1<<<2,256,0,stream>>>(p2, wpt + 0*4096, p2c, 512);

    k_avgpool<<<(64*4096+255)/256,256,0,stream>>>(cur, p3, 16,16,16, 3,4,8);
    k_conv1<<<16,256,0,stream>>>(p3, wpt + 1*4096, p3c, 4096);

    k_avgpool<<<(64*19200+255)/256,256,0,stream>>>(cur, p4, 24,32,25, 2,2,5);
    k_conv1<<<75,256,0,stream>>>(p4, wpt + 2*4096, p4c, 19200);

    // --- combine: Xout (fp32 real, final) + padded bf16 x into PV0 ---
    k_combine<<<GBR,256,0,stream>>>(cur, gc, p2c, p3c, p4c, Xout, PV0);

    // --- head: PV1 = relu(conv3(PV0, wc1)); t = PV1 @ wc2-taps (padded); Cout = gather-sum + bc ---
    k_conv3m<false,true><<<GBR,256,0,stream>>>(PV0, wc1t, nullptr, nullptr, PV1);
    k_headt<<<GBP,256,0,stream>>>(PV1, wt2, Tbuf);   // PV0 region free now
    k_heads<<<GBR,256,0,stream>>>(Tbuf, bc, Cout);
}

// Round 9
// 744.031 us; speedup vs baseline: 2.2110x; 1.3306x over previous
//
#include <hip/hip_runtime.h>
#include <math.h>

#define DD 48
#define HH 64
#define WW 128
#define VOL (DD*HH*WW)     // 393216 real voxels
#define PW 130             // padded W
#define PROWS (DD*HH)      // 3072 rows
#define PVOL (PROWS*PW)    // 399360 padded voxels
#define PVBYTES ((long)PVOL*64*2) // 51,118,080 bytes per padded bf16 volume
#define GUARD 16640L       // one padded row (130 vox * 128 B) guard each side
#define NC 64

typedef __attribute__((ext_vector_type(8))) short bf16x8;
typedef __attribute__((ext_vector_type(4))) float f32x4;
typedef __attribute__((ext_vector_type(4))) unsigned int u32x4v;
typedef __attribute__((ext_vector_type(2))) unsigned int u32x2v;

__device__ __forceinline__ float bflo(unsigned int u){
    union { unsigned int i; float f; } x; x.i = u<<16; return x.f; }
__device__ __forceinline__ float bfhi(unsigned int u){
    union { unsigned int i; float f; } x; x.i = u & 0xffff0000u; return x.f; }
__device__ __forceinline__ float bf2f(unsigned short u){
    union { unsigned int i; float f; } x; x.i = ((unsigned int)u)<<16; return x.f; }
__device__ __forceinline__ unsigned short f2bf(float f){
    union { float f; unsigned int i; } x; x.f = f;
    unsigned int i = x.i;
    return (unsigned short)((i + 0x7fffu + ((i>>16)&1u)) >> 16);  // RNE
}

// async global->LDS, 16B per lane, no VGPR destination (cannot be re-serialized)
__device__ __forceinline__ void gload16(const void* g, void* l){
    __builtin_amdgcn_global_load_lds(
        (const __attribute__((address_space(1))) void*)g,
        (__attribute__((address_space(3))) void*)l, 16, 0, 0);
}

// ================= weight prep =================

// src [co=64][ci=64][k=27] fp32 -> dst [k=27][co=64][ci=64] bf16
__global__ void k_wprep3(const float* __restrict__ src, unsigned short* __restrict__ dst){
    int idx = blockIdx.x*256 + threadIdx.x;
    if (idx >= 27*64*64) return;
    int ci = idx & 63; int t = idx >> 6; int co = t & 63; int k = t >> 6;
    dst[idx] = f2bf(src[(co*64+ci)*27 + k]);
}

__global__ void k_wprep1(const float* __restrict__ src, unsigned short* __restrict__ dst){
    int idx = blockIdx.x*256 + threadIdx.x;
    if (idx >= 4096) return;
    dst[idx] = f2bf(src[idx]);
}

// wc2 [co=64][tap=27] fp32 -> dst [taprow=32][co=64] bf16 (taps >=27 zero)
__global__ void k_wprep2(const float* __restrict__ src, unsigned short* __restrict__ dst){
    int idx = blockIdx.x*256 + threadIdx.x;
    if (idx >= 32*64) return;
    int co = idx & 63; int row = idx >> 6;
    float v = (row < 27) ? src[co*27 + row] : 0.f;
    dst[row*64 + co] = f2bf(v);
}

// M_i = W1_i + W2_i @ W1_i, output bf16 [i][co][ci]
__global__ void k_fuse_res(const float* __restrict__ w1, const float* __restrict__ w2,
                           unsigned short* __restrict__ mt){
    int idx = blockIdx.x*256 + threadIdx.x;
    if (idx >= 5*4096) return;
    int i = idx >> 12; int r = idx & 4095;
    int co = r >> 6; int ci = r & 63;
    const float* W1 = w1 + i*4096;
    const float* W2 = w2 + i*4096;
    float m = W1[co*64+ci];
    for (int k=0;k<64;++k) m += W2[co*64+k]*W1[k*64+ci];
    mt[idx] = f2bf(m);
}

// dst[ci*64+co] = src[co*64+ci]  (fp32, for pool 1x1 convs)
__global__ void k_transpose1(const float* __restrict__ src, float* __restrict__ dst){
    int idx = blockIdx.x*256 + threadIdx.x;
    if (idx >= 4096) return;
    int ci = idx >> 6; int co = idx & 63;
    dst[idx] = src[co*64+ci];
}

// ============ fvl [64][VOL] fp32 -> padded [PVOL][64] bf16 (LDS transpose) ============
__global__ __launch_bounds__(256) void k_tobf16v(const float* __restrict__ src,
                                                 unsigned short* __restrict__ dst){
    __shared__ unsigned short lds[64*66];
    int tid = threadIdx.x;
    long vbase = (long)blockIdx.x*64;           // 64 consecutive real voxels, same (d,h)
    int d = (int)(vbase >> 13);
    int h = (int)((vbase >> 7) & 63);
    int w0 = (int)(vbase & 127);                // 0 or 64
    long pbase = ((long)(d*64+h)*PW + w0 + 1);  // padded voxel index of vbase
    int v = tid & 63;
    int cg = tid >> 6;
#pragma unroll
    for (int k=0;k<16;++k){
        int ci = cg*16 + k;
        lds[v*66 + ci] = f2bf(src[(long)ci*VOL + vbase + v]);
    }
    __syncthreads();
#pragma unroll
    for (int it=0; it<2; ++it){
        int chunk = it*256 + tid;       // 512 chunks = 64v x 8 groups
        int vv = chunk >> 3, gp = chunk & 7;
        const unsigned short* s = lds + vv*66 + gp*8;
        unsigned int w0_ = (unsigned)s[0] | ((unsigned)s[1]<<16);
        unsigned int w1_ = (unsigned)s[2] | ((unsigned)s[3]<<16);
        unsigned int w2_ = (unsigned)s[4] | ((unsigned)s[5]<<16);
        unsigned int w3_ = (unsigned)s[6] | ((unsigned)s[7]<<16);
        u32x4v q = {w0_,w1_,w2_,w3_};
        *(u32x4v*)(dst + (pbase+vv)*64 + gp*8) = q;
    }
}

// ============ MFMA conv3x3x3: LDS-staged via global_load_lds ============
// (unchanged from R7 — the 321->~? fix that took conv3m off the top-5)
template<bool AUX, bool RELU>
__global__ __launch_bounds__(256,2) void k_conv3m(
    const unsigned short* __restrict__ in, const unsigned short* __restrict__ wt,
    const unsigned short* __restrict__ aux, const unsigned short* __restrict__ auxw,
    unsigned short* __restrict__ out)
{
    __shared__ __align__(16) char sA[36864];
    __shared__ __align__(16) char sB[33280];

    const int tid  = threadIdx.x;
    const int lane = tid & 63;
    const int wave = tid >> 6;
    const int ll = lane & 15;
    const int kg = lane >> 4;
    const int bid = blockIdx.x;
    const int wid = ((bid & 7) * 192) + (bid >> 3);
    const int vbr = wid*256;
    const int d  = vbr >> 13;
    const int h0 = (vbr >> 7) & 63;
    const int my_h  = h0 + (wave >> 1);
    const int my_w0 = (wave & 1) * 64;
    const long pvb = (long)(d*64 + my_h)*PW + my_w0 + 1;

    const char* inb = (const char*)in;
    const char* wtb = (const char*)wt;

    f32x4 acc[4][4];
#pragma unroll
    for (int a=0;a<4;++a)
#pragma unroll
        for (int b=0;b<4;++b) acc[a][b] = (f32x4){0.f,0.f,0.f,0.f};

#pragma unroll
    for (int kd=0; kd<3; ++kd){
        const int dd = d + kd - 1;
        if ((unsigned)dd >= 48u) continue;
        const long rowstart = ((long)(dd*64 + h0 - 1)) * 130;
#pragma unroll
        for (int khalf=0; khalf<2; ++khalf){
            __syncthreads();
#pragma unroll
            for (int rnd=0; rnd<9; ++rnd){
                int j = rnd*4096 + tid*16;
                int q = j ^ (((j>>7)&3)<<4);
                const char* src = wtb + (long)(kd*9 + (q>>12))*8192
                                      + (long)((q>>6)&63)*128 + khalf*64 + (q&63);
                gload16(src, sA + j);
            }
#pragma unroll
            for (int rnd=0; rnd<8; ++rnd){
                int j = rnd*4096 + tid*16;
                int q = j ^ (((j>>7)&3)<<4);
                const char* src = inb + (rowstart + (q>>6))*128 + khalf*64 + (q&63);
                gload16(src, sB + j);
            }
            if (tid < 32){
                int j = 32768 + tid*16;
                int q = j ^ (((j>>7)&3)<<4);
                const char* src = inb + (rowstart + (q>>6))*128 + khalf*64 + (q&63);
                gload16(src, sB + j);
            }
            __syncthreads();
#pragma unroll
            for (int kh=0; kh<3; ++kh){
                const int hh = my_h + kh - 1;
                if ((unsigned)hh >= 64u) continue;
                const int rr = (wave>>1) + kh;
#pragma unroll
                for (int kw=0; kw<3; ++kw){
                    const int tap_rel = kh*3 + kw;
                    bf16x8 Af[4], Bf[4];
#pragma unroll
                    for (int t=0;t<4;++t){
                        int qa = tap_rel*4096 + (t*16+ll)*64 + kg*16;
                        Af[t] = *(const bf16x8*)(sA + (qa ^ (((qa>>7)&3)<<4)));
                    }
#pragma unroll
                    for (int vt=0; vt<4; ++vt){
                        int vrel = rr*130 + my_w0 + vt*16 + ll + kw;
                        int qb = vrel*64 + kg*16;
                        Bf[vt] = *(const bf16x8*)(sB + (qb ^ (((qb>>7)&3)<<4)));
                    }
#pragma unroll
                    for (int vt=0; vt<4; ++vt)
#pragma unroll
                        for (int t=0; t<4; ++t)
                            acc[t][vt] = __builtin_amdgcn_mfma_f32_16x16x32_bf16(Af[t], Bf[vt], acc[t][vt], 0,0,0);
                }
            }
        }
    }

    if (AUX){
        bf16x8 Aa[2][4], Ba[2][4];
#pragma unroll
        for (int half=0; half<2; ++half){
            const int ko = half*32 + kg*8;
#pragma unroll
            for (int t=0;t<4;++t)
                Aa[half][t] = *(const bf16x8*)(auxw + (t*16+ll)*64 + ko);
#pragma unroll
            for (int vt=0; vt<4; ++vt)
                Ba[half][vt] = *(const bf16x8*)(aux + (pvb + vt*16 + ll)*64 + ko);
        }
#pragma unroll
        for (int half=0; half<2; ++half)
#pragma unroll
            for (int vt=0; vt<4; ++vt)
#pragma unroll
                for (int t=0;t<4;++t)
                    acc[t][vt] = __builtin_amdgcn_mfma_f32_16x16x32_bf16(Aa[half][t], Ba[half][vt], acc[t][vt], 0,0,0);
    }

#pragma unroll
    for (int vt=0; vt<4; ++vt){
        unsigned short* op = out + (pvb + vt*16 + ll)*64 + kg*4;
#pragma unroll
        for (int t=0;t<4;++t){
            float r0 = acc[t][vt][0], r1 = acc[t][vt][1], r2 = acc[t][vt][2], r3 = acc[t][vt][3];
            if (RELU){ r0=fmaxf(r0,0.f); r1=fmaxf(r1,0.f); r2=fmaxf(r2,0.f); r3=fmaxf(r3,0.f); }
            unsigned int lo = (unsigned)f2bf(r0) | ((unsigned)f2bf(r1)<<16);
            unsigned int hi = (unsigned)f2bf(r2) | ((unsigned)f2bf(r3)<<16);
            u32x2v q = {lo, hi};
            *(u32x2v*)(op + t*16) = q;
        }
    }
}

// ============ MFMA 1x1 conv on PADDED linear space (halo: relu(M*0)=0 preserved) ============
__global__ __launch_bounds__(256,3) void k_conv1m(const unsigned short* __restrict__ in,
        const unsigned short* __restrict__ wt, unsigned short* __restrict__ out){
    const int lane = threadIdx.x & 63;
    const int wave = threadIdx.x >> 6;
    const int ll = lane & 15;
    const int kg = lane >> 4;
    const long vb = (long)blockIdx.x*256 + wave*64;

    bf16x8 A[2][4], B[2][4];
#pragma unroll
    for (int half=0; half<2; ++half){
        const int ko = half*32 + kg*8;
#pragma unroll
        for (int t=0;t<4;++t)
            A[half][t] = *(const bf16x8*)(wt + (t*16+ll)*64 + ko);
#pragma unroll
        for (int vt=0; vt<4; ++vt)
            B[half][vt] = *(const bf16x8*)(in + (vb+vt*16+ll)*64 + ko);
    }

    f32x4 acc[4][4];
#pragma unroll
    for (int a=0;a<4;++a)
#pragma unroll
        for (int b=0;b<4;++b) acc[a][b] = (f32x4){0.f,0.f,0.f,0.f};

#pragma unroll
    for (int half=0; half<2; ++half)
#pragma unroll
        for (int vt=0; vt<4; ++vt)
#pragma unroll
            for (int t=0;t<4;++t)
                acc[t][vt] = __builtin_amdgcn_mfma_f32_16x16x32_bf16(A[half][t], B[half][vt], acc[t][vt], 0,0,0);

#pragma unroll
    for (int vt=0; vt<4; ++vt){
        unsigned short* op = out + (vb+vt*16+ll)*64 + kg*4;
#pragma unroll
        for (int t=0;t<4;++t){
            float r0 = fmaxf(acc[t][vt][0],0.f), r1 = fmaxf(acc[t][vt][1],0.f);
            float r2 = fmaxf(acc[t][vt][2],0.f), r3 = fmaxf(acc[t][vt][3],0.f);
            unsigned int lo = (unsigned)f2bf(r0) | ((unsigned)f2bf(r1)<<16);
            unsigned int hi = (unsigned)f2bf(r2) | ((unsigned)f2bf(r3)<<16);
            u32x2v q = {lo, hi};
            *(u32x2v*)(op + t*16) = q;
        }
    }
}

// ============ head stage 1: t[tap][pv] = sum_co in[pv][co]*wc2[co][tap] ============
__global__ __launch_bounds__(256) void k_headt(const unsigned short* __restrict__ in,
        const unsigned short* __restrict__ wt2, float* __restrict__ t){
    const int lane = threadIdx.x & 63;
    const int wave = threadIdx.x >> 6;
    const int ll = lane & 15;
    const int kg = lane >> 4;
    const long vb = (long)blockIdx.x*256 + wave*64;

    f32x4 acc[2][4];
#pragma unroll
    for (int a=0;a<2;++a)
#pragma unroll
        for (int b=0;b<4;++b) acc[a][b] = (f32x4){0.f,0.f,0.f,0.f};

#pragma unroll
    for (int khalf=0; khalf<2; ++khalf){
        const int ko = khalf*32 + kg*8;
        bf16x8 afr[2];
#pragma unroll
        for (int tl=0;tl<2;++tl)
            afr[tl] = *(const bf16x8*)(wt2 + (tl*16+ll)*64 + ko);
#pragma unroll
        for (int vt=0; vt<4; ++vt){
            bf16x8 bfr = *(const bf16x8*)(in + (vb+vt*16+ll)*64 + ko);
#pragma unroll
            for (int tl=0;tl<2;++tl)
                acc[tl][vt] = __builtin_amdgcn_mfma_f32_16x16x32_bf16(afr[tl], bfr, acc[tl][vt], 0,0,0);
        }
    }
#pragma unroll
    for (int vt=0; vt<4; ++vt){
        long vx = vb + vt*16 + ll;
#pragma unroll
        for (int tl=0;tl<2;++tl){
#pragma unroll
            for (int r=0;r<4;++r){
                int tap = tl*16 + kg*4 + r;
                if (tap < 27) t[(long)tap*PVOL + vx] = acc[tl][vt][r];
            }
        }
    }
}

// ============ head stage 2: out[v] = bias + sum_tap t[tap][p + dv_p(tap)] ============
__global__ __launch_bounds__(256) void k_heads(const float* __restrict__ t,
        const float* __restrict__ bias, float* __restrict__ out){
    int v = blockIdx.x*256 + threadIdx.x;
    int ww = v & 127; int h = (v>>7)&63; int d = v>>13;
    long p = (long)(d*64+h)*PW + ww + 1;
    float s = bias[0];
#pragma unroll
    for (int kd=0;kd<3;++kd){
#pragma unroll
      for (int kh=0;kh<3;++kh){
#pragma unroll
        for (int kw=0;kw<3;++kw){
            const int tap = (kd*3+kh)*3+kw;
            const long dvp = (long)((kd-1)*64 + (kh-1))*PW + (kw-1);
            bool ok = ((unsigned)(d+kd-1)<48u) && ((unsigned)(h+kh-1)<64u);
            long va = ok ? (p + dvp) : p;
            float x = t[(long)tap*PVOL + va];
            s += ok ? x : 0.f;
        }
      }
    }
    out[v] = s;
}

// ============ pool stage 1: S3 cell sums (grid 16x16x16, window 3x4x8) ============
// one block per cell; 256 threads = 8 ch-groups x 32 parts; 3 vec-loads/thread
__global__ __launch_bounds__(256) void k_pool3(const unsigned short* __restrict__ in,
                                               float* __restrict__ S3){
    __shared__ float sm[32*68];
    int tid = threadIdx.x;
    int cg = tid & 7, part = tid >> 3;
    int cell = blockIdx.x;
    int Z = cell >> 8, Y = (cell >> 4) & 15, X = cell & 15;
    float a[8];
#pragma unroll
    for (int j=0;j<8;++j) a[j]=0.f;
#pragma unroll
    for (int j=0;j<3;++j){
        int i = part*3 + j;                    // 0..95
        int di = i >> 5, rem = i & 31, hi = rem >> 3, wi = rem & 7;
        long p = ((long)((3*Z+di)*64 + 4*Y+hi))*PW + 8*X+wi + 1;
        u32x4v q = *(const u32x4v*)(in + p*64 + cg*8);
#pragma unroll
        for (int e=0;e<4;++e){ a[e*2] += bflo(q[e]); a[e*2+1] += bfhi(q[e]); }
    }
#pragma unroll
    for (int j=0;j<8;++j) sm[part*68 + cg*8 + j] = a[j];
    __syncthreads();
    if (tid < 64){
        float s=0.f;
        for (int r=0;r<32;++r) s += sm[r*68 + tid];
        S3[tid*4096 + cell] = s;               // channel-major sums
    }
}

// ============ p2 sums from S3 (6x8x16 window = 2x2x2 of p3 cells) ============
__global__ __launch_bounds__(256) void k_pool2(const float* __restrict__ S3,
                                               float* __restrict__ P2){
    int idx = blockIdx.x*256 + threadIdx.x;    // 32768 = 64ch x 512 cells
    int cell = idx & 511; int c = idx >> 9;
    int z = cell >> 6, y = (cell >> 3) & 7, x = cell & 7;
    const float* b = S3 + c*4096;
    float s = 0.f;
#pragma unroll
    for (int a2=0;a2<2;++a2)
#pragma unroll
        for (int b2=0;b2<2;++b2)
#pragma unroll
            for (int e=0;e<2;++e)
                s += b[((2*z+a2)<<8) + ((2*y+b2)<<4) + (2*x+e)];
    P2[c*512 + cell] = s;
}

// ============ g + gc from S3 (global avg -> 1x1 conv wp0) ============
__global__ void k_gcm(const float* __restrict__ S3, const float* __restrict__ wp0,
                      float* __restrict__ gc){
    __shared__ float sm[4][64];
    __shared__ float sg[64];
    int tid = threadIdx.x;
    int c = tid & 63, part = tid >> 6;         // 4 parts x 1024 cells
    float s = 0.f;
    const float* row = S3 + c*4096 + part*1024;
    for (int i=0;i<1024;i+=4){
        f32x4 q = *(const f32x4*)(row + i);
        s += q[0]+q[1]+q[2]+q[3];
    }
    sm[part][c] = s;
    __syncthreads();
    if (tid < 64){
        sg[tid] = (sm[0][tid]+sm[1][tid]+sm[2][tid]+sm[3][tid]) * (1.0f/(float)VOL);
    }
    __syncthreads();
    if (tid < 64){
        float g=0.f;
        for (int ci=0;ci<64;++ci) g += wp0[tid*64+ci]*sg[ci];
        gc[tid] = g;
    }
}

// ============ p4 sums (grid 24x32x25, window 2x2x5): 8 cells/block cooperative ============
__global__ __launch_bounds__(256) void k_pool4(const unsigned short* __restrict__ in,
                                               float* __restrict__ P4){
    __shared__ float sm[32*68];                 // [slot*4+part][68]
    int tid = threadIdx.x;
    int cg = tid & 7, part = (tid >> 3) & 3, slot = tid >> 5;
    int cell = blockIdx.x*8 + slot;             // 2400 blocks x 8 = 19200
    int z = cell / 800; int rem = cell - z*800; int y = rem / 25; int x = rem - y*25;
    int a2 = part >> 1, b2 = part & 1;
    float a[8];
#pragma unroll
    for (int j=0;j<8;++j) a[j]=0.f;
#pragma unroll
    for (int e=0;e<5;++e){
        long p = ((long)((2*z+a2)*64 + 2*y+b2))*PW + 5*x+e + 1;
        u32x4v q = *(const u32x4v*)(in + p*64 + cg*8);
#pragma unroll
        for (int k=0;k<4;++k){ a[k*2] += bflo(q[k]); a[k*2+1] += bfhi(q[k]); }
    }
#pragma unroll
    for (int j=0;j<8;++j) sm[(slot*4+part)*68 + cg*8 + j] = a[j];
    __syncthreads();
#pragma unroll
    for (int r=0;r<2;++r){
        int o = r*256 + tid;                    // 512 outputs = 8 cells x 64 ch
        int c = o >> 3, s = o & 7;
        float v = sm[(s*4+0)*68 + c] + sm[(s*4+1)*68 + c]
                + sm[(s*4+2)*68 + c] + sm[(s*4+3)*68 + c];
        P4[(long)c*19200 + blockIdx.x*8 + s] = v;
    }
}

// ============ 1x1 conv fp32 on pooled SUMS; wt [ci][co], scale folds the avg ============
// OUT voxel-major [cell][64] for k_combine
__global__ void k_conv1(const float* __restrict__ in, const float* __restrict__ wt,
                        float* __restrict__ out, int vol, float scale){
    int v = blockIdx.x*256 + threadIdx.x;
    if (v >= vol) return;
    float acc[64];
#pragma unroll
    for (int i=0;i<64;++i) acc[i]=0.f;
    for (int ci=0; ci<64; ++ci){
        float xv = in[ci*vol + v];
        const float* wr = wt + ci*64;
#pragma unroll
        for (int co=0; co<64; ++co) acc[co] = fmaf(wr[co], xv, acc[co]);
    }
    float* op = out + (long)v*64;
#pragma unroll
    for (int q=0;q<16;++q){
        f32x4 t = {acc[q*4]*scale, acc[q*4+1]*scale, acc[q*4+2]*scale, acc[q*4+3]*scale};
        *(f32x4*)(op + q*4) = t;
    }
}

// ============ trilinear gather ============
__device__ __forceinline__ void tri_setup(int d,int h,int w,int gd,int gh,int gw,
                                          int* o, float* wt){
    float fz = (d+0.5f)*((float)gd/(float)DD) - 0.5f;
    float fy = (h+0.5f)*((float)gh/(float)HH) - 0.5f;
    float fx = (w+0.5f)*((float)gw/(float)WW) - 0.5f;
    float z0f = floorf(fz), y0f = floorf(fy), x0f = floorf(fx);
    float tz = fz - z0f, ty = fy - y0f, tx = fx - x0f;
    int z0 = (int)z0f, y0 = (int)y0f, x0 = (int)x0f;
    int z1 = z0+1, y1 = y0+1, x1 = x0+1;
    z0 = min(max(z0,0),gd-1); z1 = min(max(z1,0),gd-1);
    y0 = min(max(y0,0),gh-1); y1 = min(max(y1,0),gh-1);
    x0 = min(max(x0,0),gw-1); x1 = min(max(x1,0),gw-1);
    o[0] = (z0*gh+y0)*gw+x0; wt[0] = (1-tz)*(1-ty)*(1-tx);
    o[1] = (z0*gh+y0)*gw+x1; wt[1] = (1-tz)*(1-ty)*tx;
    o[2] = (z0*gh+y1)*gw+x0; wt[2] = (1-tz)*ty*(1-tx);
    o[3] = (z0*gh+y1)*gw+x1; wt[3] = (1-tz)*ty*tx;
    o[4] = (z1*gh+y0)*gw+x0; wt[4] = tz*(1-ty)*(1-tx);
    o[5] = (z1*gh+y0)*gw+x1; wt[5] = tz*(1-ty)*tx;
    o[6] = (z1*gh+y1)*gw+x0; wt[6] = tz*ty*(1-tx);
    o[7] = (z1*gh+y1)*gw+x1; wt[7] = tz*ty*tx;
}

// out = relu((xc + 0.25*(gc + up(p2)+up(p3)+up(p4)))/2)
__global__ __launch_bounds__(256) void k_combine(
        const unsigned short* __restrict__ xc, const float* __restrict__ gc,
        const float* __restrict__ p2, const float* __restrict__ p3,
        const float* __restrict__ p4, float* __restrict__ xout,
        unsigned short* __restrict__ xv){
    int tid = threadIdx.x;
    long v = (long)blockIdx.x*256 + tid;
    int w = v & 127; int h = (v>>7)&63; int d = v>>13;
    long p = (long)(d*64+h)*PW + w + 1;
    int o2[8], o3[8], o4[8];
    float w2_[8], w3_[8], w4_[8];
    tri_setup(d,h,w, 8,8,8,    o2, w2_);
    tri_setup(d,h,w, 16,16,16, o3, w3_);
    tri_setup(d,h,w, 24,32,25, o4, w4_);
#pragma unroll
    for (int half=0; half<2; ++half){
        float res[32];
#pragma unroll
        for (int j=0;j<32;++j) res[j] = gc[half*32+j];
#pragma unroll
        for (int t=0;t<8;++t){
            const float* b2 = p2 + (long)o2[t]*64 + half*32;
#pragma unroll
            for (int q=0;q<8;++q){
                f32x4 x4 = *(const f32x4*)(b2 + q*4);
                res[q*4+0] = fmaf(w2_[t], x4[0], res[q*4+0]);
                res[q*4+1] = fmaf(w2_[t], x4[1], res[q*4+1]);
                res[q*4+2] = fmaf(w2_[t], x4[2], res[q*4+2]);
                res[q*4+3] = fmaf(w2_[t], x4[3], res[q*4+3]);
            }
        }
#pragma unroll
        for (int t=0;t<8;++t){
            const float* b3 = p3 + (long)o3[t]*64 + half*32;
#pragma unroll
            for (int q=0;q<8;++q){
                f32x4 x4 = *(const f32x4*)(b3 + q*4);
                res[q*4+0] = fmaf(w3_[t], x4[0], res[q*4+0]);
                res[q*4+1] = fmaf(w3_[t], x4[1], res[q*4+1]);
                res[q*4+2] = fmaf(w3_[t], x4[2], res[q*4+2]);
                res[q*4+3] = fmaf(w3_[t], x4[3], res[q*4+3]);
            }
        }
#pragma unroll
        for (int t=0;t<8;++t){
            const float* b4 = p4 + (long)o4[t]*64 + half*32;
#pragma unroll
            for (int q=0;q<8;++q){
                f32x4 x4 = *(const f32x4*)(b4 + q*4);
                res[q*4+0] = fmaf(w4_[t], x4[0], res[q*4+0]);
                res[q*4+1] = fmaf(w4_[t], x4[1], res[q*4+1]);
                res[q*4+2] = fmaf(w4_[t], x4[2], res[q*4+2]);
                res[q*4+3] = fmaf(w4_[t], x4[3], res[q*4+3]);
            }
        }
        const u32x4v* xq = (const u32x4v*)(xc + p*64 + half*32);
#pragma unroll
        for (int q=0;q<4;++q){
            u32x4v qv = xq[q];
            unsigned int pk[4];
#pragma unroll
            for (int e=0;e<4;++e){
                int j = q*8 + e*2;
                float r0 = fmaxf((bflo(qv[e]) + 0.25f*res[j])*0.5f, 0.f);
                float r1 = fmaxf((bfhi(qv[e]) + 0.25f*res[j+1])*0.5f, 0.f);
                xout[(long)(half*32+j)*VOL + v]   = r0;
                xout[(long)(half*32+j+1)*VOL + v] = r1;
                pk[e] = (unsigned)f2bf(r0) | ((unsigned)f2bf(r1)<<16);
            }
            u32x4v pq = {pk[0],pk[1],pk[2],pk[3]};
            *(u32x4v*)(xv + p*64 + half*32 + q*8) = pq;
        }
    }
}

// ================= workspace layout (bytes) =================
constexpr long RPV = GUARD + PVBYTES + GUARD;       // guarded padded volume region
constexpr long OFF_PV0R = 0;
constexpr long OFF_PV1R = RPV;                      // 51,151,360
constexpr long OFF_WA1 = 2*RPV;                     // 102,302,720
constexpr long OFF_WA2 = OFF_WA1 + 221184;
constexpr long OFF_WC1 = OFF_WA2 + 221184;
constexpr long OFF_NIN = OFF_WC1 + 221184;          // 8,192
constexpr long OFF_MT  = OFF_NIN + 8192;            // 40,960
constexpr long OFF_WT2 = OFF_MT + 40960;            // 4,096
constexpr long OFF_WPT = OFF_WT2 + 4096;            // 49,152
constexpr long OFF_GC  = OFF_WPT + 49152;           // 256
constexpr long OFF_P2  = OFF_GC + 256;              // 131,072 (p2 sums, ch-major)
constexpr long OFF_P2C = OFF_P2 + 131072;           // 131,072 (p2c, vox-major)
constexpr long OFF_S3  = OFF_P2C + 131072;          // 1,048,576 (S3 sums, ch-major)
constexpr long OFF_P3C = OFF_S3 + 1048576;          // 1,048,576 (p3c, vox-major)
constexpr long OFF_P4  = OFF_P3C + 1048576;         // 4,915,200 (p4 sums, ch-major)
constexpr long OFF_P4C = OFF_P4 + 4915200;          // 4,915,200 (p4c, vox-major)
// end ~= 115.4 MB

extern "C" void kernel_launch(void* const* d_in, const int* in_sizes, int n_in,
                              void* d_out, int out_size, void* d_ws, size_t ws_size,
                              hipStream_t stream) {
    const float* fvl  = (const float*)d_in[0];
    const float* w_a1 = (const float*)d_in[1];
    const float* w_a2 = (const float*)d_in[2];
    const float* wnin = (const float*)d_in[3];
    const float* w1s  = (const float*)d_in[4];
    const float* w2s  = (const float*)d_in[5];
    const float* wp0  = (const float*)d_in[6];
    const float* wp1  = (const float*)d_in[7];
    const float* wp2  = (const float*)d_in[8];
    const float* wp3  = (const float*)d_in[9];
    const float* wc1  = (const float*)d_in[10];
    const float* wc2  = (const float*)d_in[11];
    const float* bc   = (const float*)d_in[12];

    char* ws = (char*)d_ws;
    unsigned short* PV0  = (unsigned short*)(ws + OFF_PV0R + GUARD);
    unsigned short* PV1  = (unsigned short*)(ws + OFF_PV1R + GUARD);
    unsigned short* wa1t = (unsigned short*)(ws + OFF_WA1);
    unsigned short* wa2t = (unsigned short*)(ws + OFF_WA2);
    unsigned short* wc1t = (unsigned short*)(ws + OFF_WC1);
    unsigned short* nint = (unsigned short*)(ws + OFF_NIN);
    unsigned short* Mt   = (unsigned short*)(ws + OFF_MT);
    unsigned short* wt2  = (unsigned short*)(ws + OFF_WT2);
    float* wpt  = (float*)(ws + OFF_WPT);
    float* gc   = (float*)(ws + OFF_GC);
    float* p2   = (float*)(ws + OFF_P2);
    float* p2c  = (float*)(ws + OFF_P2C);
    float* S3   = (float*)(ws + OFF_S3);
    float* p3c  = (float*)(ws + OFF_P3C);
    float* p4   = (float*)(ws + OFF_P4);
    float* p4c  = (float*)(ws + OFF_P4C);

    float* Xout = (float*)d_out;                       // [64][VOL] fp32 (final x)
    float* Cout = Xout + (long)NC*VOL;                 // [VOL] fp32 (final c)
    float* Tbuf = (float*)PV0;                         // head t fp32 [27][PVOL] aliases PV0

    const int GBR = VOL/256;     // 1536 blocks (real-voxel kernels)
    const int GBP = PVOL/256;    // 1560 blocks (padded-linear kernels)

    // --- zero padded volumes (halo invariant; deterministic each call) ---
    hipMemsetAsync(PV0, 0, PVBYTES, stream);
    hipMemsetAsync(PV1, 0, PVBYTES, stream);

    // --- prep ---
    k_wprep3<<<(27*64*64+255)/256,256,0,stream>>>(w_a1, wa1t);
    k_wprep3<<<(27*64*64+255)/256,256,0,stream>>>(w_a2, wa2t);
    k_wprep3<<<(27*64*64+255)/256,256,0,stream>>>(wc1, wc1t);
    k_wprep1<<<16,256,0,stream>>>(wnin, nint);
    k_wprep2<<<8,256,0,stream>>>(wc2, wt2);
    k_fuse_res<<<80,256,0,stream>>>(w1s, w2s, Mt);
    k_transpose1<<<16,256,0,stream>>>(wp1, wpt + 0*4096);
    k_transpose1<<<16,256,0,stream>>>(wp2, wpt + 1*4096);
    k_transpose1<<<16,256,0,stream>>>(wp3, wpt + 2*4096);
    k_tobf16v<<<VOL/64,256,0,stream>>>(fvl, PV0);

    // --- stage A: PV1 = conv3(PV0, wa1) ---
    k_conv3m<false,false><<<GBR,256,0,stream>>>(PV0, wa1t, nullptr, nullptr, PV1);
    // --- stage B: PV0 = conv3(PV1, wa2) + conv1(PV0, nin) ---
    k_conv3m<true,false><<<GBR,256,0,stream>>>(PV1, wa2t, PV0, nint, PV0);

    // --- stage C: 5x fused residual 1x1 (relu), ping-pong; ends in PV1 ---
    unsigned short* cur = PV0; unsigned short* nxt = PV1;
    for (int i=0;i<5;++i){
        k_conv1m<<<GBP,256,0,stream>>>(cur, Mt + i*4096, nxt);
        unsigned short* t = cur; cur = nxt; nxt = t;
    }
    // cur == PV1

    // --- stage D: pool pyramid (one volume pass for S3, one for p4) ---
    k_pool3<<<4096,256,0,stream>>>(cur, S3);
    k_gcm<<<1,256,0,stream>>>(S3, wp0, gc);
    k_pool2<<<128,256,0,stream>>>(S3, p2);
    k_pool4<<<2400,256,0,stream>>>(cur, p4);
    k_conv1<<<2,256,0,stream>>>(p2, wpt + 0*4096, p2c, 512,   1.0f/768.0f);
    k_conv1<<<16,256,0,stream>>>(S3, wpt + 1*4096, p3c, 4096, 1.0f/96.0f);
    k_conv1<<<75,256,0,stream>>>(p4, wpt + 2*4096, p4c, 19200, 1.0f/20.0f);

    // --- combine: Xout (fp32 real, final) + padded bf16 x into PV0 ---
    k_combine<<<GBR,256,0,stream>>>(cur, gc, p2c, p3c, p4c, Xout, PV0);

    // --- head ---
    k_conv3m<false,true><<<GBR,256,0,stream>>>(PV0, wc1t, nullptr, nullptr, PV1);
    k_headt<<<GBP,256,0,stream>>>(PV1, wt2, Tbuf);
    k_heads<<<GBR,256,0,stream>>>(Tbuf, bc, Cout);
}

// Round 10
// 680.101 us; speedup vs baseline: 2.4188x; 1.0940x over previous
//
#include <hip/hip_runtime.h>
#include <math.h>

#define DD 48
#define HH 64
#define WW 128
#define VOL (DD*HH*WW)     // 393216 real voxels
#define PW 130             // padded W
#define PROWS (DD*HH)      // 3072 rows
#define PVOL (PROWS*PW)    // 399360 padded voxels
#define PVBYTES ((long)PVOL*64*2) // 51,118,080 bytes per padded bf16 volume
#define GUARD 16640L       // one padded row guard each side
#define NC 64

typedef __attribute__((ext_vector_type(8))) short bf16x8;
typedef __attribute__((ext_vector_type(4))) float f32x4;
typedef __attribute__((ext_vector_type(4))) unsigned int u32x4v;
typedef __attribute__((ext_vector_type(2))) unsigned int u32x2v;

__device__ __forceinline__ float bflo(unsigned int u){
    union { unsigned int i; float f; } x; x.i = u<<16; return x.f; }
__device__ __forceinline__ float bfhi(unsigned int u){
    union { unsigned int i; float f; } x; x.i = u & 0xffff0000u; return x.f; }
__device__ __forceinline__ float bf2f(unsigned short u){
    union { unsigned int i; float f; } x; x.i = ((unsigned int)u)<<16; return x.f; }
__device__ __forceinline__ unsigned short f2bf(float f){
    union { float f; unsigned int i; } x; x.f = f;
    unsigned int i = x.i;
    return (unsigned short)((i + 0x7fffu + ((i>>16)&1u)) >> 16);  // RNE
}

__device__ __forceinline__ void gload16(const void* g, void* l){
    __builtin_amdgcn_global_load_lds(
        (const __attribute__((address_space(1))) void*)g,
        (__attribute__((address_space(3))) void*)l, 16, 0, 0);
}

// ================= weight prep =================

__global__ void k_wprep3(const float* __restrict__ src, unsigned short* __restrict__ dst){
    int idx = blockIdx.x*256 + threadIdx.x;
    if (idx >= 27*64*64) return;
    int ci = idx & 63; int t = idx >> 6; int co = t & 63; int k = t >> 6;
    dst[idx] = f2bf(src[(co*64+ci)*27 + k]);
}

__global__ void k_wprep1(const float* __restrict__ src, unsigned short* __restrict__ dst){
    int idx = blockIdx.x*256 + threadIdx.x;
    if (idx >= 4096) return;
    dst[idx] = f2bf(src[idx]);
}

__global__ void k_wprep2(const float* __restrict__ src, unsigned short* __restrict__ dst){
    int idx = blockIdx.x*256 + threadIdx.x;
    if (idx >= 32*64) return;
    int co = idx & 63; int row = idx >> 6;
    float v = (row < 27) ? src[co*27 + row] : 0.f;
    dst[row*64 + co] = f2bf(v);
}

__global__ void k_fuse_res(const float* __restrict__ w1, const float* __restrict__ w2,
                           unsigned short* __restrict__ mt){
    int idx = blockIdx.x*256 + threadIdx.x;
    if (idx >= 5*4096) return;
    int i = idx >> 12; int r = idx & 4095;
    int co = r >> 6; int ci = r & 63;
    const float* W1 = w1 + i*4096;
    const float* W2 = w2 + i*4096;
    float m = W1[co*64+ci];
    for (int k=0;k<64;++k) m += W2[co*64+k]*W1[k*64+ci];
    mt[idx] = f2bf(m);
}

__global__ void k_transpose1(const float* __restrict__ src, float* __restrict__ dst){
    int idx = blockIdx.x*256 + threadIdx.x;
    if (idx >= 4096) return;
    int ci = idx >> 6; int co = idx & 63;
    dst[idx] = src[co*64+ci];
}

// ============ fvl [64][VOL] fp32 -> padded [PVOL][64] bf16 (LDS transpose) ============
__global__ __launch_bounds__(256) void k_tobf16v(const float* __restrict__ src,
                                                 unsigned short* __restrict__ dst){
    __shared__ unsigned short lds[64*66];
    int tid = threadIdx.x;
    long vbase = (long)blockIdx.x*64;
    int d = (int)(vbase >> 13);
    int h = (int)((vbase >> 7) & 63);
    int w0 = (int)(vbase & 127);
    long pbase = ((long)(d*64+h)*PW + w0 + 1);
    int v = tid & 63;
    int cg = tid >> 6;
#pragma unroll
    for (int k=0;k<16;++k){
        int ci = cg*16 + k;
        lds[v*66 + ci] = f2bf(src[(long)ci*VOL + vbase + v]);
    }
    __syncthreads();
#pragma unroll
    for (int it=0; it<2; ++it){
        int chunk = it*256 + tid;
        int vv = chunk >> 3, gp = chunk & 7;
        const unsigned short* s = lds + vv*66 + gp*8;
        unsigned int w0_ = (unsigned)s[0] | ((unsigned)s[1]<<16);
        unsigned int w1_ = (unsigned)s[2] | ((unsigned)s[3]<<16);
        unsigned int w2_ = (unsigned)s[4] | ((unsigned)s[5]<<16);
        unsigned int w3_ = (unsigned)s[6] | ((unsigned)s[7]<<16);
        u32x4v q = {w0_,w1_,w2_,w3_};
        *(u32x4v*)(dst + (pbase+vv)*64 + gp*8) = q;
    }
}

// ============ MFMA conv3x3x3: LDS-staged via global_load_lds (R7, unchanged) ============
template<bool AUX, bool RELU>
__global__ __launch_bounds__(256,2) void k_conv3m(
    const unsigned short* __restrict__ in, const unsigned short* __restrict__ wt,
    const unsigned short* __restrict__ aux, const unsigned short* __restrict__ auxw,
    unsigned short* __restrict__ out)
{
    __shared__ __align__(16) char sA[36864];
    __shared__ __align__(16) char sB[33280];

    const int tid  = threadIdx.x;
    const int lane = tid & 63;
    const int wave = tid >> 6;
    const int ll = lane & 15;
    const int kg = lane >> 4;
    const int bid = blockIdx.x;
    const int wid = ((bid & 7) * 192) + (bid >> 3);
    const int vbr = wid*256;
    const int d  = vbr >> 13;
    const int h0 = (vbr >> 7) & 63;
    const int my_h  = h0 + (wave >> 1);
    const int my_w0 = (wave & 1) * 64;
    const long pvb = (long)(d*64 + my_h)*PW + my_w0 + 1;

    const char* inb = (const char*)in;
    const char* wtb = (const char*)wt;

    f32x4 acc[4][4];
#pragma unroll
    for (int a=0;a<4;++a)
#pragma unroll
        for (int b=0;b<4;++b) acc[a][b] = (f32x4){0.f,0.f,0.f,0.f};

#pragma unroll
    for (int kd=0; kd<3; ++kd){
        const int dd = d + kd - 1;
        if ((unsigned)dd >= 48u) continue;
        const long rowstart = ((long)(dd*64 + h0 - 1)) * 130;
#pragma unroll
        for (int khalf=0; khalf<2; ++khalf){
            __syncthreads();
#pragma unroll
            for (int rnd=0; rnd<9; ++rnd){
                int j = rnd*4096 + tid*16;
                int q = j ^ (((j>>7)&3)<<4);
                const char* src = wtb + (long)(kd*9 + (q>>12))*8192
                                      + (long)((q>>6)&63)*128 + khalf*64 + (q&63);
                gload16(src, sA + j);
            }
#pragma unroll
            for (int rnd=0; rnd<8; ++rnd){
                int j = rnd*4096 + tid*16;
                int q = j ^ (((j>>7)&3)<<4);
                const char* src = inb + (rowstart + (q>>6))*128 + khalf*64 + (q&63);
                gload16(src, sB + j);
            }
            if (tid < 32){
                int j = 32768 + tid*16;
                int q = j ^ (((j>>7)&3)<<4);
                const char* src = inb + (rowstart + (q>>6))*128 + khalf*64 + (q&63);
                gload16(src, sB + j);
            }
            __syncthreads();
#pragma unroll
            for (int kh=0; kh<3; ++kh){
                const int hh = my_h + kh - 1;
                if ((unsigned)hh >= 64u) continue;
                const int rr = (wave>>1) + kh;
#pragma unroll
                for (int kw=0; kw<3; ++kw){
                    const int tap_rel = kh*3 + kw;
                    bf16x8 Af[4], Bf[4];
#pragma unroll
                    for (int t=0;t<4;++t){
                        int qa = tap_rel*4096 + (t*16+ll)*64 + kg*16;
                        Af[t] = *(const bf16x8*)(sA + (qa ^ (((qa>>7)&3)<<4)));
                    }
#pragma unroll
                    for (int vt=0; vt<4; ++vt){
                        int vrel = rr*130 + my_w0 + vt*16 + ll + kw;
                        int qb = vrel*64 + kg*16;
                        Bf[vt] = *(const bf16x8*)(sB + (qb ^ (((qb>>7)&3)<<4)));
                    }
#pragma unroll
                    for (int vt=0; vt<4; ++vt)
#pragma unroll
                        for (int t=0; t<4; ++t)
                            acc[t][vt] = __builtin_amdgcn_mfma_f32_16x16x32_bf16(Af[t], Bf[vt], acc[t][vt], 0,0,0);
                }
            }
        }
    }

    if (AUX){
        bf16x8 Aa[2][4], Ba[2][4];
#pragma unroll
        for (int half=0; half<2; ++half){
            const int ko = half*32 + kg*8;
#pragma unroll
            for (int t=0;t<4;++t)
                Aa[half][t] = *(const bf16x8*)(auxw + (t*16+ll)*64 + ko);
#pragma unroll
            for (int vt=0; vt<4; ++vt)
                Ba[half][vt] = *(const bf16x8*)(aux + (pvb + vt*16 + ll)*64 + ko);
        }
#pragma unroll
        for (int half=0; half<2; ++half)
#pragma unroll
            for (int vt=0; vt<4; ++vt)
#pragma unroll
                for (int t=0;t<4;++t)
                    acc[t][vt] = __builtin_amdgcn_mfma_f32_16x16x32_bf16(Aa[half][t], Ba[half][vt], acc[t][vt], 0,0,0);
    }

#pragma unroll
    for (int vt=0; vt<4; ++vt){
        unsigned short* op = out + (pvb + vt*16 + ll)*64 + kg*4;
#pragma unroll
        for (int t=0;t<4;++t){
            float r0 = acc[t][vt][0], r1 = acc[t][vt][1], r2 = acc[t][vt][2], r3 = acc[t][vt][3];
            if (RELU){ r0=fmaxf(r0,0.f); r1=fmaxf(r1,0.f); r2=fmaxf(r2,0.f); r3=fmaxf(r3,0.f); }
            unsigned int lo = (unsigned)f2bf(r0) | ((unsigned)f2bf(r1)<<16);
            unsigned int hi = (unsigned)f2bf(r2) | ((unsigned)f2bf(r3)<<16);
            u32x2v q = {lo, hi};
            *(u32x2v*)(op + t*16) = q;
        }
    }
}

// ============ FUSED residual chain: x <- relu(M4·relu(M3·...relu(M0·x))) ============
// One global read + one global write; inter-stage channel redistribution via
// per-wave 8KB LDS tile (XOR swizzle col^=(row&7)<<4; wave-local, no barriers).
__global__ __launch_bounds__(256,3) void k_chain(const unsigned short* __restrict__ in,
        const unsigned short* __restrict__ Mt, unsigned short* __restrict__ out){
    __shared__ __align__(16) char sX[4][8192];
    const int lane = threadIdx.x & 63;
    const int wave = threadIdx.x >> 6;
    const int ll = lane & 15;
    const int kg = lane >> 4;
    const long vb = (long)blockIdx.x*256 + wave*64;
    char* myL = sX[wave];

    bf16x8 B[2][4];
#pragma unroll
    for (int half=0; half<2; ++half){
        const int ko = half*32 + kg*8;
#pragma unroll
        for (int vt=0; vt<4; ++vt)
            B[half][vt] = *(const bf16x8*)(in + (vb+vt*16+ll)*64 + ko);
    }

#pragma unroll
    for (int s=0; s<5; ++s){
        const unsigned short* wt = Mt + s*4096;
        bf16x8 A[2][4];
#pragma unroll
        for (int half=0; half<2; ++half){
            const int ko = half*32 + kg*8;
#pragma unroll
            for (int t=0;t<4;++t)
                A[half][t] = *(const bf16x8*)(wt + (t*16+ll)*64 + ko);
        }
        f32x4 acc[4][4];
#pragma unroll
        for (int a=0;a<4;++a)
#pragma unroll
            for (int b=0;b<4;++b) acc[a][b] = (f32x4){0.f,0.f,0.f,0.f};
#pragma unroll
        for (int half=0; half<2; ++half)
#pragma unroll
            for (int vt=0; vt<4; ++vt)
#pragma unroll
                for (int t=0;t<4;++t)
                    acc[t][vt] = __builtin_amdgcn_mfma_f32_16x16x32_bf16(A[half][t], B[half][vt], acc[t][vt], 0,0,0);

        if (s < 4){
            // relu+pack -> LDS (swizzled), then reload B-fragments
#pragma unroll
            for (int vt=0; vt<4; ++vt){
                const int row = vt*16 + ll;
                const int sw = (row & 7) << 4;
#pragma unroll
                for (int t=0;t<4;++t){
                    float r0 = fmaxf(acc[t][vt][0],0.f), r1 = fmaxf(acc[t][vt][1],0.f);
                    float r2 = fmaxf(acc[t][vt][2],0.f), r3 = fmaxf(acc[t][vt][3],0.f);
                    unsigned int lo = (unsigned)f2bf(r0) | ((unsigned)f2bf(r1)<<16);
                    unsigned int hi = (unsigned)f2bf(r2) | ((unsigned)f2bf(r3)<<16);
                    u32x2v q = {lo, hi};
                    int colb = kg*8 + t*32;
                    *(u32x2v*)(myL + row*128 + (colb ^ sw)) = q;
                }
            }
#pragma unroll
            for (int half=0; half<2; ++half){
#pragma unroll
                for (int vt=0; vt<4; ++vt){
                    const int row = vt*16 + ll;
                    const int sw = (row & 7) << 4;
                    int colb = half*64 + kg*16;
                    B[half][vt] = *(const bf16x8*)(myL + row*128 + (colb ^ sw));
                }
            }
        } else {
#pragma unroll
            for (int vt=0; vt<4; ++vt){
                unsigned short* op = out + (vb+vt*16+ll)*64 + kg*4;
#pragma unroll
                for (int t=0;t<4;++t){
                    float r0 = fmaxf(acc[t][vt][0],0.f), r1 = fmaxf(acc[t][vt][1],0.f);
                    float r2 = fmaxf(acc[t][vt][2],0.f), r3 = fmaxf(acc[t][vt][3],0.f);
                    unsigned int lo = (unsigned)f2bf(r0) | ((unsigned)f2bf(r1)<<16);
                    unsigned int hi = (unsigned)f2bf(r2) | ((unsigned)f2bf(r3)<<16);
                    u32x2v q = {lo, hi};
                    *(u32x2v*)(op + t*16) = q;
                }
            }
        }
    }
}

// ============ head stage 1: t[tap][pv] = sum_co in[pv][co]*wc2[co][tap] ============
__global__ __launch_bounds__(256) void k_headt(const unsigned short* __restrict__ in,
        const unsigned short* __restrict__ wt2, float* __restrict__ t){
    const int lane = threadIdx.x & 63;
    const int wave = threadIdx.x >> 6;
    const int ll = lane & 15;
    const int kg = lane >> 4;
    const long vb = (long)blockIdx.x*256 + wave*64;

    f32x4 acc[2][4];
#pragma unroll
    for (int a=0;a<2;++a)
#pragma unroll
        for (int b=0;b<4;++b) acc[a][b] = (f32x4){0.f,0.f,0.f,0.f};

#pragma unroll
    for (int khalf=0; khalf<2; ++khalf){
        const int ko = khalf*32 + kg*8;
        bf16x8 afr[2];
#pragma unroll
        for (int tl=0;tl<2;++tl)
            afr[tl] = *(const bf16x8*)(wt2 + (tl*16+ll)*64 + ko);
#pragma unroll
        for (int vt=0; vt<4; ++vt){
            bf16x8 bfr = *(const bf16x8*)(in + (vb+vt*16+ll)*64 + ko);
#pragma unroll
            for (int tl=0;tl<2;++tl)
                acc[tl][vt] = __builtin_amdgcn_mfma_f32_16x16x32_bf16(afr[tl], bfr, acc[tl][vt], 0,0,0);
        }
    }
#pragma unroll
    for (int vt=0; vt<4; ++vt){
        long vx = vb + vt*16 + ll;
#pragma unroll
        for (int tl=0;tl<2;++tl){
#pragma unroll
            for (int r=0;r<4;++r){
                int tap = tl*16 + kg*4 + r;
                if (tap < 27) t[(long)tap*PVOL + vx] = acc[tl][vt][r];
            }
        }
    }
}

// ============ head stage 2 ============
__global__ __launch_bounds__(256) void k_heads(const float* __restrict__ t,
        const float* __restrict__ bias, float* __restrict__ out){
    int v = blockIdx.x*256 + threadIdx.x;
    int ww = v & 127; int h = (v>>7)&63; int d = v>>13;
    long p = (long)(d*64+h)*PW + ww + 1;
    float s = bias[0];
#pragma unroll
    for (int kd=0;kd<3;++kd){
#pragma unroll
      for (int kh=0;kh<3;++kh){
#pragma unroll
        for (int kw=0;kw<3;++kw){
            const int tap = (kd*3+kh)*3+kw;
            const long dvp = (long)((kd-1)*64 + (kh-1))*PW + (kw-1);
            bool ok = ((unsigned)(d+kd-1)<48u) && ((unsigned)(h+kh-1)<64u);
            long va = ok ? (p + dvp) : p;
            float x = t[(long)tap*PVOL + va];
            s += ok ? x : 0.f;
        }
      }
    }
    out[v] = s;
}

// ============ pool stage 1: S3 cell sums ============
__global__ __launch_bounds__(256) void k_pool3(const unsigned short* __restrict__ in,
                                               float* __restrict__ S3){
    __shared__ float sm[32*68];
    int tid = threadIdx.x;
    int cg = tid & 7, part = tid >> 3;
    int cell = blockIdx.x;
    int Z = cell >> 8, Y = (cell >> 4) & 15, X = cell & 15;
    float a[8];
#pragma unroll
    for (int j=0;j<8;++j) a[j]=0.f;
#pragma unroll
    for (int j=0;j<3;++j){
        int i = part*3 + j;
        int di = i >> 5, rem = i & 31, hi = rem >> 3, wi = rem & 7;
        long p = ((long)((3*Z+di)*64 + 4*Y+hi))*PW + 8*X+wi + 1;
        u32x4v q = *(const u32x4v*)(in + p*64 + cg*8);
#pragma unroll
        for (int e=0;e<4;++e){ a[e*2] += bflo(q[e]); a[e*2+1] += bfhi(q[e]); }
    }
#pragma unroll
    for (int j=0;j<8;++j) sm[part*68 + cg*8 + j] = a[j];
    __syncthreads();
    if (tid < 64){
        float s=0.f;
        for (int r=0;r<32;++r) s += sm[r*68 + tid];
        S3[tid*4096 + cell] = s;
    }
}

// ============ p2 sums from S3 ============
__global__ __launch_bounds__(256) void k_pool2(const float* __restrict__ S3,
                                               float* __restrict__ P2){
    int idx = blockIdx.x*256 + threadIdx.x;
    int cell = idx & 511; int c = idx >> 9;
    int z = cell >> 6, y = (cell >> 3) & 7, x = cell & 7;
    const float* b = S3 + c*4096;
    float s = 0.f;
#pragma unroll
    for (int a2=0;a2<2;++a2)
#pragma unroll
        for (int b2=0;b2<2;++b2)
#pragma unroll
            for (int e=0;e<2;++e)
                s += b[((2*z+a2)<<8) + ((2*y+b2)<<4) + (2*x+e)];
    P2[c*512 + cell] = s;
}

// ============ g + gc from S3 ============
__global__ void k_gcm(const float* __restrict__ S3, const float* __restrict__ wp0,
                      float* __restrict__ gc){
    __shared__ float sm[4][64];
    __shared__ float sg[64];
    int tid = threadIdx.x;
    int c = tid & 63, part = tid >> 6;
    float s = 0.f;
    const float* row = S3 + c*4096 + part*1024;
    for (int i=0;i<1024;i+=4){
        f32x4 q = *(const f32x4*)(row + i);
        s += q[0]+q[1]+q[2]+q[3];
    }
    sm[part][c] = s;
    __syncthreads();
    if (tid < 64){
        sg[tid] = (sm[0][tid]+sm[1][tid]+sm[2][tid]+sm[3][tid]) * (1.0f/(float)VOL);
    }
    __syncthreads();
    if (tid < 64){
        float g=0.f;
        for (int ci=0;ci<64;++ci) g += wp0[tid*64+ci]*sg[ci];
        gc[tid] = g;
    }
}

// ============ p4 sums ============
__global__ __launch_bounds__(256) void k_pool4(const unsigned short* __restrict__ in,
                                               float* __restrict__ P4){
    __shared__ float sm[32*68];
    int tid = threadIdx.x;
    int cg = tid & 7, part = (tid >> 3) & 3, slot = tid >> 5;
    int cell = blockIdx.x*8 + slot;
    int z = cell / 800; int rem = cell - z*800; int y = rem / 25; int x = rem - y*25;
    int a2 = part >> 1, b2 = part & 1;
    float a[8];
#pragma unroll
    for (int j=0;j<8;++j) a[j]=0.f;
#pragma unroll
    for (int e=0;e<5;++e){
        long p = ((long)((2*z+a2)*64 + 2*y+b2))*PW + 5*x+e + 1;
        u32x4v q = *(const u32x4v*)(in + p*64 + cg*8);
#pragma unroll
        for (int k=0;k<4;++k){ a[k*2] += bflo(q[k]); a[k*2+1] += bfhi(q[k]); }
    }
#pragma unroll
    for (int j=0;j<8;++j) sm[(slot*4+part)*68 + cg*8 + j] = a[j];
    __syncthreads();
#pragma unroll
    for (int r=0;r<2;++r){
        int o = r*256 + tid;
        int c = o >> 3, s = o & 7;
        float v = sm[(s*4+0)*68 + c] + sm[(s*4+1)*68 + c]
                + sm[(s*4+2)*68 + c] + sm[(s*4+3)*68 + c];
        P4[(long)c*19200 + blockIdx.x*8 + s] = v;
    }
}

// ============ 1x1 conv fp32 on pooled SUMS ============
__global__ void k_conv1(const float* __restrict__ in, const float* __restrict__ wt,
                        float* __restrict__ out, int vol, float scale){
    int v = blockIdx.x*256 + threadIdx.x;
    if (v >= vol) return;
    float acc[64];
#pragma unroll
    for (int i=0;i<64;++i) acc[i]=0.f;
    for (int ci=0; ci<64; ++ci){
        float xv = in[ci*vol + v];
        const float* wr = wt + ci*64;
#pragma unroll
        for (int co=0; co<64; ++co) acc[co] = fmaf(wr[co], xv, acc[co]);
    }
    float* op = out + (long)v*64;
#pragma unroll
    for (int q=0;q<16;++q){
        f32x4 t = {acc[q*4]*scale, acc[q*4+1]*scale, acc[q*4+2]*scale, acc[q*4+3]*scale};
        *(f32x4*)(op + q*4) = t;
    }
}

// ============ trilinear gather ============
__device__ __forceinline__ void tri_setup(int d,int h,int w,int gd,int gh,int gw,
                                          int* o, float* wt){
    float fz = (d+0.5f)*((float)gd/(float)DD) - 0.5f;
    float fy = (h+0.5f)*((float)gh/(float)HH) - 0.5f;
    float fx = (w+0.5f)*((float)gw/(float)WW) - 0.5f;
    float z0f = floorf(fz), y0f = floorf(fy), x0f = floorf(fx);
    float tz = fz - z0f, ty = fy - y0f, tx = fx - x0f;
    int z0 = (int)z0f, y0 = (int)y0f, x0 = (int)x0f;
    int z1 = z0+1, y1 = y0+1, x1 = x0+1;
    z0 = min(max(z0,0),gd-1); z1 = min(max(z1,0),gd-1);
    y0 = min(max(y0,0),gh-1); y1 = min(max(y1,0),gh-1);
    x0 = min(max(x0,0),gw-1); x1 = min(max(x1,0),gw-1);
    o[0] = (z0*gh+y0)*gw+x0; wt[0] = (1-tz)*(1-ty)*(1-tx);
    o[1] = (z0*gh+y0)*gw+x1; wt[1] = (1-tz)*(1-ty)*tx;
    o[2] = (z0*gh+y1)*gw+x0; wt[2] = (1-tz)*ty*(1-tx);
    o[3] = (z0*gh+y1)*gw+x1; wt[3] = (1-tz)*ty*tx;
    o[4] = (z1*gh+y0)*gw+x0; wt[4] = tz*(1-ty)*(1-tx);
    o[5] = (z1*gh+y0)*gw+x1; wt[5] = tz*(1-ty)*tx;
    o[6] = (z1*gh+y1)*gw+x0; wt[6] = tz*ty*(1-tx);
    o[7] = (z1*gh+y1)*gw+x1; wt[7] = tz*ty*tx;
}

// out = relu((xc + 0.25*(gc + up(p2)+up(p3)+up(p4)))/2)
// 1024-thread blocks: each block covers 1024 consecutive voxels -> 4KB
// contiguous per channel-stream (HBM page locality for the fp32 store)
__global__ __launch_bounds__(1024) void k_combine(
        const unsigned short* __restrict__ xc, const float* __restrict__ gc,
        const float* __restrict__ p2, const float* __restrict__ p3,
        const float* __restrict__ p4, float* __restrict__ xout,
        unsigned short* __restrict__ xv){
    int tid = threadIdx.x;
    long v = (long)blockIdx.x*1024 + tid;
    int w = v & 127; int h = (v>>7)&63; int d = v>>13;
    long p = (long)(d*64+h)*PW + w + 1;
    int o2[8], o3[8], o4[8];
    float w2_[8], w3_[8], w4_[8];
    tri_setup(d,h,w, 8,8,8,    o2, w2_);
    tri_setup(d,h,w, 16,16,16, o3, w3_);
    tri_setup(d,h,w, 24,32,25, o4, w4_);
#pragma unroll
    for (int half=0; half<2; ++half){
        float res[32];
#pragma unroll
        for (int j=0;j<32;++j) res[j] = gc[half*32+j];
#pragma unroll
        for (int t=0;t<8;++t){
            const float* b2 = p2 + (long)o2[t]*64 + half*32;
#pragma unroll
            for (int q=0;q<8;++q){
                f32x4 x4 = *(const f32x4*)(b2 + q*4);
                res[q*4+0] = fmaf(w2_[t], x4[0], res[q*4+0]);
                res[q*4+1] = fmaf(w2_[t], x4[1], res[q*4+1]);
                res[q*4+2] = fmaf(w2_[t], x4[2], res[q*4+2]);
                res[q*4+3] = fmaf(w2_[t], x4[3], res[q*4+3]);
            }
        }
#pragma unroll
        for (int t=0;t<8;++t){
            const float* b3 = p3 + (long)o3[t]*64 + half*32;
#pragma unroll
            for (int q=0;q<8;++q){
                f32x4 x4 = *(const f32x4*)(b3 + q*4);
                res[q*4+0] = fmaf(w3_[t], x4[0], res[q*4+0]);
                res[q*4+1] = fmaf(w3_[t], x4[1], res[q*4+1]);
                res[q*4+2] = fmaf(w3_[t], x4[2], res[q*4+2]);
                res[q*4+3] = fmaf(w3_[t], x4[3], res[q*4+3]);
            }
        }
#pragma unroll
        for (int t=0;t<8;++t){
            const float* b4 = p4 + (long)o4[t]*64 + half*32;
#pragma unroll
            for (int q=0;q<8;++q){
                f32x4 x4 = *(const f32x4*)(b4 + q*4);
                res[q*4+0] = fmaf(w4_[t], x4[0], res[q*4+0]);
                res[q*4+1] = fmaf(w4_[t], x4[1], res[q*4+1]);
                res[q*4+2] = fmaf(w4_[t], x4[2], res[q*4+2]);
                res[q*4+3] = fmaf(w4_[t], x4[3], res[q*4+3]);
            }
        }
        const u32x4v* xq = (const u32x4v*)(xc + p*64 + half*32);
#pragma unroll
        for (int q=0;q<4;++q){
            u32x4v qv = xq[q];
            unsigned int pk[4];
#pragma unroll
            for (int e=0;e<4;++e){
                int j = q*8 + e*2;
                float r0 = fmaxf((bflo(qv[e]) + 0.25f*res[j])*0.5f, 0.f);
                float r1 = fmaxf((bfhi(qv[e]) + 0.25f*res[j+1])*0.5f, 0.f);
                xout[(long)(half*32+j)*VOL + v]   = r0;
                xout[(long)(half*32+j+1)*VOL + v] = r1;
                pk[e] = (unsigned)f2bf(r0) | ((unsigned)f2bf(r1)<<16);
            }
            u32x4v pq = {pk[0],pk[1],pk[2],pk[3]};
            *(u32x4v*)(xv + p*64 + half*32 + q*8) = pq;
        }
    }
}

// ================= workspace layout (bytes) =================
constexpr long RPV = GUARD + PVBYTES + GUARD;
constexpr long OFF_PV0R = 0;
constexpr long OFF_PV1R = RPV;
constexpr long OFF_WA1 = 2*RPV;
constexpr long OFF_WA2 = OFF_WA1 + 221184;
constexpr long OFF_WC1 = OFF_WA2 + 221184;
constexpr long OFF_NIN = OFF_WC1 + 221184;
constexpr long OFF_MT  = OFF_NIN + 8192;
constexpr long OFF_WT2 = OFF_MT + 40960;
constexpr long OFF_WPT = OFF_WT2 + 4096;
constexpr long OFF_GC  = OFF_WPT + 49152;
constexpr long OFF_P2  = OFF_GC + 256;
constexpr long OFF_P2C = OFF_P2 + 131072;
constexpr long OFF_S3  = OFF_P2C + 131072;
constexpr long OFF_P3C = OFF_S3 + 1048576;
constexpr long OFF_P4  = OFF_P3C + 1048576;
constexpr long OFF_P4C = OFF_P4 + 4915200;
// end ~= 115.4 MB

extern "C" void kernel_launch(void* const* d_in, const int* in_sizes, int n_in,
                              void* d_out, int out_size, void* d_ws, size_t ws_size,
                              hipStream_t stream) {
    const float* fvl  = (const float*)d_in[0];
    const float* w_a1 = (const float*)d_in[1];
    const float* w_a2 = (const float*)d_in[2];
    const float* wnin = (const float*)d_in[3];
    const float* w1s  = (const float*)d_in[4];
    const float* w2s  = (const float*)d_in[5];
    const float* wp0  = (const float*)d_in[6];
    const float* wp1  = (const float*)d_in[7];
    const float* wp2  = (const float*)d_in[8];
    const float* wp3  = (const float*)d_in[9];
    const float* wc1  = (const float*)d_in[10];
    const float* wc2  = (const float*)d_in[11];
    const float* bc   = (const float*)d_in[12];

    char* ws = (char*)d_ws;
    unsigned short* PV0  = (unsigned short*)(ws + OFF_PV0R + GUARD);
    unsigned short* PV1  = (unsigned short*)(ws + OFF_PV1R + GUARD);
    unsigned short* wa1t = (unsigned short*)(ws + OFF_WA1);
    unsigned short* wa2t = (unsigned short*)(ws + OFF_WA2);
    unsigned short* wc1t = (unsigned short*)(ws + OFF_WC1);
    unsigned short* nint = (unsigned short*)(ws + OFF_NIN);
    unsigned short* Mt   = (unsigned short*)(ws + OFF_MT);
    unsigned short* wt2  = (unsigned short*)(ws + OFF_WT2);
    float* wpt  = (float*)(ws + OFF_WPT);
    float* gc   = (float*)(ws + OFF_GC);
    float* p2   = (float*)(ws + OFF_P2);
    float* p2c  = (float*)(ws + OFF_P2C);
    float* S3   = (float*)(ws + OFF_S3);
    float* p3c  = (float*)(ws + OFF_P3C);
    float* p4   = (float*)(ws + OFF_P4);
    float* p4c  = (float*)(ws + OFF_P4C);

    float* Xout = (float*)d_out;
    float* Cout = Xout + (long)NC*VOL;
    float* Tbuf = (float*)PV0;

    const int GBR = VOL/256;     // 1536
    const int GBP = PVOL/256;    // 1560

    hipMemsetAsync(PV0, 0, PVBYTES, stream);
    hipMemsetAsync(PV1, 0, PVBYTES, stream);

    k_wprep3<<<(27*64*64+255)/256,256,0,stream>>>(w_a1, wa1t);
    k_wprep3<<<(27*64*64+255)/256,256,0,stream>>>(w_a2, wa2t);
    k_wprep3<<<(27*64*64+255)/256,256,0,stream>>>(wc1, wc1t);
    k_wprep1<<<16,256,0,stream>>>(wnin, nint);
    k_wprep2<<<8,256,0,stream>>>(wc2, wt2);
    k_fuse_res<<<80,256,0,stream>>>(w1s, w2s, Mt);
    k_transpose1<<<16,256,0,stream>>>(wp1, wpt + 0*4096);
    k_transpose1<<<16,256,0,stream>>>(wp2, wpt + 1*4096);
    k_transpose1<<<16,256,0,stream>>>(wp3, wpt + 2*4096);
    k_tobf16v<<<VOL/64,256,0,stream>>>(fvl, PV0);

    // stage A/B: conv3 chain
    k_conv3m<false,false><<<GBR,256,0,stream>>>(PV0, wa1t, nullptr, nullptr, PV1);
    k_conv3m<true,false><<<GBR,256,0,stream>>>(PV1, wa2t, PV0, nint, PV0);

    // stage C: fused 5-stage residual chain PV0 -> PV1 (one kernel)
    k_chain<<<GBP,256,0,stream>>>(PV0, Mt, PV1);

    // stage D: pool pyramid
    k_pool3<<<4096,256,0,stream>>>(PV1, S3);
    k_gcm<<<1,256,0,stream>>>(S3, wp0, gc);
    k_pool2<<<128,256,0,stream>>>(S3, p2);
    k_pool4<<<2400,256,0,stream>>>(PV1, p4);
    k_conv1<<<2,256,0,stream>>>(p2, wpt + 0*4096, p2c, 512,   1.0f/768.0f);
    k_conv1<<<16,256,0,stream>>>(S3, wpt + 1*4096, p3c, 4096, 1.0f/96.0f);
    k_conv1<<<75,256,0,stream>>>(p4, wpt + 2*4096, p4c, 19200, 1.0f/20.0f);

    // combine: Xout + padded bf16 x into PV0
    k_combine<<<VOL/1024,1024,0,stream>>>(PV1, gc, p2c, p3c, p4c, Xout, PV0);

    // head
    k_conv3m<false,true><<<GBR,256,0,stream>>>(PV0, wc1t, nullptr, nullptr, PV1);
    k_headt<<<GBP,256,0,stream>>>(PV1, wt2, Tbuf);
    k_heads<<<GBR,256,0,stream>>>(Tbuf, bc, Cout);
}

// Round 11
// 615.354 us; speedup vs baseline: 2.6733x; 1.1052x over previous
//
#include <hip/hip_runtime.h>
#include <math.h>

#define DD 48
#define HH 64
#define WW 128
#define VOL (DD*HH*WW)     // 393216 real voxels
#define PW 130             // padded W
#define PROWS (DD*HH)      // 3072 rows
#define PVOL (PROWS*PW)    // 399360 padded voxels
#define PVBYTES ((long)PVOL*64*2) // 51,118,080 bytes per padded bf16 volume
#define GUARD 16640L       // one padded row guard each side
#define NC 64

typedef __attribute__((ext_vector_type(8))) short bf16x8;
typedef __attribute__((ext_vector_type(4))) float f32x4;
typedef __attribute__((ext_vector_type(4))) unsigned int u32x4v;
typedef __attribute__((ext_vector_type(2))) unsigned int u32x2v;

__device__ __forceinline__ float bflo(unsigned int u){
    union { unsigned int i; float f; } x; x.i = u<<16; return x.f; }
__device__ __forceinline__ float bfhi(unsigned int u){
    union { unsigned int i; float f; } x; x.i = u & 0xffff0000u; return x.f; }
__device__ __forceinline__ float bf2f(unsigned short u){
    union { unsigned int i; float f; } x; x.i = ((unsigned int)u)<<16; return x.f; }
__device__ __forceinline__ unsigned short f2bf(float f){
    union { float f; unsigned int i; } x; x.f = f;
    unsigned int i = x.i;
    return (unsigned short)((i + 0x7fffu + ((i>>16)&1u)) >> 16);  // RNE
}

__device__ __forceinline__ void gload16(const void* g, void* l){
    __builtin_amdgcn_global_load_lds(
        (const __attribute__((address_space(1))) void*)g,
        (__attribute__((address_space(3))) void*)l, 16, 0, 0);
}

// ================= weight prep =================

__global__ void k_wprep3(const float* __restrict__ src, unsigned short* __restrict__ dst){
    int idx = blockIdx.x*256 + threadIdx.x;
    if (idx >= 27*64*64) return;
    int ci = idx & 63; int t = idx >> 6; int co = t & 63; int k = t >> 6;
    dst[idx] = f2bf(src[(co*64+ci)*27 + k]);
}

__global__ void k_wprep1(const float* __restrict__ src, unsigned short* __restrict__ dst){
    int idx = blockIdx.x*256 + threadIdx.x;
    if (idx >= 4096) return;
    dst[idx] = f2bf(src[idx]);
}

__global__ void k_wprep2(const float* __restrict__ src, unsigned short* __restrict__ dst){
    int idx = blockIdx.x*256 + threadIdx.x;
    if (idx >= 32*64) return;
    int co = idx & 63; int row = idx >> 6;
    float v = (row < 27) ? src[co*27 + row] : 0.f;
    dst[row*64 + co] = f2bf(v);
}

__global__ void k_fuse_res(const float* __restrict__ w1, const float* __restrict__ w2,
                           unsigned short* __restrict__ mt){
    int idx = blockIdx.x*256 + threadIdx.x;
    if (idx >= 5*4096) return;
    int i = idx >> 12; int r = idx & 4095;
    int co = r >> 6; int ci = r & 63;
    const float* W1 = w1 + i*4096;
    const float* W2 = w2 + i*4096;
    float m = W1[co*64+ci];
    for (int k=0;k<64;++k) m += W2[co*64+k]*W1[k*64+ci];
    mt[idx] = f2bf(m);
}

__global__ void k_transpose1(const float* __restrict__ src, float* __restrict__ dst){
    int idx = blockIdx.x*256 + threadIdx.x;
    if (idx >= 4096) return;
    int ci = idx >> 6; int co = idx & 63;
    dst[idx] = src[co*64+ci];
}

// ============ zero the pad columns (w=-1, w=128) of both padded volumes ============
// 12,288 segments x 128B = 1.5MB (replaces 102MB of full-volume memsets; halo
// rows staged-but-never-computed may stay garbage)
__global__ __launch_bounds__(256) void k_zeropad(unsigned short* __restrict__ pv0,
                                                 unsigned short* __restrict__ pv1){
    int idx = blockIdx.x*256 + threadIdx.x;      // 98,304 = 12,288 seg x 8 parts
    int seg = idx >> 3, part = idx & 7;
    int vol = seg / 6144; int r2 = seg - vol*6144;
    int row = r2 >> 1; int col = (r2 & 1) ? 129 : 0;
    long boff = ((long)row*130 + col)*128 + part*16;
    u32x4v z = {0,0,0,0};
    char* base = (char*)(vol ? pv1 : pv0);
    *(u32x4v*)(base + boff) = z;
}

// ============ fvl [64][VOL] fp32 -> padded [PVOL][64] bf16 (LDS transpose) ============
__global__ __launch_bounds__(256) void k_tobf16v(const float* __restrict__ src,
                                                 unsigned short* __restrict__ dst){
    __shared__ unsigned short lds[64*66];
    int tid = threadIdx.x;
    long vbase = (long)blockIdx.x*64;
    int d = (int)(vbase >> 13);
    int h = (int)((vbase >> 7) & 63);
    int w0 = (int)(vbase & 127);
    long pbase = ((long)(d*64+h)*PW + w0 + 1);
    int v = tid & 63;
    int cg = tid >> 6;
#pragma unroll
    for (int k=0;k<16;++k){
        int ci = cg*16 + k;
        lds[v*66 + ci] = f2bf(src[(long)ci*VOL + vbase + v]);
    }
    __syncthreads();
#pragma unroll
    for (int it=0; it<2; ++it){
        int chunk = it*256 + tid;
        int vv = chunk >> 3, gp = chunk & 7;
        const unsigned short* s = lds + vv*66 + gp*8;
        unsigned int w0_ = (unsigned)s[0] | ((unsigned)s[1]<<16);
        unsigned int w1_ = (unsigned)s[2] | ((unsigned)s[3]<<16);
        unsigned int w2_ = (unsigned)s[4] | ((unsigned)s[5]<<16);
        unsigned int w3_ = (unsigned)s[6] | ((unsigned)s[7]<<16);
        u32x4v q = {w0_,w1_,w2_,w3_};
        *(u32x4v*)(dst + (pbase+vv)*64 + gp*8) = q;
    }
}

// ============ MFMA conv3x3x3: LDS-staged via global_load_lds (R7, unchanged) ============
template<bool AUX, bool RELU>
__global__ __launch_bounds__(256,2) void k_conv3m(
    const unsigned short* __restrict__ in, const unsigned short* __restrict__ wt,
    const unsigned short* __restrict__ aux, const unsigned short* __restrict__ auxw,
    unsigned short* __restrict__ out)
{
    __shared__ __align__(16) char sA[36864];
    __shared__ __align__(16) char sB[33280];

    const int tid  = threadIdx.x;
    const int lane = tid & 63;
    const int wave = tid >> 6;
    const int ll = lane & 15;
    const int kg = lane >> 4;
    const int bid = blockIdx.x;
    const int wid = ((bid & 7) * 192) + (bid >> 3);
    const int vbr = wid*256;
    const int d  = vbr >> 13;
    const int h0 = (vbr >> 7) & 63;
    const int my_h  = h0 + (wave >> 1);
    const int my_w0 = (wave & 1) * 64;
    const long pvb = (long)(d*64 + my_h)*PW + my_w0 + 1;

    const char* inb = (const char*)in;
    const char* wtb = (const char*)wt;

    f32x4 acc[4][4];
#pragma unroll
    for (int a=0;a<4;++a)
#pragma unroll
        for (int b=0;b<4;++b) acc[a][b] = (f32x4){0.f,0.f,0.f,0.f};

#pragma unroll
    for (int kd=0; kd<3; ++kd){
        const int dd = d + kd - 1;
        if ((unsigned)dd >= 48u) continue;
        const long rowstart = ((long)(dd*64 + h0 - 1)) * 130;
#pragma unroll
        for (int khalf=0; khalf<2; ++khalf){
            __syncthreads();
#pragma unroll
            for (int rnd=0; rnd<9; ++rnd){
                int j = rnd*4096 + tid*16;
                int q = j ^ (((j>>7)&3)<<4);
                const char* src = wtb + (long)(kd*9 + (q>>12))*8192
                                      + (long)((q>>6)&63)*128 + khalf*64 + (q&63);
                gload16(src, sA + j);
            }
#pragma unroll
            for (int rnd=0; rnd<8; ++rnd){
                int j = rnd*4096 + tid*16;
                int q = j ^ (((j>>7)&3)<<4);
                const char* src = inb + (rowstart + (q>>6))*128 + khalf*64 + (q&63);
                gload16(src, sB + j);
            }
            if (tid < 32){
                int j = 32768 + tid*16;
                int q = j ^ (((j>>7)&3)<<4);
                const char* src = inb + (rowstart + (q>>6))*128 + khalf*64 + (q&63);
                gload16(src, sB + j);
            }
            __syncthreads();
#pragma unroll
            for (int kh=0; kh<3; ++kh){
                const int hh = my_h + kh - 1;
                if ((unsigned)hh >= 64u) continue;
                const int rr = (wave>>1) + kh;
#pragma unroll
                for (int kw=0; kw<3; ++kw){
                    const int tap_rel = kh*3 + kw;
                    bf16x8 Af[4], Bf[4];
#pragma unroll
                    for (int t=0;t<4;++t){
                        int qa = tap_rel*4096 + (t*16+ll)*64 + kg*16;
                        Af[t] = *(const bf16x8*)(sA + (qa ^ (((qa>>7)&3)<<4)));
                    }
#pragma unroll
                    for (int vt=0; vt<4; ++vt){
                        int vrel = rr*130 + my_w0 + vt*16 + ll + kw;
                        int qb = vrel*64 + kg*16;
                        Bf[vt] = *(const bf16x8*)(sB + (qb ^ (((qb>>7)&3)<<4)));
                    }
#pragma unroll
                    for (int vt=0; vt<4; ++vt)
#pragma unroll
                        for (int t=0; t<4; ++t)
                            acc[t][vt] = __builtin_amdgcn_mfma_f32_16x16x32_bf16(Af[t], Bf[vt], acc[t][vt], 0,0,0);
                }
            }
        }
    }

    if (AUX){
        bf16x8 Aa[2][4], Ba[2][4];
#pragma unroll
        for (int half=0; half<2; ++half){
            const int ko = half*32 + kg*8;
#pragma unroll
            for (int t=0;t<4;++t)
                Aa[half][t] = *(const bf16x8*)(auxw + (t*16+ll)*64 + ko);
#pragma unroll
            for (int vt=0; vt<4; ++vt)
                Ba[half][vt] = *(const bf16x8*)(aux + (pvb + vt*16 + ll)*64 + ko);
        }
#pragma unroll
        for (int half=0; half<2; ++half)
#pragma unroll
            for (int vt=0; vt<4; ++vt)
#pragma unroll
                for (int t=0;t<4;++t)
                    acc[t][vt] = __builtin_amdgcn_mfma_f32_16x16x32_bf16(Aa[half][t], Ba[half][vt], acc[t][vt], 0,0,0);
    }

#pragma unroll
    for (int vt=0; vt<4; ++vt){
        unsigned short* op = out + (pvb + vt*16 + ll)*64 + kg*4;
#pragma unroll
        for (int t=0;t<4;++t){
            float r0 = acc[t][vt][0], r1 = acc[t][vt][1], r2 = acc[t][vt][2], r3 = acc[t][vt][3];
            if (RELU){ r0=fmaxf(r0,0.f); r1=fmaxf(r1,0.f); r2=fmaxf(r2,0.f); r3=fmaxf(r3,0.f); }
            unsigned int lo = (unsigned)f2bf(r0) | ((unsigned)f2bf(r1)<<16);
            unsigned int hi = (unsigned)f2bf(r2) | ((unsigned)f2bf(r3)<<16);
            u32x2v q = {lo, hi};
            *(u32x2v*)(op + t*16) = q;
        }
    }
}

// ============ FUSED residual chain (R9, unchanged) ============
__global__ __launch_bounds__(256,3) void k_chain(const unsigned short* __restrict__ in,
        const unsigned short* __restrict__ Mt, unsigned short* __restrict__ out){
    __shared__ __align__(16) char sX[4][8192];
    const int lane = threadIdx.x & 63;
    const int wave = threadIdx.x >> 6;
    const int ll = lane & 15;
    const int kg = lane >> 4;
    const long vb = (long)blockIdx.x*256 + wave*64;
    char* myL = sX[wave];

    bf16x8 B[2][4];
#pragma unroll
    for (int half=0; half<2; ++half){
        const int ko = half*32 + kg*8;
#pragma unroll
        for (int vt=0; vt<4; ++vt)
            B[half][vt] = *(const bf16x8*)(in + (vb+vt*16+ll)*64 + ko);
    }

#pragma unroll
    for (int s=0; s<5; ++s){
        const unsigned short* wt = Mt + s*4096;
        bf16x8 A[2][4];
#pragma unroll
        for (int half=0; half<2; ++half){
            const int ko = half*32 + kg*8;
#pragma unroll
            for (int t=0;t<4;++t)
                A[half][t] = *(const bf16x8*)(wt + (t*16+ll)*64 + ko);
        }
        f32x4 acc[4][4];
#pragma unroll
        for (int a=0;a<4;++a)
#pragma unroll
            for (int b=0;b<4;++b) acc[a][b] = (f32x4){0.f,0.f,0.f,0.f};
#pragma unroll
        for (int half=0; half<2; ++half)
#pragma unroll
            for (int vt=0; vt<4; ++vt)
#pragma unroll
                for (int t=0;t<4;++t)
                    acc[t][vt] = __builtin_amdgcn_mfma_f32_16x16x32_bf16(A[half][t], B[half][vt], acc[t][vt], 0,0,0);

        if (s < 4){
#pragma unroll
            for (int vt=0; vt<4; ++vt){
                const int row = vt*16 + ll;
                const int sw = (row & 7) << 4;
#pragma unroll
                for (int t=0;t<4;++t){
                    float r0 = fmaxf(acc[t][vt][0],0.f), r1 = fmaxf(acc[t][vt][1],0.f);
                    float r2 = fmaxf(acc[t][vt][2],0.f), r3 = fmaxf(acc[t][vt][3],0.f);
                    unsigned int lo = (unsigned)f2bf(r0) | ((unsigned)f2bf(r1)<<16);
                    unsigned int hi = (unsigned)f2bf(r2) | ((unsigned)f2bf(r3)<<16);
                    u32x2v q = {lo, hi};
                    int colb = kg*8 + t*32;
                    *(u32x2v*)(myL + row*128 + (colb ^ sw)) = q;
                }
            }
#pragma unroll
            for (int half=0; half<2; ++half){
#pragma unroll
                for (int vt=0; vt<4; ++vt){
                    const int row = vt*16 + ll;
                    const int sw = (row & 7) << 4;
                    int colb = half*64 + kg*16;
                    B[half][vt] = *(const bf16x8*)(myL + row*128 + (colb ^ sw));
                }
            }
        } else {
#pragma unroll
            for (int vt=0; vt<4; ++vt){
                unsigned short* op = out + (vb+vt*16+ll)*64 + kg*4;
#pragma unroll
                for (int t=0;t<4;++t){
                    float r0 = fmaxf(acc[t][vt][0],0.f), r1 = fmaxf(acc[t][vt][1],0.f);
                    float r2 = fmaxf(acc[t][vt][2],0.f), r3 = fmaxf(acc[t][vt][3],0.f);
                    unsigned int lo = (unsigned)f2bf(r0) | ((unsigned)f2bf(r1)<<16);
                    unsigned int hi = (unsigned)f2bf(r2) | ((unsigned)f2bf(r3)<<16);
                    u32x2v q = {lo, hi};
                    *(u32x2v*)(op + t*16) = q;
                }
            }
        }
    }
}

// ============ head stage 1 (unchanged) ============
__global__ __launch_bounds__(256) void k_headt(const unsigned short* __restrict__ in,
        const unsigned short* __restrict__ wt2, float* __restrict__ t){
    const int lane = threadIdx.x & 63;
    const int wave = threadIdx.x >> 6;
    const int ll = lane & 15;
    const int kg = lane >> 4;
    const long vb = (long)blockIdx.x*256 + wave*64;

    f32x4 acc[2][4];
#pragma unroll
    for (int a=0;a<2;++a)
#pragma unroll
        for (int b=0;b<4;++b) acc[a][b] = (f32x4){0.f,0.f,0.f,0.f};

#pragma unroll
    for (int khalf=0; khalf<2; ++khalf){
        const int ko = khalf*32 + kg*8;
        bf16x8 afr[2];
#pragma unroll
        for (int tl=0;tl<2;++tl)
            afr[tl] = *(const bf16x8*)(wt2 + (tl*16+ll)*64 + ko);
#pragma unroll
        for (int vt=0; vt<4; ++vt){
            bf16x8 bfr = *(const bf16x8*)(in + (vb+vt*16+ll)*64 + ko);
#pragma unroll
            for (int tl=0;tl<2;++tl)
                acc[tl][vt] = __builtin_amdgcn_mfma_f32_16x16x32_bf16(afr[tl], bfr, acc[tl][vt], 0,0,0);
        }
    }
#pragma unroll
    for (int vt=0; vt<4; ++vt){
        long vx = vb + vt*16 + ll;
#pragma unroll
        for (int tl=0;tl<2;++tl){
#pragma unroll
            for (int r=0;r<4;++r){
                int tap = tl*16 + kg*4 + r;
                if (tap < 27) t[(long)tap*PVOL + vx] = acc[tl][vt][r];
            }
        }
    }
}

// ============ head stage 2 (unchanged) ============
__global__ __launch_bounds__(256) void k_heads(const float* __restrict__ t,
        const float* __restrict__ bias, float* __restrict__ out){
    int v = blockIdx.x*256 + threadIdx.x;
    int ww = v & 127; int h = (v>>7)&63; int d = v>>13;
    long p = (long)(d*64+h)*PW + ww + 1;
    float s = bias[0];
#pragma unroll
    for (int kd=0;kd<3;++kd){
#pragma unroll
      for (int kh=0;kh<3;++kh){
#pragma unroll
        for (int kw=0;kw<3;++kw){
            const int tap = (kd*3+kh)*3+kw;
            const long dvp = (long)((kd-1)*64 + (kh-1))*PW + (kw-1);
            bool ok = ((unsigned)(d+kd-1)<48u) && ((unsigned)(h+kh-1)<64u);
            long va = ok ? (p + dvp) : p;
            float x = t[(long)tap*PVOL + va];
            s += ok ? x : 0.f;
        }
      }
    }
    out[v] = s;
}

// ============ pool stage 1: S3 cell sums (unchanged) ============
__global__ __launch_bounds__(256) void k_pool3(const unsigned short* __restrict__ in,
                                               float* __restrict__ S3){
    __shared__ float sm[32*68];
    int tid = threadIdx.x;
    int cg = tid & 7, part = tid >> 3;
    int cell = blockIdx.x;
    int Z = cell >> 8, Y = (cell >> 4) & 15, X = cell & 15;
    float a[8];
#pragma unroll
    for (int j=0;j<8;++j) a[j]=0.f;
#pragma unroll
    for (int j=0;j<3;++j){
        int i = part*3 + j;
        int di = i >> 5, rem = i & 31, hi = rem >> 3, wi = rem & 7;
        long p = ((long)((3*Z+di)*64 + 4*Y+hi))*PW + 8*X+wi + 1;
        u32x4v q = *(const u32x4v*)(in + p*64 + cg*8);
#pragma unroll
        for (int e=0;e<4;++e){ a[e*2] += bflo(q[e]); a[e*2+1] += bfhi(q[e]); }
    }
#pragma unroll
    for (int j=0;j<8;++j) sm[part*68 + cg*8 + j] = a[j];
    __syncthreads();
    if (tid < 64){
        float s=0.f;
        for (int r=0;r<32;++r) s += sm[r*68 + tid];
        S3[tid*4096 + cell] = s;
    }
}

// ============ p2 sums from S3 (unchanged) ============
__global__ __launch_bounds__(256) void k_pool2(const float* __restrict__ S3,
                                               float* __restrict__ P2){
    int idx = blockIdx.x*256 + threadIdx.x;
    int cell = idx & 511; int c = idx >> 9;
    int z = cell >> 6, y = (cell >> 3) & 7, x = cell & 7;
    const float* b = S3 + c*4096;
    float s = 0.f;
#pragma unroll
    for (int a2=0;a2<2;++a2)
#pragma unroll
        for (int b2=0;b2<2;++b2)
#pragma unroll
            for (int e=0;e<2;++e)
                s += b[((2*z+a2)<<8) + ((2*y+b2)<<4) + (2*x+e)];
    P2[c*512 + cell] = s;
}

// ============ g + gc from S3 (unchanged) ============
__global__ void k_gcm(const float* __restrict__ S3, const float* __restrict__ wp0,
                      float* __restrict__ gc){
    __shared__ float sm[4][64];
    __shared__ float sg[64];
    int tid = threadIdx.x;
    int c = tid & 63, part = tid >> 6;
    float s = 0.f;
    const float* row = S3 + c*4096 + part*1024;
    for (int i=0;i<1024;i+=4){
        f32x4 q = *(const f32x4*)(row + i);
        s += q[0]+q[1]+q[2]+q[3];
    }
    sm[part][c] = s;
    __syncthreads();
    if (tid < 64){
        sg[tid] = (sm[0][tid]+sm[1][tid]+sm[2][tid]+sm[3][tid]) * (1.0f/(float)VOL);
    }
    __syncthreads();
    if (tid < 64){
        float g=0.f;
        for (int ci=0;ci<64;++ci) g += wp0[tid*64+ci]*sg[ci];
        gc[tid] = g;
    }
}

// ============ p4 sums (unchanged) ============
__global__ __launch_bounds__(256) void k_pool4(const unsigned short* __restrict__ in,
                                               float* __restrict__ P4){
    __shared__ float sm[32*68];
    int tid = threadIdx.x;
    int cg = tid & 7, part = (tid >> 3) & 3, slot = tid >> 5;
    int cell = blockIdx.x*8 + slot;
    int z = cell / 800; int rem = cell - z*800; int y = rem / 25; int x = rem - y*25;
    int a2 = part >> 1, b2 = part & 1;
    float a[8];
#pragma unroll
    for (int j=0;j<8;++j) a[j]=0.f;
#pragma unroll
    for (int e=0;e<5;++e){
        long p = ((long)((2*z+a2)*64 + 2*y+b2))*PW + 5*x+e + 1;
        u32x4v q = *(const u32x4v*)(in + p*64 + cg*8);
#pragma unroll
        for (int k=0;k<4;++k){ a[k*2] += bflo(q[k]); a[k*2+1] += bfhi(q[k]); }
    }
#pragma unroll
    for (int j=0;j<8;++j) sm[(slot*4+part)*68 + cg*8 + j] = a[j];
    __syncthreads();
#pragma unroll
    for (int r=0;r<2;++r){
        int o = r*256 + tid;
        int c = o >> 3, s = o & 7;
        float v = sm[(s*4+0)*68 + c] + sm[(s*4+1)*68 + c]
                + sm[(s*4+2)*68 + c] + sm[(s*4+3)*68 + c];
        P4[(long)c*19200 + blockIdx.x*8 + s] = v;
    }
}

// ============ 1x1 conv fp32 on pooled SUMS (unchanged) ============
__global__ void k_conv1(const float* __restrict__ in, const float* __restrict__ wt,
                        float* __restrict__ out, int vol, float scale){
    int v = blockIdx.x*256 + threadIdx.x;
    if (v >= vol) return;
    float acc[64];
#pragma unroll
    for (int i=0;i<64;++i) acc[i]=0.f;
    for (int ci=0; ci<64; ++ci){
        float xv = in[ci*vol + v];
        const float* wr = wt + ci*64;
#pragma unroll
        for (int co=0; co<64; ++co) acc[co] = fmaf(wr[co], xv, acc[co]);
    }
    float* op = out + (long)v*64;
#pragma unroll
    for (int q=0;q<16;++q){
        f32x4 t = {acc[q*4]*scale, acc[q*4+1]*scale, acc[q*4+2]*scale, acc[q*4+3]*scale};
        *(f32x4*)(op + q*4) = t;
    }
}

// ============ trilinear gather ============
__device__ __forceinline__ void tri_setup(int d,int h,int w,int gd,int gh,int gw,
                                          int* o, float* wt){
    float fz = (d+0.5f)*((float)gd/(float)DD) - 0.5f;
    float fy = (h+0.5f)*((float)gh/(float)HH) - 0.5f;
    float fx = (w+0.5f)*((float)gw/(float)WW) - 0.5f;
    float z0f = floorf(fz), y0f = floorf(fy), x0f = floorf(fx);
    float tz = fz - z0f, ty = fy - y0f, tx = fx - x0f;
    int z0 = (int)z0f, y0 = (int)y0f, x0 = (int)x0f;
    int z1 = z0+1, y1 = y0+1, x1 = x0+1;
    z0 = min(max(z0,0),gd-1); z1 = min(max(z1,0),gd-1);
    y0 = min(max(y0,0),gh-1); y1 = min(max(y1,0),gh-1);
    x0 = min(max(x0,0),gw-1); x1 = min(max(x1,0),gw-1);
    o[0] = (z0*gh+y0)*gw+x0; wt[0] = (1-tz)*(1-ty)*(1-tx);
    o[1] = (z0*gh+y0)*gw+x1; wt[1] = (1-tz)*(1-ty)*tx;
    o[2] = (z0*gh+y1)*gw+x0; wt[2] = (1-tz)*ty*(1-tx);
    o[3] = (z0*gh+y1)*gw+x1; wt[3] = (1-tz)*ty*tx;
    o[4] = (z1*gh+y0)*gw+x0; wt[4] = tz*(1-ty)*(1-tx);
    o[5] = (z1*gh+y0)*gw+x1; wt[5] = tz*(1-ty)*tx;
    o[6] = (z1*gh+y1)*gw+x0; wt[6] = tz*ty*(1-tx);
    o[7] = (z1*gh+y1)*gw+x1; wt[7] = tz*ty*tx;
}

// out = relu((xc + 0.25*(gc + up(p2)+up(p3)+up(p4)))/2)
// 256-thread blocks + XCD swizzle (contiguous 1/8 volume per XCD) +
// nontemporal fp32 stores (write-once stream; keep L2 for gather tables)
__global__ __launch_bounds__(256) void k_combine(
        const unsigned short* __restrict__ xc, const float* __restrict__ gc,
        const float* __restrict__ p2, const float* __restrict__ p3,
        const float* __restrict__ p4, float* __restrict__ xout,
        unsigned short* __restrict__ xv){
    int tid = threadIdx.x;
    const int bid = blockIdx.x;
    const int wid = ((bid & 7) * 192) + (bid >> 3);   // 1536 blocks, bijective
    long v = (long)wid*256 + tid;
    int w = v & 127; int h = (v>>7)&63; int d = v>>13;
    long p = (long)(d*64+h)*PW + w + 1;
    int o2[8], o3[8], o4[8];
    float w2_[8], w3_[8], w4_[8];
    tri_setup(d,h,w, 8,8,8,    o2, w2_);
    tri_setup(d,h,w, 16,16,16, o3, w3_);
    tri_setup(d,h,w, 24,32,25, o4, w4_);
#pragma unroll
    for (int half=0; half<2; ++half){
        float res[32];
#pragma unroll
        for (int j=0;j<32;++j) res[j] = gc[half*32+j];
#pragma unroll
        for (int t=0;t<8;++t){
            const float* b2 = p2 + (long)o2[t]*64 + half*32;
#pragma unroll
            for (int q=0;q<8;++q){
                f32x4 x4 = *(const f32x4*)(b2 + q*4);
                res[q*4+0] = fmaf(w2_[t], x4[0], res[q*4+0]);
                res[q*4+1] = fmaf(w2_[t], x4[1], res[q*4+1]);
                res[q*4+2] = fmaf(w2_[t], x4[2], res[q*4+2]);
                res[q*4+3] = fmaf(w2_[t], x4[3], res[q*4+3]);
            }
        }
#pragma unroll
        for (int t=0;t<8;++t){
            const float* b3 = p3 + (long)o3[t]*64 + half*32;
#pragma unroll
            for (int q=0;q<8;++q){
                f32x4 x4 = *(const f32x4*)(b3 + q*4);
                res[q*4+0] = fmaf(w3_[t], x4[0], res[q*4+0]);
                res[q*4+1] = fmaf(w3_[t], x4[1], res[q*4+1]);
                res[q*4+2] = fmaf(w3_[t], x4[2], res[q*4+2]);
                res[q*4+3] = fmaf(w3_[t], x4[3], res[q*4+3]);
            }
        }
#pragma unroll
        for (int t=0;t<8;++t){
            const float* b4 = p4 + (long)o4[t]*64 + half*32;
#pragma unroll
            for (int q=0;q<8;++q){
                f32x4 x4 = *(const f32x4*)(b4 + q*4);
                res[q*4+0] = fmaf(w4_[t], x4[0], res[q*4+0]);
                res[q*4+1] = fmaf(w4_[t], x4[1], res[q*4+1]);
                res[q*4+2] = fmaf(w4_[t], x4[2], res[q*4+2]);
                res[q*4+3] = fmaf(w4_[t], x4[3], res[q*4+3]);
            }
        }
        const u32x4v* xq = (const u32x4v*)(xc + p*64 + half*32);
#pragma unroll
        for (int q=0;q<4;++q){
            u32x4v qv = xq[q];
            unsigned int pk[4];
#pragma unroll
            for (int e=0;e<4;++e){
                int j = q*8 + e*2;
                float r0 = fmaxf((bflo(qv[e]) + 0.25f*res[j])*0.5f, 0.f);
                float r1 = fmaxf((bfhi(qv[e]) + 0.25f*res[j+1])*0.5f, 0.f);
                __builtin_nontemporal_store(r0, &xout[(long)(half*32+j)*VOL + v]);
                __builtin_nontemporal_store(r1, &xout[(long)(half*32+j+1)*VOL + v]);
                pk[e] = (unsigned)f2bf(r0) | ((unsigned)f2bf(r1)<<16);
            }
            u32x4v pq = {pk[0],pk[1],pk[2],pk[3]};
            *(u32x4v*)(xv + p*64 + half*32 + q*8) = pq;
        }
    }
}

// ================= workspace layout (bytes) =================
constexpr long RPV = GUARD + PVBYTES + GUARD;
constexpr long OFF_PV0R = 0;
constexpr long OFF_PV1R = RPV;
constexpr long OFF_WA1 = 2*RPV;
constexpr long OFF_WA2 = OFF_WA1 + 221184;
constexpr long OFF_WC1 = OFF_WA2 + 221184;
constexpr long OFF_NIN = OFF_WC1 + 221184;
constexpr long OFF_MT  = OFF_NIN + 8192;
constexpr long OFF_WT2 = OFF_MT + 40960;
constexpr long OFF_WPT = OFF_WT2 + 4096;
constexpr long OFF_GC  = OFF_WPT + 49152;
constexpr long OFF_P2  = OFF_GC + 256;
constexpr long OFF_P2C = OFF_P2 + 131072;
constexpr long OFF_S3  = OFF_P2C + 131072;
constexpr long OFF_P3C = OFF_S3 + 1048576;
constexpr long OFF_P4  = OFF_P3C + 1048576;
constexpr long OFF_P4C = OFF_P4 + 4915200;
// end ~= 115.4 MB

extern "C" void kernel_launch(void* const* d_in, const int* in_sizes, int n_in,
                              void* d_out, int out_size, void* d_ws, size_t ws_size,
                              hipStream_t stream) {
    const float* fvl  = (const float*)d_in[0];
    const float* w_a1 = (const float*)d_in[1];
    const float* w_a2 = (const float*)d_in[2];
    const float* wnin = (const float*)d_in[3];
    const float* w1s  = (const float*)d_in[4];
    const float* w2s  = (const float*)d_in[5];
    const float* wp0  = (const float*)d_in[6];
    const float* wp1  = (const float*)d_in[7];
    const float* wp2  = (const float*)d_in[8];
    const float* wp3  = (const float*)d_in[9];
    const float* wc1  = (const float*)d_in[10];
    const float* wc2  = (const float*)d_in[11];
    const float* bc   = (const float*)d_in[12];

    char* ws = (char*)d_ws;
    unsigned short* PV0  = (unsigned short*)(ws + OFF_PV0R + GUARD);
    unsigned short* PV1  = (unsigned short*)(ws + OFF_PV1R + GUARD);
    unsigned short* wa1t = (unsigned short*)(ws + OFF_WA1);
    unsigned short* wa2t = (unsigned short*)(ws + OFF_WA2);
    unsigned short* wc1t = (unsigned short*)(ws + OFF_WC1);
    unsigned short* nint = (unsigned short*)(ws + OFF_NIN);
    unsigned short* Mt   = (unsigned short*)(ws + OFF_MT);
    unsigned short* wt2  = (unsigned short*)(ws + OFF_WT2);
    float* wpt  = (float*)(ws + OFF_WPT);
    float* gc   = (float*)(ws + OFF_GC);
    float* p2   = (float*)(ws + OFF_P2);
    float* p2c  = (float*)(ws + OFF_P2C);
    float* S3   = (float*)(ws + OFF_S3);
    float* p3c  = (float*)(ws + OFF_P3C);
    float* p4   = (float*)(ws + OFF_P4);
    float* p4c  = (float*)(ws + OFF_P4C);

    float* Xout = (float*)d_out;
    float* Cout = Xout + (long)NC*VOL;
    float* Tbuf = (float*)PV0;

    const int GBR = VOL/256;     // 1536
    const int GBP = PVOL/256;    // 1560

    // zero only the pad columns (1.5MB instead of 102MB of memset)
    k_zeropad<<<384,256,0,stream>>>(PV0, PV1);

    k_wprep3<<<(27*64*64+255)/256,256,0,stream>>>(w_a1, wa1t);
    k_wprep3<<<(27*64*64+255)/256,256,0,stream>>>(w_a2, wa2t);
    k_wprep3<<<(27*64*64+255)/256,256,0,stream>>>(wc1, wc1t);
    k_wprep1<<<16,256,0,stream>>>(wnin, nint);
    k_wprep2<<<8,256,0,stream>>>(wc2, wt2);
    k_fuse_res<<<80,256,0,stream>>>(w1s, w2s, Mt);
    k_transpose1<<<16,256,0,stream>>>(wp1, wpt + 0*4096);
    k_transpose1<<<16,256,0,stream>>>(wp2, wpt + 1*4096);
    k_transpose1<<<16,256,0,stream>>>(wp3, wpt + 2*4096);
    k_tobf16v<<<VOL/64,256,0,stream>>>(fvl, PV0);

    // stage A/B: conv3 chain
    k_conv3m<false,false><<<GBR,256,0,stream>>>(PV0, wa1t, nullptr, nullptr, PV1);
    k_conv3m<true,false><<<GBR,256,0,stream>>>(PV1, wa2t, PV0, nint, PV0);

    // stage C: fused 5-stage residual chain PV0 -> PV1 (one kernel)
    k_chain<<<GBP,256,0,stream>>>(PV0, Mt, PV1);

    // stage D: pool pyramid
    k_pool3<<<4096,256,0,stream>>>(PV1, S3);
    k_gcm<<<1,256,0,stream>>>(S3, wp0, gc);
    k_pool2<<<128,256,0,stream>>>(S3, p2);
    k_pool4<<<2400,256,0,stream>>>(PV1, p4);
    k_conv1<<<2,256,0,stream>>>(p2, wpt + 0*4096, p2c, 512,   1.0f/768.0f);
    k_conv1<<<16,256,0,stream>>>(S3, wpt + 1*4096, p3c, 4096, 1.0f/96.0f);
    k_conv1<<<75,256,0,stream>>>(p4, wpt + 2*4096, p4c, 19200, 1.0f/20.0f);

    // combine: Xout + padded bf16 x into PV0
    k_combine<<<GBR,256,0,stream>>>(PV1, gc, p2c, p3c, p4c, Xout, PV0);

    // head
    k_conv3m<false,true><<<GBR,256,0,stream>>>(PV0, wc1t, nullptr, nullptr, PV1);
    k_headt<<<GBP,256,0,stream>>>(PV1, wt2, Tbuf);
    k_heads<<<GBR,256,0,stream>>>(Tbuf, bc, Cout);
}

// Round 13
// 600.322 us; speedup vs baseline: 2.7402x; 1.0250x over previous
//
#include <hip/hip_runtime.h>
#include <math.h>

#define DD 48
#define HH 64
#define WW 128
#define VOL (DD*HH*WW)     // 393216 real voxels
#define PW 130             // padded W
#define PROWS (DD*HH)      // 3072 rows
#define PVOL (PROWS*PW)    // 399360 padded voxels
#define PVBYTES ((long)PVOL*64*2) // 51,118,080 bytes per padded bf16 volume
#define GUARD 16640L       // one padded row guard each side
#define NC 64

typedef __attribute__((ext_vector_type(8))) short bf16x8;
typedef __attribute__((ext_vector_type(4))) float f32x4;
typedef __attribute__((ext_vector_type(4))) unsigned int u32x4v;
typedef __attribute__((ext_vector_type(2))) unsigned int u32x2v;

__device__ __forceinline__ float bflo(unsigned int u){
    union { unsigned int i; float f; } x; x.i = u<<16; return x.f; }
__device__ __forceinline__ float bfhi(unsigned int u){
    union { unsigned int i; float f; } x; x.i = u & 0xffff0000u; return x.f; }
__device__ __forceinline__ float bf2f(unsigned short u){
    union { unsigned int i; float f; } x; x.i = ((unsigned int)u)<<16; return x.f; }
__device__ __forceinline__ unsigned short f2bf(float f){
    union { float f; unsigned int i; } x; x.f = f;
    unsigned int i = x.i;
    return (unsigned short)((i + 0x7fffu + ((i>>16)&1u)) >> 16);  // RNE
}

__device__ __forceinline__ void gload16(const void* g, void* l){
    __builtin_amdgcn_global_load_lds(
        (const __attribute__((address_space(1))) void*)g,
        (__attribute__((address_space(3))) void*)l, 16, 0, 0);
}

// ================= merged weight prep (one launch) =================
// FIXED partitioning (R11 bug: wprep3 got 108 blocks/weight, needs 432):
// [0,1296): wprep3 x3 (432 each) | [1296,1376): fuse_res | [1376,1392): wprep1
// [1392,1400): wprep2 | [1400,1448): transpose1 x3
__global__ void k_prep_all(
    const float* __restrict__ w_a1, const float* __restrict__ w_a2,
    const float* __restrict__ wc1,  const float* __restrict__ wnin,
    const float* __restrict__ wc2,  const float* __restrict__ w1s,
    const float* __restrict__ w2s,  const float* __restrict__ wp1,
    const float* __restrict__ wp2,  const float* __restrict__ wp3,
    unsigned short* __restrict__ wa1t, unsigned short* __restrict__ wa2t,
    unsigned short* __restrict__ wc1t, unsigned short* __restrict__ nint,
    unsigned short* __restrict__ wt2,  unsigned short* __restrict__ Mt,
    float* __restrict__ wpt)
{
    int b = blockIdx.x, tid = threadIdx.x;
    if (b < 1296){                      // [k=27][co][ci] bf16 repack x3 (432 blocks each)
        int which = b/432, bb = b - which*432;
        int idx = bb*256 + tid;
        if (idx < 27*64*64){
            const float* src = which==0 ? w_a1 : (which==1 ? w_a2 : wc1);
            unsigned short* dst = which==0 ? wa1t : (which==1 ? wa2t : wc1t);
            int ci = idx & 63; int t = idx >> 6; int co = t & 63; int k = t >> 6;
            dst[idx] = f2bf(src[(co*64+ci)*27 + k]);
        }
    } else if (b < 1376){               // M_i = W1 + W2@W1 -> bf16 (80 blocks)
        int idx = (b-1296)*256 + tid;
        int i = idx >> 12; int r = idx & 4095;
        int co = r >> 6; int ci = r & 63;
        const float* W1 = w1s + i*4096;
        const float* W2 = w2s + i*4096;
        float m = W1[co*64+ci];
        for (int k=0;k<64;++k) m += W2[co*64+k]*W1[k*64+ci];
        Mt[idx] = f2bf(m);
    } else if (b < 1392){               // nin bf16 (16 blocks)
        int idx = (b-1376)*256 + tid;
        nint[idx] = f2bf(wnin[idx]);
    } else if (b < 1400){               // head taps [32][64] bf16 (8 blocks)
        int idx = (b-1392)*256 + tid;
        int co = idx & 63; int row = idx >> 6;
        float v = (row < 27) ? wc2[co*27 + row] : 0.f;
        wt2[row*64 + co] = f2bf(v);
    } else {                            // pool-conv weight transpose x3 (48 blocks)
        int bb = b - 1400;
        int which = bb/16;
        int idx = (bb - which*16)*256 + tid;
        const float* src = which==0 ? wp1 : (which==1 ? wp2 : wp3);
        int ci = idx >> 6; int co = idx & 63;
        wpt[which*4096 + idx] = src[co*64+ci];
    }
}

// ============ zero the pad columns (w=-1, w=128) of both padded volumes ============
__global__ __launch_bounds__(256) void k_zeropad(unsigned short* __restrict__ pv0,
                                                 unsigned short* __restrict__ pv1){
    int idx = blockIdx.x*256 + threadIdx.x;      // 98,304 = 12,288 seg x 8 parts
    int seg = idx >> 3, part = idx & 7;
    int vol = seg / 6144; int r2 = seg - vol*6144;
    int row = r2 >> 1; int col = (r2 & 1) ? 129 : 0;
    long boff = ((long)row*130 + col)*128 + part*16;
    u32x4v z = {0,0,0,0};
    char* base = (char*)(vol ? pv1 : pv0);
    *(u32x4v*)(base + boff) = z;
}

// ============ fvl [64][VOL] fp32 -> padded [PVOL][64] bf16 (LDS transpose) ============
__global__ __launch_bounds__(256) void k_tobf16v(const float* __restrict__ src,
                                                 unsigned short* __restrict__ dst){
    __shared__ unsigned short lds[64*66];
    int tid = threadIdx.x;
    long vbase = (long)blockIdx.x*64;
    int d = (int)(vbase >> 13);
    int h = (int)((vbase >> 7) & 63);
    int w0 = (int)(vbase & 127);
    long pbase = ((long)(d*64+h)*PW + w0 + 1);
    int v = tid & 63;
    int cg = tid >> 6;
#pragma unroll
    for (int k=0;k<16;++k){
        int ci = cg*16 + k;
        lds[v*66 + ci] = f2bf(src[(long)ci*VOL + vbase + v]);
    }
    __syncthreads();
#pragma unroll
    for (int it=0; it<2; ++it){
        int chunk = it*256 + tid;
        int vv = chunk >> 3, gp = chunk & 7;
        const unsigned short* s = lds + vv*66 + gp*8;
        unsigned int w0_ = (unsigned)s[0] | ((unsigned)s[1]<<16);
        unsigned int w1_ = (unsigned)s[2] | ((unsigned)s[3]<<16);
        unsigned int w2_ = (unsigned)s[4] | ((unsigned)s[5]<<16);
        unsigned int w3_ = (unsigned)s[6] | ((unsigned)s[7]<<16);
        u32x4v q = {w0_,w1_,w2_,w3_};
        *(u32x4v*)(dst + (pbase+vv)*64 + gp*8) = q;
    }
}

// ============ MFMA conv3x3x3: LDS-staged via global_load_lds (R7, unchanged) ============
template<bool AUX, bool RELU>
__global__ __launch_bounds__(256,2) void k_conv3m(
    const unsigned short* __restrict__ in, const unsigned short* __restrict__ wt,
    const unsigned short* __restrict__ aux, const unsigned short* __restrict__ auxw,
    unsigned short* __restrict__ out)
{
    __shared__ __align__(16) char sA[36864];
    __shared__ __align__(16) char sB[33280];

    const int tid  = threadIdx.x;
    const int lane = tid & 63;
    const int wave = tid >> 6;
    const int ll = lane & 15;
    const int kg = lane >> 4;
    const int bid = blockIdx.x;
    const int wid = ((bid & 7) * 192) + (bid >> 3);
    const int vbr = wid*256;
    const int d  = vbr >> 13;
    const int h0 = (vbr >> 7) & 63;
    const int my_h  = h0 + (wave >> 1);
    const int my_w0 = (wave & 1) * 64;
    const long pvb = (long)(d*64 + my_h)*PW + my_w0 + 1;

    const char* inb = (const char*)in;
    const char* wtb = (const char*)wt;

    f32x4 acc[4][4];
#pragma unroll
    for (int a=0;a<4;++a)
#pragma unroll
        for (int b=0;b<4;++b) acc[a][b] = (f32x4){0.f,0.f,0.f,0.f};

#pragma unroll
    for (int kd=0; kd<3; ++kd){
        const int dd = d + kd - 1;
        if ((unsigned)dd >= 48u) continue;
        const long rowstart = ((long)(dd*64 + h0 - 1)) * 130;
#pragma unroll
        for (int khalf=0; khalf<2; ++khalf){
            __syncthreads();
#pragma unroll
            for (int rnd=0; rnd<9; ++rnd){
                int j = rnd*4096 + tid*16;
                int q = j ^ (((j>>7)&3)<<4);
                const char* src = wtb + (long)(kd*9 + (q>>12))*8192
                                      + (long)((q>>6)&63)*128 + khalf*64 + (q&63);
                gload16(src, sA + j);
            }
#pragma unroll
            for (int rnd=0; rnd<8; ++rnd){
                int j = rnd*4096 + tid*16;
                int q = j ^ (((j>>7)&3)<<4);
                const char* src = inb + (rowstart + (q>>6))*128 + khalf*64 + (q&63);
                gload16(src, sB + j);
            }
            if (tid < 32){
                int j = 32768 + tid*16;
                int q = j ^ (((j>>7)&3)<<4);
                const char* src = inb + (rowstart + (q>>6))*128 + khalf*64 + (q&63);
                gload16(src, sB + j);
            }
            __syncthreads();
#pragma unroll
            for (int kh=0; kh<3; ++kh){
                const int hh = my_h + kh - 1;
                if ((unsigned)hh >= 64u) continue;
                const int rr = (wave>>1) + kh;
#pragma unroll
                for (int kw=0; kw<3; ++kw){
                    const int tap_rel = kh*3 + kw;
                    bf16x8 Af[4], Bf[4];
#pragma unroll
                    for (int t=0;t<4;++t){
                        int qa = tap_rel*4096 + (t*16+ll)*64 + kg*16;
                        Af[t] = *(const bf16x8*)(sA + (qa ^ (((qa>>7)&3)<<4)));
                    }
#pragma unroll
                    for (int vt=0; vt<4; ++vt){
                        int vrel = rr*130 + my_w0 + vt*16 + ll + kw;
                        int qb = vrel*64 + kg*16;
                        Bf[vt] = *(const bf16x8*)(sB + (qb ^ (((qb>>7)&3)<<4)));
                    }
#pragma unroll
                    for (int vt=0; vt<4; ++vt)
#pragma unroll
                        for (int t=0; t<4; ++t)
                            acc[t][vt] = __builtin_amdgcn_mfma_f32_16x16x32_bf16(Af[t], Bf[vt], acc[t][vt], 0,0,0);
                }
            }
        }
    }

    if (AUX){
        bf16x8 Aa[2][4], Ba[2][4];
#pragma unroll
        for (int half=0; half<2; ++half){
            const int ko = half*32 + kg*8;
#pragma unroll
            for (int t=0;t<4;++t)
                Aa[half][t] = *(const bf16x8*)(auxw + (t*16+ll)*64 + ko);
#pragma unroll
            for (int vt=0; vt<4; ++vt)
                Ba[half][vt] = *(const bf16x8*)(aux + (pvb + vt*16 + ll)*64 + ko);
        }
#pragma unroll
        for (int half=0; half<2; ++half)
#pragma unroll
            for (int vt=0; vt<4; ++vt)
#pragma unroll
                for (int t=0;t<4;++t)
                    acc[t][vt] = __builtin_amdgcn_mfma_f32_16x16x32_bf16(Aa[half][t], Ba[half][vt], acc[t][vt], 0,0,0);
    }

#pragma unroll
    for (int vt=0; vt<4; ++vt){
        unsigned short* op = out + (pvb + vt*16 + ll)*64 + kg*4;
#pragma unroll
        for (int t=0;t<4;++t){
            float r0 = acc[t][vt][0], r1 = acc[t][vt][1], r2 = acc[t][vt][2], r3 = acc[t][vt][3];
            if (RELU){ r0=fmaxf(r0,0.f); r1=fmaxf(r1,0.f); r2=fmaxf(r2,0.f); r3=fmaxf(r3,0.f); }
            unsigned int lo = (unsigned)f2bf(r0) | ((unsigned)f2bf(r1)<<16);
            unsigned int hi = (unsigned)f2bf(r2) | ((unsigned)f2bf(r3)<<16);
            u32x2v q = {lo, hi};
            *(u32x2v*)(op + t*16) = q;
        }
    }
}

// ============ FUSED residual chain (R9, unchanged) ============
__global__ __launch_bounds__(256,3) void k_chain(const unsigned short* __restrict__ in,
        const unsigned short* __restrict__ Mt, unsigned short* __restrict__ out){
    __shared__ __align__(16) char sX[4][8192];
    const int lane = threadIdx.x & 63;
    const int wave = threadIdx.x >> 6;
    const int ll = lane & 15;
    const int kg = lane >> 4;
    const long vb = (long)blockIdx.x*256 + wave*64;
    char* myL = sX[wave];

    bf16x8 B[2][4];
#pragma unroll
    for (int half=0; half<2; ++half){
        const int ko = half*32 + kg*8;
#pragma unroll
        for (int vt=0; vt<4; ++vt)
            B[half][vt] = *(const bf16x8*)(in + (vb+vt*16+ll)*64 + ko);
    }

#pragma unroll
    for (int s=0; s<5; ++s){
        const unsigned short* wt = Mt + s*4096;
        bf16x8 A[2][4];
#pragma unroll
        for (int half=0; half<2; ++half){
            const int ko = half*32 + kg*8;
#pragma unroll
            for (int t=0;t<4;++t)
                A[half][t] = *(const bf16x8*)(wt + (t*16+ll)*64 + ko);
        }
        f32x4 acc[4][4];
#pragma unroll
        for (int a=0;a<4;++a)
#pragma unroll
            for (int b=0;b<4;++b) acc[a][b] = (f32x4){0.f,0.f,0.f,0.f};
#pragma unroll
        for (int half=0; half<2; ++half)
#pragma unroll
            for (int vt=0; vt<4; ++vt)
#pragma unroll
                for (int t=0;t<4;++t)
                    acc[t][vt] = __builtin_amdgcn_mfma_f32_16x16x32_bf16(A[half][t], B[half][vt], acc[t][vt], 0,0,0);

        if (s < 4){
#pragma unroll
            for (int vt=0; vt<4; ++vt){
                const int row = vt*16 + ll;
                const int sw = (row & 7) << 4;
#pragma unroll
                for (int t=0;t<4;++t){
                    float r0 = fmaxf(acc[t][vt][0],0.f), r1 = fmaxf(acc[t][vt][1],0.f);
                    float r2 = fmaxf(acc[t][vt][2],0.f), r3 = fmaxf(acc[t][vt][3],0.f);
                    unsigned int lo = (unsigned)f2bf(r0) | ((unsigned)f2bf(r1)<<16);
                    unsigned int hi = (unsigned)f2bf(r2) | ((unsigned)f2bf(r3)<<16);
                    u32x2v q = {lo, hi};
                    int colb = kg*8 + t*32;
                    *(u32x2v*)(myL + row*128 + (colb ^ sw)) = q;
                }
            }
#pragma unroll
            for (int half=0; half<2; ++half){
#pragma unroll
                for (int vt=0; vt<4; ++vt){
                    const int row = vt*16 + ll;
                    const int sw = (row & 7) << 4;
                    int colb = half*64 + kg*16;
                    B[half][vt] = *(const bf16x8*)(myL + row*128 + (colb ^ sw));
                }
            }
        } else {
#pragma unroll
            for (int vt=0; vt<4; ++vt){
                unsigned short* op = out + (vb+vt*16+ll)*64 + kg*4;
#pragma unroll
                for (int t=0;t<4;++t){
                    float r0 = fmaxf(acc[t][vt][0],0.f), r1 = fmaxf(acc[t][vt][1],0.f);
                    float r2 = fmaxf(acc[t][vt][2],0.f), r3 = fmaxf(acc[t][vt][3],0.f);
                    unsigned int lo = (unsigned)f2bf(r0) | ((unsigned)f2bf(r1)<<16);
                    unsigned int hi = (unsigned)f2bf(r2) | ((unsigned)f2bf(r3)<<16);
                    u32x2v q = {lo, hi};
                    *(u32x2v*)(op + t*16) = q;
                }
            }
        }
    }
}

// ============ head stage 1: t[tap][pv] (bf16) = sum_co in[pv][co]*wc2[co][tap] ============
__global__ __launch_bounds__(256) void k_headt(const unsigned short* __restrict__ in,
        const unsigned short* __restrict__ wt2, unsigned short* __restrict__ t){
    const int lane = threadIdx.x & 63;
    const int wave = threadIdx.x >> 6;
    const int ll = lane & 15;
    const int kg = lane >> 4;
    const long vb = (long)blockIdx.x*256 + wave*64;

    f32x4 acc[2][4];
#pragma unroll
    for (int a=0;a<2;++a)
#pragma unroll
        for (int b=0;b<4;++b) acc[a][b] = (f32x4){0.f,0.f,0.f,0.f};

#pragma unroll
    for (int khalf=0; khalf<2; ++khalf){
        const int ko = khalf*32 + kg*8;
        bf16x8 afr[2];
#pragma unroll
        for (int tl=0;tl<2;++tl)
            afr[tl] = *(const bf16x8*)(wt2 + (tl*16+ll)*64 + ko);
#pragma unroll
        for (int vt=0; vt<4; ++vt){
            bf16x8 bfr = *(const bf16x8*)(in + (vb+vt*16+ll)*64 + ko);
#pragma unroll
            for (int tl=0;tl<2;++tl)
                acc[tl][vt] = __builtin_amdgcn_mfma_f32_16x16x32_bf16(afr[tl], bfr, acc[tl][vt], 0,0,0);
        }
    }
#pragma unroll
    for (int vt=0; vt<4; ++vt){
        long vx = vb + vt*16 + ll;
#pragma unroll
        for (int tl=0;tl<2;++tl){
#pragma unroll
            for (int r=0;r<4;++r){
                int tap = tl*16 + kg*4 + r;
                if (tap < 27) t[(long)tap*PVOL + vx] = f2bf(acc[tl][vt][r]);
            }
        }
    }
}

// ============ head stage 2: out[v] = bias + sum_tap bf2f(t[tap][p+dv]) ============
__global__ __launch_bounds__(256) void k_heads(const unsigned short* __restrict__ t,
        const float* __restrict__ bias, float* __restrict__ out){
    int v = blockIdx.x*256 + threadIdx.x;
    int ww = v & 127; int h = (v>>7)&63; int d = v>>13;
    long p = (long)(d*64+h)*PW + ww + 1;
    float s = bias[0];
#pragma unroll
    for (int kd=0;kd<3;++kd){
#pragma unroll
      for (int kh=0;kh<3;++kh){
#pragma unroll
        for (int kw=0;kw<3;++kw){
            const int tap = (kd*3+kh)*3+kw;
            const long dvp = (long)((kd-1)*64 + (kh-1))*PW + (kw-1);
            bool ok = ((unsigned)(d+kd-1)<48u) && ((unsigned)(h+kh-1)<64u);
            long va = ok ? (p + dvp) : p;
            float x = bf2f(t[(long)tap*PVOL + va]);
            s += ok ? x : 0.f;
        }
      }
    }
    out[v] = s;
}

// ============ pool stage 1: S3 cell sums (unchanged) ============
__global__ __launch_bounds__(256) void k_pool3(const unsigned short* __restrict__ in,
                                               float* __restrict__ S3){
    __shared__ float sm[32*68];
    int tid = threadIdx.x;
    int cg = tid & 7, part = tid >> 3;
    int cell = blockIdx.x;
    int Z = cell >> 8, Y = (cell >> 4) & 15, X = cell & 15;
    float a[8];
#pragma unroll
    for (int j=0;j<8;++j) a[j]=0.f;
#pragma unroll
    for (int j=0;j<3;++j){
        int i = part*3 + j;
        int di = i >> 5, rem = i & 31, hi = rem >> 3, wi = rem & 7;
        long p = ((long)((3*Z+di)*64 + 4*Y+hi))*PW + 8*X+wi + 1;
        u32x4v q = *(const u32x4v*)(in + p*64 + cg*8);
#pragma unroll
        for (int e=0;e<4;++e){ a[e*2] += bflo(q[e]); a[e*2+1] += bfhi(q[e]); }
    }
#pragma unroll
    for (int j=0;j<8;++j) sm[part*68 + cg*8 + j] = a[j];
    __syncthreads();
    if (tid < 64){
        float s=0.f;
        for (int r=0;r<32;++r) s += sm[r*68 + tid];
        S3[tid*4096 + cell] = s;
    }
}

// ============ p2 sums from S3 (unchanged) ============
__global__ __launch_bounds__(256) void k_pool2(const float* __restrict__ S3,
                                               float* __restrict__ P2){
    int idx = blockIdx.x*256 + threadIdx.x;
    int cell = idx & 511; int c = idx >> 9;
    int z = cell >> 6, y = (cell >> 3) & 7, x = cell & 7;
    const float* b = S3 + c*4096;
    float s = 0.f;
#pragma unroll
    for (int a2=0;a2<2;++a2)
#pragma unroll
        for (int b2=0;b2<2;++b2)
#pragma unroll
            for (int e=0;e<2;++e)
                s += b[((2*z+a2)<<8) + ((2*y+b2)<<4) + (2*x+e)];
    P2[c*512 + cell] = s;
}

// ============ g + gc from S3 (unchanged) ============
__global__ void k_gcm(const float* __restrict__ S3, const float* __restrict__ wp0,
                      float* __restrict__ gc){
    __shared__ float sm[4][64];
    __shared__ float sg[64];
    int tid = threadIdx.x;
    int c = tid & 63, part = tid >> 6;
    float s = 0.f;
    const float* row = S3 + c*4096 + part*1024;
    for (int i=0;i<1024;i+=4){
        f32x4 q = *(const f32x4*)(row + i);
        s += q[0]+q[1]+q[2]+q[3];
    }
    sm[part][c] = s;
    __syncthreads();
    if (tid < 64){
        sg[tid] = (sm[0][tid]+sm[1][tid]+sm[2][tid]+sm[3][tid]) * (1.0f/(float)VOL);
    }
    __syncthreads();
    if (tid < 64){
        float g=0.f;
        for (int ci=0;ci<64;++ci) g += wp0[tid*64+ci]*sg[ci];
        gc[tid] = g;
    }
}

// ============ p4 sums (unchanged) ============
__global__ __launch_bounds__(256) void k_pool4(const unsigned short* __restrict__ in,
                                               float* __restrict__ P4){
    __shared__ float sm[32*68];
    int tid = threadIdx.x;
    int cg = tid & 7, part = (tid >> 3) & 3, slot = tid >> 5;
    int cell = blockIdx.x*8 + slot;
    int z = cell / 800; int rem = cell - z*800; int y = rem / 25; int x = rem - y*25;
    int a2 = part >> 1, b2 = part & 1;
    float a[8];
#pragma unroll
    for (int j=0;j<8;++j) a[j]=0.f;
#pragma unroll
    for (int e=0;e<5;++e){
        long p = ((long)((2*z+a2)*64 + 2*y+b2))*PW + 5*x+e + 1;
        u32x4v q = *(const u32x4v*)(in + p*64 + cg*8);
#pragma unroll
        for (int k=0;k<4;++k){ a[k*2] += bflo(q[k]); a[k*2+1] += bfhi(q[k]); }
    }
#pragma unroll
    for (int j=0;j<8;++j) sm[(slot*4+part)*68 + cg*8 + j] = a[j];
    __syncthreads();
#pragma unroll
    for (int r=0;r<2;++r){
        int o = r*256 + tid;
        int c = o >> 3, s = o & 7;
        float v = sm[(s*4+0)*68 + c] + sm[(s*4+1)*68 + c]
                + sm[(s*4+2)*68 + c] + sm[(s*4+3)*68 + c];
        P4[(long)c*19200 + blockIdx.x*8 + s] = v;
    }
}

// ============ 1x1 conv fp32 on pooled SUMS (unchanged) ============
__global__ void k_conv1(const float* __restrict__ in, const float* __restrict__ wt,
                        float* __restrict__ out, int vol, float scale){
    int v = blockIdx.x*256 + threadIdx.x;
    if (v >= vol) return;
    float acc[64];
#pragma unroll
    for (int i=0;i<64;++i) acc[i]=0.f;
    for (int ci=0; ci<64; ++ci){
        float xv = in[ci*vol + v];
        const float* wr = wt + ci*64;
#pragma unroll
        for (int co=0; co<64; ++co) acc[co] = fmaf(wr[co], xv, acc[co]);
    }
    float* op = out + (long)v*64;
#pragma unroll
    for (int q=0;q<16;++q){
        f32x4 t = {acc[q*4]*scale, acc[q*4+1]*scale, acc[q*4+2]*scale, acc[q*4+3]*scale};
        *(f32x4*)(op + q*4) = t;
    }
}

// ============ trilinear gather ============
__device__ __forceinline__ void tri_setup(int d,int h,int w,int gd,int gh,int gw,
                                          int* o, float* wt){
    float fz = (d+0.5f)*((float)gd/(float)DD) - 0.5f;
    float fy = (h+0.5f)*((float)gh/(float)HH) - 0.5f;
    float fx = (w+0.5f)*((float)gw/(float)WW) - 0.5f;
    float z0f = floorf(fz), y0f = floorf(fy), x0f = floorf(fx);
    float tz = fz - z0f, ty = fy - y0f, tx = fx - x0f;
    int z0 = (int)z0f, y0 = (int)y0f, x0 = (int)x0f;
    int z1 = z0+1, y1 = y0+1, x1 = x0+1;
    z0 = min(max(z0,0),gd-1); z1 = min(max(z1,0),gd-1);
    y0 = min(max(y0,0),gh-1); y1 = min(max(y1,0),gh-1);
    x0 = min(max(x0,0),gw-1); x1 = min(max(x1,0),gw-1);
    o[0] = (z0*gh+y0)*gw+x0; wt[0] = (1-tz)*(1-ty)*(1-tx);
    o[1] = (z0*gh+y0)*gw+x1; wt[1] = (1-tz)*(1-ty)*tx;
    o[2] = (z0*gh+y1)*gw+x0; wt[2] = (1-tz)*ty*(1-tx);
    o[3] = (z0*gh+y1)*gw+x1; wt[3] = (1-tz)*ty*tx;
    o[4] = (z1*gh+y0)*gw+x0; wt[4] = tz*(1-ty)*(1-tx);
    o[5] = (z1*gh+y0)*gw+x1; wt[5] = tz*(1-ty)*tx;
    o[6] = (z1*gh+y1)*gw+x0; wt[6] = tz*ty*(1-tx);
    o[7] = (z1*gh+y1)*gw+x1; wt[7] = tz*ty*tx;
}

// out = relu((xc + 0.25*(gc + up(p2)+up(p3)+up(p4)))/2)
// SPLIT-HALF: 3072 blocks x 256 threads; thread = (voxel, channel-half).
__global__ __launch_bounds__(256) void k_combine(
        const unsigned short* __restrict__ xc, const float* __restrict__ gc,
        const float* __restrict__ p2, const float* __restrict__ p3,
        const float* __restrict__ p4, float* __restrict__ xout,
        unsigned short* __restrict__ xv){
    int tid = threadIdx.x;
    const int bid = blockIdx.x;
    const int wid = ((bid & 7) * 384) + (bid >> 3);   // 3072 blocks, bijective
    const int half = tid >> 7;
    long v = (long)wid*128 + (tid & 127);
    int w = v & 127; int h = (v>>7)&63; int d = v>>13;
    long p = (long)(d*64+h)*PW + w + 1;
    int o2[8], o3[8], o4[8];
    float w2_[8], w3_[8], w4_[8];
    tri_setup(d,h,w, 8,8,8,    o2, w2_);
    tri_setup(d,h,w, 16,16,16, o3, w3_);
    tri_setup(d,h,w, 24,32,25, o4, w4_);

    float res[32];
#pragma unroll
    for (int j=0;j<32;++j) res[j] = gc[half*32+j];
#pragma unroll
    for (int t=0;t<8;++t){
        const float* b2 = p2 + (long)o2[t]*64 + half*32;
#pragma unroll
        for (int q=0;q<8;++q){
            f32x4 x4 = *(const f32x4*)(b2 + q*4);
            res[q*4+0] = fmaf(w2_[t], x4[0], res[q*4+0]);
            res[q*4+1] = fmaf(w2_[t], x4[1], res[q*4+1]);
            res[q*4+2] = fmaf(w2_[t], x4[2], res[q*4+2]);
            res[q*4+3] = fmaf(w2_[t], x4[3], res[q*4+3]);
        }
    }
#pragma unroll
    for (int t=0;t<8;++t){
        const float* b3 = p3 + (long)o3[t]*64 + half*32;
#pragma unroll
        for (int q=0;q<8;++q){
            f32x4 x4 = *(const f32x4*)(b3 + q*4);
            res[q*4+0] = fmaf(w3_[t], x4[0], res[q*4+0]);
            res[q*4+1] = fmaf(w3_[t], x4[1], res[q*4+1]);
            res[q*4+2] = fmaf(w3_[t], x4[2], res[q*4+2]);
            res[q*4+3] = fmaf(w3_[t], x4[3], res[q*4+3]);
        }
    }
#pragma unroll
    for (int t=0;t<8;++t){
        const float* b4 = p4 + (long)o4[t]*64 + half*32;
#pragma unroll
        for (int q=0;q<8;++q){
            f32x4 x4 = *(const f32x4*)(b4 + q*4);
            res[q*4+0] = fmaf(w4_[t], x4[0], res[q*4+0]);
            res[q*4+1] = fmaf(w4_[t], x4[1], res[q*4+1]);
            res[q*4+2] = fmaf(w4_[t], x4[2], res[q*4+2]);
            res[q*4+3] = fmaf(w4_[t], x4[3], res[q*4+3]);
        }
    }
    const u32x4v* xq = (const u32x4v*)(xc + p*64 + half*32);
#pragma unroll
    for (int q=0;q<4;++q){
        u32x4v qv = xq[q];
        unsigned int pk[4];
#pragma unroll
        for (int e=0;e<4;++e){
            int j = q*8 + e*2;
            float r0 = fmaxf((bflo(qv[e]) + 0.25f*res[j])*0.5f, 0.f);
            float r1 = fmaxf((bfhi(qv[e]) + 0.25f*res[j+1])*0.5f, 0.f);
            __builtin_nontemporal_store(r0, &xout[(long)(half*32+j)*VOL + v]);
            __builtin_nontemporal_store(r1, &xout[(long)(half*32+j+1)*VOL + v]);
            pk[e] = (unsigned)f2bf(r0) | ((unsigned)f2bf(r1)<<16);
        }
        u32x4v pq = {pk[0],pk[1],pk[2],pk[3]};
        *(u32x4v*)(xv + p*64 + half*32 + q*8) = pq;
    }
}

// ================= workspace layout (bytes) =================
constexpr long RPV = GUARD + PVBYTES + GUARD;
constexpr long OFF_PV0R = 0;
constexpr long OFF_PV1R = RPV;
constexpr long OFF_WA1 = 2*RPV;
constexpr long OFF_WA2 = OFF_WA1 + 221184;
constexpr long OFF_WC1 = OFF_WA2 + 221184;
constexpr long OFF_NIN = OFF_WC1 + 221184;
constexpr long OFF_MT  = OFF_NIN + 8192;
constexpr long OFF_WT2 = OFF_MT + 40960;
constexpr long OFF_WPT = OFF_WT2 + 4096;
constexpr long OFF_GC  = OFF_WPT + 49152;
constexpr long OFF_P2  = OFF_GC + 256;
constexpr long OFF_P2C = OFF_P2 + 131072;
constexpr long OFF_S3  = OFF_P2C + 131072;
constexpr long OFF_P3C = OFF_S3 + 1048576;
constexpr long OFF_P4  = OFF_P3C + 1048576;
constexpr long OFF_P4C = OFF_P4 + 4915200;
// end ~= 115.4 MB

extern "C" void kernel_launch(void* const* d_in, const int* in_sizes, int n_in,
                              void* d_out, int out_size, void* d_ws, size_t ws_size,
                              hipStream_t stream) {
    const float* fvl  = (const float*)d_in[0];
    const float* w_a1 = (const float*)d_in[1];
    const float* w_a2 = (const float*)d_in[2];
    const float* wnin = (const float*)d_in[3];
    const float* w1s  = (const float*)d_in[4];
    const float* w2s  = (const float*)d_in[5];
    const float* wp0  = (const float*)d_in[6];
    const float* wp1  = (const float*)d_in[7];
    const float* wp2  = (const float*)d_in[8];
    const float* wp3  = (const float*)d_in[9];
    const float* wc1  = (const float*)d_in[10];
    const float* wc2  = (const float*)d_in[11];
    const float* bc   = (const float*)d_in[12];

    char* ws = (char*)d_ws;
    unsigned short* PV0  = (unsigned short*)(ws + OFF_PV0R + GUARD);
    unsigned short* PV1  = (unsigned short*)(ws + OFF_PV1R + GUARD);
    unsigned short* wa1t = (unsigned short*)(ws + OFF_WA1);
    unsigned short* wa2t = (unsigned short*)(ws + OFF_WA2);
    unsigned short* wc1t = (unsigned short*)(ws + OFF_WC1);
    unsigned short* nint = (unsigned short*)(ws + OFF_NIN);
    unsigned short* Mt   = (unsigned short*)(ws + OFF_MT);
    unsigned short* wt2  = (unsigned short*)(ws + OFF_WT2);
    float* wpt  = (float*)(ws + OFF_WPT);
    float* gc   = (float*)(ws + OFF_GC);
    float* p2   = (float*)(ws + OFF_P2);
    float* p2c  = (float*)(ws + OFF_P2C);
    float* S3   = (float*)(ws + OFF_S3);
    float* p3c  = (float*)(ws + OFF_P3C);
    float* p4   = (float*)(ws + OFF_P4);
    float* p4c  = (float*)(ws + OFF_P4C);

    float* Xout = (float*)d_out;
    float* Cout = Xout + (long)NC*VOL;
    unsigned short* Tbuf = (unsigned short*)PV0;   // head t bf16 [27][PVOL] = 21.5MB, aliases PV0

    const int GBR = VOL/256;     // 1536
    const int GBP = PVOL/256;    // 1560

    // zero only the pad columns (1.5MB instead of 102MB of memset)
    k_zeropad<<<384,256,0,stream>>>(PV0, PV1);

    // all weight prep in ONE launch (FIXED: 432 blocks per wprep3)
    k_prep_all<<<1448,256,0,stream>>>(w_a1, w_a2, wc1, wnin, wc2, w1s, w2s,
                                      wp1, wp2, wp3,
                                      wa1t, wa2t, wc1t, nint, wt2, Mt, wpt);
    k_tobf16v<<<VOL/64,256,0,stream>>>(fvl, PV0);

    // stage A/B: conv3 chain
    k_conv3m<false,false><<<GBR,256,0,stream>>>(PV0, wa1t, nullptr, nullptr, PV1);
    k_conv3m<true,false><<<GBR,256,0,stream>>>(PV1, wa2t, PV0, nint, PV0);

    // stage C: fused 5-stage residual chain PV0 -> PV1 (one kernel)
    k_chain<<<GBP,256,0,stream>>>(PV0, Mt, PV1);

    // stage D: pool pyramid
    k_pool3<<<4096,256,0,stream>>>(PV1, S3);
    k_gcm<<<1,256,0,stream>>>(S3, wp0, gc);
    k_pool2<<<128,256,0,stream>>>(S3, p2);
    k_pool4<<<2400,256,0,stream>>>(PV1, p4);
    k_conv1<<<2,256,0,stream>>>(p2, wpt + 0*4096, p2c, 512,   1.0f/768.0f);
    k_conv1<<<16,256,0,stream>>>(S3, wpt + 1*4096, p3c, 4096, 1.0f/96.0f);
    k_conv1<<<75,256,0,stream>>>(p4, wpt + 2*4096, p4c, 19200, 1.0f/20.0f);

    // combine: Xout + padded bf16 x into PV0 (split-half, 3072 blocks)
    k_combine<<<3072,256,0,stream>>>(PV1, gc, p2c, p3c, p4c, Xout, PV0);

    // head
    k_conv3m<false,true><<<GBR,256,0,stream>>>(PV0, wc1t, nullptr, nullptr, PV1);
    k_headt<<<GBP,256,0,stream>>>(PV1, wt2, Tbuf);
    k_heads<<<GBR,256,0,stream>>>(Tbuf, bc, Cout);
}

// Round 14
// 580.920 us; speedup vs baseline: 2.8317x; 1.0334x over previous
//
#include <hip/hip_runtime.h>
#include <math.h>

#define DD 48
#define HH 64
#define WW 128
#define VOL (DD*HH*WW)     // 393216 real voxels
#define PW 130             // padded W
#define PROWS (DD*HH)      // 3072 rows
#define PVOL (PROWS*PW)    // 399360 padded voxels
#define PVBYTES ((long)PVOL*64*2) // 51,118,080 bytes per padded bf16 volume
#define GUARD 16640L       // one padded row guard each side
#define NC 64

typedef __attribute__((ext_vector_type(8))) short bf16x8;
typedef __attribute__((ext_vector_type(4))) float f32x4;
typedef __attribute__((ext_vector_type(4))) unsigned int u32x4v;
typedef __attribute__((ext_vector_type(2))) unsigned int u32x2v;

__device__ __forceinline__ float bflo(unsigned int u){
    union { unsigned int i; float f; } x; x.i = u<<16; return x.f; }
__device__ __forceinline__ float bfhi(unsigned int u){
    union { unsigned int i; float f; } x; x.i = u & 0xffff0000u; return x.f; }
__device__ __forceinline__ float bf2f(unsigned short u){
    union { unsigned int i; float f; } x; x.i = ((unsigned int)u)<<16; return x.f; }
__device__ __forceinline__ unsigned short f2bf(float f){
    union { float f; unsigned int i; } x; x.f = f;
    unsigned int i = x.i;
    return (unsigned short)((i + 0x7fffu + ((i>>16)&1u)) >> 16);  // RNE
}

__device__ __forceinline__ void gload16(const void* g, void* l){
    __builtin_amdgcn_global_load_lds(
        (const __attribute__((address_space(1))) void*)g,
        (__attribute__((address_space(3))) void*)l, 16, 0, 0);
}

// ================= merged weight prep (one launch) =================
// [0,1296): wprep3 x3 (432 each) | [1296,1376): fuse_res | [1376,1392): wprep1
// [1392,1400): wprep2 | [1400,1448): transpose1 x3
__global__ void k_prep_all(
    const float* __restrict__ w_a1, const float* __restrict__ w_a2,
    const float* __restrict__ wc1,  const float* __restrict__ wnin,
    const float* __restrict__ wc2,  const float* __restrict__ w1s,
    const float* __restrict__ w2s,  const float* __restrict__ wp1,
    const float* __restrict__ wp2,  const float* __restrict__ wp3,
    unsigned short* __restrict__ wa1t, unsigned short* __restrict__ wa2t,
    unsigned short* __restrict__ wc1t, unsigned short* __restrict__ nint,
    unsigned short* __restrict__ wt2,  unsigned short* __restrict__ Mt,
    float* __restrict__ wpt)
{
    int b = blockIdx.x, tid = threadIdx.x;
    if (b < 1296){                      // [k=27][co][ci] bf16 repack x3 (432 blocks each)
        int which = b/432, bb = b - which*432;
        int idx = bb*256 + tid;
        if (idx < 27*64*64){
            const float* src = which==0 ? w_a1 : (which==1 ? w_a2 : wc1);
            unsigned short* dst = which==0 ? wa1t : (which==1 ? wa2t : wc1t);
            int ci = idx & 63; int t = idx >> 6; int co = t & 63; int k = t >> 6;
            dst[idx] = f2bf(src[(co*64+ci)*27 + k]);
        }
    } else if (b < 1376){               // M_i = W1 + W2@W1 -> bf16 (80 blocks)
        int idx = (b-1296)*256 + tid;
        int i = idx >> 12; int r = idx & 4095;
        int co = r >> 6; int ci = r & 63;
        const float* W1 = w1s + i*4096;
        const float* W2 = w2s + i*4096;
        float m = W1[co*64+ci];
        for (int k=0;k<64;++k) m += W2[co*64+k]*W1[k*64+ci];
        Mt[idx] = f2bf(m);
    } else if (b < 1392){               // nin bf16 (16 blocks)
        int idx = (b-1376)*256 + tid;
        nint[idx] = f2bf(wnin[idx]);
    } else if (b < 1400){               // head taps [32][64] bf16 (8 blocks)
        int idx = (b-1392)*256 + tid;
        int co = idx & 63; int row = idx >> 6;
        float v = (row < 27) ? wc2[co*27 + row] : 0.f;
        wt2[row*64 + co] = f2bf(v);
    } else {                            // pool-conv weight transpose x3 (48 blocks)
        int bb = b - 1400;
        int which = bb/16;
        int idx = (bb - which*16)*256 + tid;
        const float* src = which==0 ? wp1 : (which==1 ? wp2 : wp3);
        int ci = idx >> 6; int co = idx & 63;
        wpt[which*4096 + idx] = src[co*64+ci];
    }
}

// ============ zero the pad columns (w=-1, w=128) of both padded volumes ============
__global__ __launch_bounds__(256) void k_zeropad(unsigned short* __restrict__ pv0,
                                                 unsigned short* __restrict__ pv1){
    int idx = blockIdx.x*256 + threadIdx.x;      // 98,304 = 12,288 seg x 8 parts
    int seg = idx >> 3, part = idx & 7;
    int vol = seg / 6144; int r2 = seg - vol*6144;
    int row = r2 >> 1; int col = (r2 & 1) ? 129 : 0;
    long boff = ((long)row*130 + col)*128 + part*16;
    u32x4v z = {0,0,0,0};
    char* base = (char*)(vol ? pv1 : pv0);
    *(u32x4v*)(base + boff) = z;
}

// ============ fvl [64][VOL] fp32 -> padded [PVOL][64] bf16 (LDS transpose) ============
__global__ __launch_bounds__(256) void k_tobf16v(const float* __restrict__ src,
                                                 unsigned short* __restrict__ dst){
    __shared__ unsigned short lds[64*66];
    int tid = threadIdx.x;
    long vbase = (long)blockIdx.x*64;
    int d = (int)(vbase >> 13);
    int h = (int)((vbase >> 7) & 63);
    int w0 = (int)(vbase & 127);
    long pbase = ((long)(d*64+h)*PW + w0 + 1);
    int v = tid & 63;
    int cg = tid >> 6;
#pragma unroll
    for (int k=0;k<16;++k){
        int ci = cg*16 + k;
        lds[v*66 + ci] = f2bf(src[(long)ci*VOL + vbase + v]);
    }
    __syncthreads();
#pragma unroll
    for (int it=0; it<2; ++it){
        int chunk = it*256 + tid;
        int vv = chunk >> 3, gp = chunk & 7;
        const unsigned short* s = lds + vv*66 + gp*8;
        unsigned int w0_ = (unsigned)s[0] | ((unsigned)s[1]<<16);
        unsigned int w1_ = (unsigned)s[2] | ((unsigned)s[3]<<16);
        unsigned int w2_ = (unsigned)s[4] | ((unsigned)s[5]<<16);
        unsigned int w3_ = (unsigned)s[6] | ((unsigned)s[7]<<16);
        u32x4v q = {w0_,w1_,w2_,w3_};
        *(u32x4v*)(dst + (pbase+vv)*64 + gp*8) = q;
    }
}

// ============ MFMA conv3x3x3: LDS-staged via global_load_lds (R7, unchanged) ============
template<bool AUX, bool RELU>
__global__ __launch_bounds__(256,2) void k_conv3m(
    const unsigned short* __restrict__ in, const unsigned short* __restrict__ wt,
    const unsigned short* __restrict__ aux, const unsigned short* __restrict__ auxw,
    unsigned short* __restrict__ out)
{
    __shared__ __align__(16) char sA[36864];
    __shared__ __align__(16) char sB[33280];

    const int tid  = threadIdx.x;
    const int lane = tid & 63;
    const int wave = tid >> 6;
    const int ll = lane & 15;
    const int kg = lane >> 4;
    const int bid = blockIdx.x;
    const int wid = ((bid & 7) * 192) + (bid >> 3);
    const int vbr = wid*256;
    const int d  = vbr >> 13;
    const int h0 = (vbr >> 7) & 63;
    const int my_h  = h0 + (wave >> 1);
    const int my_w0 = (wave & 1) * 64;
    const long pvb = (long)(d*64 + my_h)*PW + my_w0 + 1;

    const char* inb = (const char*)in;
    const char* wtb = (const char*)wt;

    f32x4 acc[4][4];
#pragma unroll
    for (int a=0;a<4;++a)
#pragma unroll
        for (int b=0;b<4;++b) acc[a][b] = (f32x4){0.f,0.f,0.f,0.f};

#pragma unroll
    for (int kd=0; kd<3; ++kd){
        const int dd = d + kd - 1;
        if ((unsigned)dd >= 48u) continue;
        const long rowstart = ((long)(dd*64 + h0 - 1)) * 130;
#pragma unroll
        for (int khalf=0; khalf<2; ++khalf){
            __syncthreads();
#pragma unroll
            for (int rnd=0; rnd<9; ++rnd){
                int j = rnd*4096 + tid*16;
                int q = j ^ (((j>>7)&3)<<4);
                const char* src = wtb + (long)(kd*9 + (q>>12))*8192
                                      + (long)((q>>6)&63)*128 + khalf*64 + (q&63);
                gload16(src, sA + j);
            }
#pragma unroll
            for (int rnd=0; rnd<8; ++rnd){
                int j = rnd*4096 + tid*16;
                int q = j ^ (((j>>7)&3)<<4);
                const char* src = inb + (rowstart + (q>>6))*128 + khalf*64 + (q&63);
                gload16(src, sB + j);
            }
            if (tid < 32){
                int j = 32768 + tid*16;
                int q = j ^ (((j>>7)&3)<<4);
                const char* src = inb + (rowstart + (q>>6))*128 + khalf*64 + (q&63);
                gload16(src, sB + j);
            }
            __syncthreads();
#pragma unroll
            for (int kh=0; kh<3; ++kh){
                const int hh = my_h + kh - 1;
                if ((unsigned)hh >= 64u) continue;
                const int rr = (wave>>1) + kh;
#pragma unroll
                for (int kw=0; kw<3; ++kw){
                    const int tap_rel = kh*3 + kw;
                    bf16x8 Af[4], Bf[4];
#pragma unroll
                    for (int t=0;t<4;++t){
                        int qa = tap_rel*4096 + (t*16+ll)*64 + kg*16;
                        Af[t] = *(const bf16x8*)(sA + (qa ^ (((qa>>7)&3)<<4)));
                    }
#pragma unroll
                    for (int vt=0; vt<4; ++vt){
                        int vrel = rr*130 + my_w0 + vt*16 + ll + kw;
                        int qb = vrel*64 + kg*16;
                        Bf[vt] = *(const bf16x8*)(sB + (qb ^ (((qb>>7)&3)<<4)));
                    }
#pragma unroll
                    for (int vt=0; vt<4; ++vt)
#pragma unroll
                        for (int t=0; t<4; ++t)
                            acc[t][vt] = __builtin_amdgcn_mfma_f32_16x16x32_bf16(Af[t], Bf[vt], acc[t][vt], 0,0,0);
                }
            }
        }
    }

    if (AUX){
        bf16x8 Aa[2][4], Ba[2][4];
#pragma unroll
        for (int half=0; half<2; ++half){
            const int ko = half*32 + kg*8;
#pragma unroll
            for (int t=0;t<4;++t)
                Aa[half][t] = *(const bf16x8*)(auxw + (t*16+ll)*64 + ko);
#pragma unroll
            for (int vt=0; vt<4; ++vt)
                Ba[half][vt] = *(const bf16x8*)(aux + (pvb + vt*16 + ll)*64 + ko);
        }
#pragma unroll
        for (int half=0; half<2; ++half)
#pragma unroll
            for (int vt=0; vt<4; ++vt)
#pragma unroll
                for (int t=0;t<4;++t)
                    acc[t][vt] = __builtin_amdgcn_mfma_f32_16x16x32_bf16(Aa[half][t], Ba[half][vt], acc[t][vt], 0,0,0);
    }

#pragma unroll
    for (int vt=0; vt<4; ++vt){
        unsigned short* op = out + (pvb + vt*16 + ll)*64 + kg*4;
#pragma unroll
        for (int t=0;t<4;++t){
            float r0 = acc[t][vt][0], r1 = acc[t][vt][1], r2 = acc[t][vt][2], r3 = acc[t][vt][3];
            if (RELU){ r0=fmaxf(r0,0.f); r1=fmaxf(r1,0.f); r2=fmaxf(r2,0.f); r3=fmaxf(r3,0.f); }
            unsigned int lo = (unsigned)f2bf(r0) | ((unsigned)f2bf(r1)<<16);
            unsigned int hi = (unsigned)f2bf(r2) | ((unsigned)f2bf(r3)<<16);
            u32x2v q = {lo, hi};
            *(u32x2v*)(op + t*16) = q;
        }
    }
}

// ============ HEAD: conv3(x,wc1)+relu FUSED with tap-GEMM (headt) ============
// Same conv3m body (RELU path), but instead of writing the 64-ch volume,
// relu'd acc goes through a per-wave swizzled LDS tile (k_chain pattern,
// reusing sA) and a second MFMA against wt2 -> t[tap][pv] bf16 directly.
__global__ __launch_bounds__(256,2) void k_conv3h(
    const unsigned short* __restrict__ in, const unsigned short* __restrict__ wt,
    const unsigned short* __restrict__ wt2, unsigned short* __restrict__ t)
{
    __shared__ __align__(16) char sA[36864];
    __shared__ __align__(16) char sB[33280];

    const int tid  = threadIdx.x;
    const int lane = tid & 63;
    const int wave = tid >> 6;
    const int ll = lane & 15;
    const int kg = lane >> 4;
    const int bid = blockIdx.x;
    const int wid = ((bid & 7) * 192) + (bid >> 3);
    const int vbr = wid*256;
    const int d  = vbr >> 13;
    const int h0 = (vbr >> 7) & 63;
    const int my_h  = h0 + (wave >> 1);
    const int my_w0 = (wave & 1) * 64;
    const long pvb = (long)(d*64 + my_h)*PW + my_w0 + 1;

    const char* inb = (const char*)in;
    const char* wtb = (const char*)wt;

    f32x4 acc[4][4];
#pragma unroll
    for (int a=0;a<4;++a)
#pragma unroll
        for (int b=0;b<4;++b) acc[a][b] = (f32x4){0.f,0.f,0.f,0.f};

#pragma unroll
    for (int kd=0; kd<3; ++kd){
        const int dd = d + kd - 1;
        if ((unsigned)dd >= 48u) continue;
        const long rowstart = ((long)(dd*64 + h0 - 1)) * 130;
#pragma unroll
        for (int khalf=0; khalf<2; ++khalf){
            __syncthreads();
#pragma unroll
            for (int rnd=0; rnd<9; ++rnd){
                int j = rnd*4096 + tid*16;
                int q = j ^ (((j>>7)&3)<<4);
                const char* src = wtb + (long)(kd*9 + (q>>12))*8192
                                      + (long)((q>>6)&63)*128 + khalf*64 + (q&63);
                gload16(src, sA + j);
            }
#pragma unroll
            for (int rnd=0; rnd<8; ++rnd){
                int j = rnd*4096 + tid*16;
                int q = j ^ (((j>>7)&3)<<4);
                const char* src = inb + (rowstart + (q>>6))*128 + khalf*64 + (q&63);
                gload16(src, sB + j);
            }
            if (tid < 32){
                int j = 32768 + tid*16;
                int q = j ^ (((j>>7)&3)<<4);
                const char* src = inb + (rowstart + (q>>6))*128 + khalf*64 + (q&63);
                gload16(src, sB + j);
            }
            __syncthreads();
#pragma unroll
            for (int kh=0; kh<3; ++kh){
                const int hh = my_h + kh - 1;
                if ((unsigned)hh >= 64u) continue;
                const int rr = (wave>>1) + kh;
#pragma unroll
                for (int kw=0; kw<3; ++kw){
                    const int tap_rel = kh*3 + kw;
                    bf16x8 Af[4], Bf[4];
#pragma unroll
                    for (int tt=0;tt<4;++tt){
                        int qa = tap_rel*4096 + (tt*16+ll)*64 + kg*16;
                        Af[tt] = *(const bf16x8*)(sA + (qa ^ (((qa>>7)&3)<<4)));
                    }
#pragma unroll
                    for (int vt=0; vt<4; ++vt){
                        int vrel = rr*130 + my_w0 + vt*16 + ll + kw;
                        int qb = vrel*64 + kg*16;
                        Bf[vt] = *(const bf16x8*)(sB + (qb ^ (((qb>>7)&3)<<4)));
                    }
#pragma unroll
                    for (int vt=0; vt<4; ++vt)
#pragma unroll
                        for (int tt=0; tt<4; ++tt)
                            acc[tt][vt] = __builtin_amdgcn_mfma_f32_16x16x32_bf16(Af[tt], Bf[vt], acc[tt][vt], 0,0,0);
                }
            }
        }
    }

    // --- fused tap-GEMM epilogue ---
    __syncthreads();                       // all waves done reading sA
    char* myL = sA + wave*8192;            // per-wave 8KB tile (k_chain pattern)
#pragma unroll
    for (int vt=0; vt<4; ++vt){
        const int row = vt*16 + ll;
        const int sw = (row & 7) << 4;
#pragma unroll
        for (int tt=0;tt<4;++tt){
            float r0 = fmaxf(acc[tt][vt][0],0.f), r1 = fmaxf(acc[tt][vt][1],0.f);
            float r2 = fmaxf(acc[tt][vt][2],0.f), r3 = fmaxf(acc[tt][vt][3],0.f);
            unsigned int lo = (unsigned)f2bf(r0) | ((unsigned)f2bf(r1)<<16);
            unsigned int hi = (unsigned)f2bf(r2) | ((unsigned)f2bf(r3)<<16);
            u32x2v q = {lo, hi};
            int colb = kg*8 + tt*32;
            *(u32x2v*)(myL + row*128 + (colb ^ sw)) = q;
        }
    }
    f32x4 acc2[2][4];
#pragma unroll
    for (int a=0;a<2;++a)
#pragma unroll
        for (int b=0;b<4;++b) acc2[a][b] = (f32x4){0.f,0.f,0.f,0.f};
#pragma unroll
    for (int half=0; half<2; ++half){
        const int ko = half*32 + kg*8;
        bf16x8 afr[2];
#pragma unroll
        for (int tl=0;tl<2;++tl)
            afr[tl] = *(const bf16x8*)(wt2 + (tl*16+ll)*64 + ko);
#pragma unroll
        for (int vt=0; vt<4; ++vt){
            const int row = vt*16 + ll;
            const int sw = (row & 7) << 4;
            int colb = half*64 + kg*16;
            bf16x8 bfr = *(const bf16x8*)(myL + row*128 + (colb ^ sw));
#pragma unroll
            for (int tl=0;tl<2;++tl)
                acc2[tl][vt] = __builtin_amdgcn_mfma_f32_16x16x32_bf16(afr[tl], bfr, acc2[tl][vt], 0,0,0);
        }
    }
#pragma unroll
    for (int vt=0; vt<4; ++vt){
        long vx = pvb + vt*16 + ll;
#pragma unroll
        for (int tl=0;tl<2;++tl){
#pragma unroll
            for (int r=0;r<4;++r){
                int tap = tl*16 + kg*4 + r;
                if (tap < 27) t[(long)tap*PVOL + vx] = f2bf(acc2[tl][vt][r]);
            }
        }
    }
}

// ============ FUSED residual chain (R9, unchanged) ============
__global__ __launch_bounds__(256,3) void k_chain(const unsigned short* __restrict__ in,
        const unsigned short* __restrict__ Mt, unsigned short* __restrict__ out){
    __shared__ __align__(16) char sX[4][8192];
    const int lane = threadIdx.x & 63;
    const int wave = threadIdx.x >> 6;
    const int ll = lane & 15;
    const int kg = lane >> 4;
    const long vb = (long)blockIdx.x*256 + wave*64;
    char* myL = sX[wave];

    bf16x8 B[2][4];
#pragma unroll
    for (int half=0; half<2; ++half){
        const int ko = half*32 + kg*8;
#pragma unroll
        for (int vt=0; vt<4; ++vt)
            B[half][vt] = *(const bf16x8*)(in + (vb+vt*16+ll)*64 + ko);
    }

#pragma unroll
    for (int s=0; s<5; ++s){
        const unsigned short* wt = Mt + s*4096;
        bf16x8 A[2][4];
#pragma unroll
        for (int half=0; half<2; ++half){
            const int ko = half*32 + kg*8;
#pragma unroll
            for (int t=0;t<4;++t)
                A[half][t] = *(const bf16x8*)(wt + (t*16+ll)*64 + ko);
        }
        f32x4 acc[4][4];
#pragma unroll
        for (int a=0;a<4;++a)
#pragma unroll
            for (int b=0;b<4;++b) acc[a][b] = (f32x4){0.f,0.f,0.f,0.f};
#pragma unroll
        for (int half=0; half<2; ++half)
#pragma unroll
            for (int vt=0; vt<4; ++vt)
#pragma unroll
                for (int t=0;t<4;++t)
                    acc[t][vt] = __builtin_amdgcn_mfma_f32_16x16x32_bf16(A[half][t], B[half][vt], acc[t][vt], 0,0,0);

        if (s < 4){
#pragma unroll
            for (int vt=0; vt<4; ++vt){
                const int row = vt*16 + ll;
                const int sw = (row & 7) << 4;
#pragma unroll
                for (int t=0;t<4;++t){
                    float r0 = fmaxf(acc[t][vt][0],0.f), r1 = fmaxf(acc[t][vt][1],0.f);
                    float r2 = fmaxf(acc[t][vt][2],0.f), r3 = fmaxf(acc[t][vt][3],0.f);
                    unsigned int lo = (unsigned)f2bf(r0) | ((unsigned)f2bf(r1)<<16);
                    unsigned int hi = (unsigned)f2bf(r2) | ((unsigned)f2bf(r3)<<16);
                    u32x2v q = {lo, hi};
                    int colb = kg*8 + t*32;
                    *(u32x2v*)(myL + row*128 + (colb ^ sw)) = q;
                }
            }
#pragma unroll
            for (int half=0; half<2; ++half){
#pragma unroll
                for (int vt=0; vt<4; ++vt){
                    const int row = vt*16 + ll;
                    const int sw = (row & 7) << 4;
                    int colb = half*64 + kg*16;
                    B[half][vt] = *(const bf16x8*)(myL + row*128 + (colb ^ sw));
                }
            }
        } else {
#pragma unroll
            for (int vt=0; vt<4; ++vt){
                unsigned short* op = out + (vb+vt*16+ll)*64 + kg*4;
#pragma unroll
                for (int t=0;t<4;++t){
                    float r0 = fmaxf(acc[t][vt][0],0.f), r1 = fmaxf(acc[t][vt][1],0.f);
                    float r2 = fmaxf(acc[t][vt][2],0.f), r3 = fmaxf(acc[t][vt][3],0.f);
                    unsigned int lo = (unsigned)f2bf(r0) | ((unsigned)f2bf(r1)<<16);
                    unsigned int hi = (unsigned)f2bf(r2) | ((unsigned)f2bf(r3)<<16);
                    u32x2v q = {lo, hi};
                    *(u32x2v*)(op + t*16) = q;
                }
            }
        }
    }
}

// ============ head stage 2: out[v] = bias + sum_tap bf2f(t[tap][p+dv]) ============
// w-bound check restored (t's pad columns are not written by k_conv3h)
__global__ __launch_bounds__(256) void k_heads(const unsigned short* __restrict__ t,
        const float* __restrict__ bias, float* __restrict__ out){
    int v = blockIdx.x*256 + threadIdx.x;
    int ww = v & 127; int h = (v>>7)&63; int d = v>>13;
    long p = (long)(d*64+h)*PW + ww + 1;
    float s = bias[0];
#pragma unroll
    for (int kd=0;kd<3;++kd){
#pragma unroll
      for (int kh=0;kh<3;++kh){
#pragma unroll
        for (int kw=0;kw<3;++kw){
            const int tap = (kd*3+kh)*3+kw;
            const long dvp = (long)((kd-1)*64 + (kh-1))*PW + (kw-1);
            bool ok = ((unsigned)(d+kd-1)<48u) && ((unsigned)(h+kh-1)<64u)
                   && ((unsigned)(ww+kw-1)<128u);
            long va = ok ? (p + dvp) : p;
            float x = bf2f(t[(long)tap*PVOL + va]);
            s += ok ? x : 0.f;
        }
      }
    }
    out[v] = s;
}

// ============ pool stage 1: S3 cell sums (unchanged) ============
__global__ __launch_bounds__(256) void k_pool3(const unsigned short* __restrict__ in,
                                               float* __restrict__ S3){
    __shared__ float sm[32*68];
    int tid = threadIdx.x;
    int cg = tid & 7, part = tid >> 3;
    int cell = blockIdx.x;
    int Z = cell >> 8, Y = (cell >> 4) & 15, X = cell & 15;
    float a[8];
#pragma unroll
    for (int j=0;j<8;++j) a[j]=0.f;
#pragma unroll
    for (int j=0;j<3;++j){
        int i = part*3 + j;
        int di = i >> 5, rem = i & 31, hi = rem >> 3, wi = rem & 7;
        long p = ((long)((3*Z+di)*64 + 4*Y+hi))*PW + 8*X+wi + 1;
        u32x4v q = *(const u32x4v*)(in + p*64 + cg*8);
#pragma unroll
        for (int e=0;e<4;++e){ a[e*2] += bflo(q[e]); a[e*2+1] += bfhi(q[e]); }
    }
#pragma unroll
    for (int j=0;j<8;++j) sm[part*68 + cg*8 + j] = a[j];
    __syncthreads();
    if (tid < 64){
        float s=0.f;
        for (int r=0;r<32;++r) s += sm[r*68 + tid];
        S3[tid*4096 + cell] = s;
    }
}

// ============ p2 sums from S3 (unchanged) ============
__global__ __launch_bounds__(256) void k_pool2(const float* __restrict__ S3,
                                               float* __restrict__ P2){
    int idx = blockIdx.x*256 + threadIdx.x;
    int cell = idx & 511; int c = idx >> 9;
    int z = cell >> 6, y = (cell >> 3) & 7, x = cell & 7;
    const float* b = S3 + c*4096;
    float s = 0.f;
#pragma unroll
    for (int a2=0;a2<2;++a2)
#pragma unroll
        for (int b2=0;b2<2;++b2)
#pragma unroll
            for (int e=0;e<2;++e)
                s += b[((2*z+a2)<<8) + ((2*y+b2)<<4) + (2*x+e)];
    P2[c*512 + cell] = s;
}

// ============ g + gc from S3 (unchanged) ============
__global__ void k_gcm(const float* __restrict__ S3, const float* __restrict__ wp0,
                      float* __restrict__ gc){
    __shared__ float sm[4][64];
    __shared__ float sg[64];
    int tid = threadIdx.x;
    int c = tid & 63, part = tid >> 6;
    float s = 0.f;
    const float* row = S3 + c*4096 + part*1024;
    for (int i=0;i<1024;i+=4){
        f32x4 q = *(const f32x4*)(row + i);
        s += q[0]+q[1]+q[2]+q[3];
    }
    sm[part][c] = s;
    __syncthreads();
    if (tid < 64){
        sg[tid] = (sm[0][tid]+sm[1][tid]+sm[2][tid]+sm[3][tid]) * (1.0f/(float)VOL);
    }
    __syncthreads();
    if (tid < 64){
        float g=0.f;
        for (int ci=0;ci<64;++ci) g += wp0[tid*64+ci]*sg[ci];
        gc[tid] = g;
    }
}

// ============ p4 sums (unchanged) ============
__global__ __launch_bounds__(256) void k_pool4(const unsigned short* __restrict__ in,
                                               float* __restrict__ P4){
    __shared__ float sm[32*68];
    int tid = threadIdx.x;
    int cg = tid & 7, part = (tid >> 3) & 3, slot = tid >> 5;
    int cell = blockIdx.x*8 + slot;
    int z = cell / 800; int rem = cell - z*800; int y = rem / 25; int x = rem - y*25;
    int a2 = part >> 1, b2 = part & 1;
    float a[8];
#pragma unroll
    for (int j=0;j<8;++j) a[j]=0.f;
#pragma unroll
    for (int e=0;e<5;++e){
        long p = ((long)((2*z+a2)*64 + 2*y+b2))*PW + 5*x+e + 1;
        u32x4v q = *(const u32x4v*)(in + p*64 + cg*8);
#pragma unroll
        for (int k=0;k<4;++k){ a[k*2] += bflo(q[k]); a[k*2+1] += bfhi(q[k]); }
    }
#pragma unroll
    for (int j=0;j<8;++j) sm[(slot*4+part)*68 + cg*8 + j] = a[j];
    __syncthreads();
#pragma unroll
    for (int r=0;r<2;++r){
        int o = r*256 + tid;
        int c = o >> 3, s = o & 7;
        float v = sm[(s*4+0)*68 + c] + sm[(s*4+1)*68 + c]
                + sm[(s*4+2)*68 + c] + sm[(s*4+3)*68 + c];
        P4[(long)c*19200 + blockIdx.x*8 + s] = v;
    }
}

// ============ 1x1 conv fp32 on pooled SUMS (unchanged) ============
__global__ void k_conv1(const float* __restrict__ in, const float* __restrict__ wt,
                        float* __restrict__ out, int vol, float scale){
    int v = blockIdx.x*256 + threadIdx.x;
    if (v >= vol) return;
    float acc[64];
#pragma unroll
    for (int i=0;i<64;++i) acc[i]=0.f;
    for (int ci=0; ci<64; ++ci){
        float xv = in[ci*vol + v];
        const float* wr = wt + ci*64;
#pragma unroll
        for (int co=0; co<64; ++co) acc[co] = fmaf(wr[co], xv, acc[co]);
    }
    float* op = out + (long)v*64;
#pragma unroll
    for (int q=0;q<16;++q){
        f32x4 t = {acc[q*4]*scale, acc[q*4+1]*scale, acc[q*4+2]*scale, acc[q*4+3]*scale};
        *(f32x4*)(op + q*4) = t;
    }
}

// ============ trilinear gather ============
__device__ __forceinline__ void tri_setup(int d,int h,int w,int gd,int gh,int gw,
                                          int* o, float* wt){
    float fz = (d+0.5f)*((float)gd/(float)DD) - 0.5f;
    float fy = (h+0.5f)*((float)gh/(float)HH) - 0.5f;
    float fx = (w+0.5f)*((float)gw/(float)WW) - 0.5f;
    float z0f = floorf(fz), y0f = floorf(fy), x0f = floorf(fx);
    float tz = fz - z0f, ty = fy - y0f, tx = fx - x0f;
    int z0 = (int)z0f, y0 = (int)y0f, x0 = (int)x0f;
    int z1 = z0+1, y1 = y0+1, x1 = x0+1;
    z0 = min(max(z0,0),gd-1); z1 = min(max(z1,0),gd-1);
    y0 = min(max(y0,0),gh-1); y1 = min(max(y1,0),gh-1);
    x0 = min(max(x0,0),gw-1); x1 = min(max(x1,0),gw-1);
    o[0] = (z0*gh+y0)*gw+x0; wt[0] = (1-tz)*(1-ty)*(1-tx);
    o[1] = (z0*gh+y0)*gw+x1; wt[1] = (1-tz)*(1-ty)*tx;
    o[2] = (z0*gh+y1)*gw+x0; wt[2] = (1-tz)*ty*(1-tx);
    o[3] = (z0*gh+y1)*gw+x1; wt[3] = (1-tz)*ty*tx;
    o[4] = (z1*gh+y0)*gw+x0; wt[4] = tz*(1-ty)*(1-tx);
    o[5] = (z1*gh+y0)*gw+x1; wt[5] = tz*(1-ty)*tx;
    o[6] = (z1*gh+y1)*gw+x0; wt[6] = tz*ty*(1-tx);
    o[7] = (z1*gh+y1)*gw+x1; wt[7] = tz*ty*tx;
}

// out = relu((xc + 0.25*(gc + up(p2)+up(p3)+up(p4)))/2)
// R10 proven shape: 256-thread full-voxel blocks, XCD swizzle, nt fp32 stores
__global__ __launch_bounds__(256) void k_combine(
        const unsigned short* __restrict__ xc, const float* __restrict__ gc,
        const float* __restrict__ p2, const float* __restrict__ p3,
        const float* __restrict__ p4, float* __restrict__ xout,
        unsigned short* __restrict__ xv){
    int tid = threadIdx.x;
    const int bid = blockIdx.x;
    const int wid = ((bid & 7) * 192) + (bid >> 3);   // 1536 blocks, bijective
    long v = (long)wid*256 + tid;
    int w = v & 127; int h = (v>>7)&63; int d = v>>13;
    long p = (long)(d*64+h)*PW + w + 1;
    int o2[8], o3[8], o4[8];
    float w2_[8], w3_[8], w4_[8];
    tri_setup(d,h,w, 8,8,8,    o2, w2_);
    tri_setup(d,h,w, 16,16,16, o3, w3_);
    tri_setup(d,h,w, 24,32,25, o4, w4_);
#pragma unroll
    for (int half=0; half<2; ++half){
        float res[32];
#pragma unroll
        for (int j=0;j<32;++j) res[j] = gc[half*32+j];
#pragma unroll
        for (int t=0;t<8;++t){
            const float* b2 = p2 + (long)o2[t]*64 + half*32;
#pragma unroll
            for (int q=0;q<8;++q){
                f32x4 x4 = *(const f32x4*)(b2 + q*4);
                res[q*4+0] = fmaf(w2_[t], x4[0], res[q*4+0]);
                res[q*4+1] = fmaf(w2_[t], x4[1], res[q*4+1]);
                res[q*4+2] = fmaf(w2_[t], x4[2], res[q*4+2]);
                res[q*4+3] = fmaf(w2_[t], x4[3], res[q*4+3]);
            }
        }
#pragma unroll
        for (int t=0;t<8;++t){
            const float* b3 = p3 + (long)o3[t]*64 + half*32;
#pragma unroll
            for (int q=0;q<8;++q){
                f32x4 x4 = *(const f32x4*)(b3 + q*4);
                res[q*4+0] = fmaf(w3_[t], x4[0], res[q*4+0]);
                res[q*4+1] = fmaf(w3_[t], x4[1], res[q*4+1]);
                res[q*4+2] = fmaf(w3_[t], x4[2], res[q*4+2]);
                res[q*4+3] = fmaf(w3_[t], x4[3], res[q*4+3]);
            }
        }
#pragma unroll
        for (int t=0;t<8;++t){
            const float* b4 = p4 + (long)o4[t]*64 + half*32;
#pragma unroll
            for (int q=0;q<8;++q){
                f32x4 x4 = *(const f32x4*)(b4 + q*4);
                res[q*4+0] = fmaf(w4_[t], x4[0], res[q*4+0]);
                res[q*4+1] = fmaf(w4_[t], x4[1], res[q*4+1]);
                res[q*4+2] = fmaf(w4_[t], x4[2], res[q*4+2]);
                res[q*4+3] = fmaf(w4_[t], x4[3], res[q*4+3]);
            }
        }
        const u32x4v* xq = (const u32x4v*)(xc + p*64 + half*32);
#pragma unroll
        for (int q=0;q<4;++q){
            u32x4v qv = xq[q];
            unsigned int pk[4];
#pragma unroll
            for (int e=0;e<4;++e){
                int j = q*8 + e*2;
                float r0 = fmaxf((bflo(qv[e]) + 0.25f*res[j])*0.5f, 0.f);
                float r1 = fmaxf((bfhi(qv[e]) + 0.25f*res[j+1])*0.5f, 0.f);
                __builtin_nontemporal_store(r0, &xout[(long)(half*32+j)*VOL + v]);
                __builtin_nontemporal_store(r1, &xout[(long)(half*32+j+1)*VOL + v]);
                pk[e] = (unsigned)f2bf(r0) | ((unsigned)f2bf(r1)<<16);
            }
            u32x4v pq = {pk[0],pk[1],pk[2],pk[3]};
            *(u32x4v*)(xv + p*64 + half*32 + q*8) = pq;
        }
    }
}

// ================= workspace layout (bytes) =================
constexpr long RPV = GUARD + PVBYTES + GUARD;
constexpr long OFF_PV0R = 0;
constexpr long OFF_PV1R = RPV;
constexpr long OFF_WA1 = 2*RPV;
constexpr long OFF_WA2 = OFF_WA1 + 221184;
constexpr long OFF_WC1 = OFF_WA2 + 221184;
constexpr long OFF_NIN = OFF_WC1 + 221184;
constexpr long OFF_MT  = OFF_NIN + 8192;
constexpr long OFF_WT2 = OFF_MT + 40960;
constexpr long OFF_WPT = OFF_WT2 + 4096;
constexpr long OFF_GC  = OFF_WPT + 49152;
constexpr long OFF_P2  = OFF_GC + 256;
constexpr long OFF_P2C = OFF_P2 + 131072;
constexpr long OFF_S3  = OFF_P2C + 131072;
constexpr long OFF_P3C = OFF_S3 + 1048576;
constexpr long OFF_P4  = OFF_P3C + 1048576;
constexpr long OFF_P4C = OFF_P4 + 4915200;
// end ~= 115.4 MB

extern "C" void kernel_launch(void* const* d_in, const int* in_sizes, int n_in,
                              void* d_out, int out_size, void* d_ws, size_t ws_size,
                              hipStream_t stream) {
    const float* fvl  = (const float*)d_in[0];
    const float* w_a1 = (const float*)d_in[1];
    const float* w_a2 = (const float*)d_in[2];
    const float* wnin = (const float*)d_in[3];
    const float* w1s  = (const float*)d_in[4];
    const float* w2s  = (const float*)d_in[5];
    const float* wp0  = (const float*)d_in[6];
    const float* wp1  = (const float*)d_in[7];
    const float* wp2  = (const float*)d_in[8];
    const float* wp3  = (const float*)d_in[9];
    const float* wc1  = (const float*)d_in[10];
    const float* wc2  = (const float*)d_in[11];
    const float* bc   = (const float*)d_in[12];

    char* ws = (char*)d_ws;
    unsigned short* PV0  = (unsigned short*)(ws + OFF_PV0R + GUARD);
    unsigned short* PV1  = (unsigned short*)(ws + OFF_PV1R + GUARD);
    unsigned short* wa1t = (unsigned short*)(ws + OFF_WA1);
    unsigned short* wa2t = (unsigned short*)(ws + OFF_WA2);
    unsigned short* wc1t = (unsigned short*)(ws + OFF_WC1);
    unsigned short* nint = (unsigned short*)(ws + OFF_NIN);
    unsigned short* Mt   = (unsigned short*)(ws + OFF_MT);
    unsigned short* wt2  = (unsigned short*)(ws + OFF_WT2);
    float* wpt  = (float*)(ws + OFF_WPT);
    float* gc   = (float*)(ws + OFF_GC);
    float* p2   = (float*)(ws + OFF_P2);
    float* p2c  = (float*)(ws + OFF_P2C);
    float* S3   = (float*)(ws + OFF_S3);
    float* p3c  = (float*)(ws + OFF_P3C);
    float* p4   = (float*)(ws + OFF_P4);
    float* p4c  = (float*)(ws + OFF_P4C);

    float* Xout = (float*)d_out;
    float* Cout = Xout + (long)NC*VOL;
    unsigned short* Tbuf = PV1;     // head t bf16 [27][PVOL] = 21.5MB, reuses PV1 (free after combine)

    const int GBR = VOL/256;     // 1536
    const int GBP = PVOL/256;    // 1560

    // zero only the pad columns (1.5MB instead of 102MB of memset)
    k_zeropad<<<384,256,0,stream>>>(PV0, PV1);

    // all weight prep in ONE launch
    k_prep_all<<<1448,256,0,stream>>>(w_a1, w_a2, wc1, wnin, wc2, w1s, w2s,
                                      wp1, wp2, wp3,
                                      wa1t, wa2t, wc1t, nint, wt2, Mt, wpt);
    k_tobf16v<<<VOL/64,256,0,stream>>>(fvl, PV0);

    // stage A/B: conv3 chain
    k_conv3m<false,false><<<GBR,256,0,stream>>>(PV0, wa1t, nullptr, nullptr, PV1);
    k_conv3m<true,false><<<GBR,256,0,stream>>>(PV1, wa2t, PV0, nint, PV0);

    // stage C: fused 5-stage residual chain PV0 -> PV1 (one kernel)
    k_chain<<<GBP,256,0,stream>>>(PV0, Mt, PV1);

    // stage D: pool pyramid
    k_pool3<<<4096,256,0,stream>>>(PV1, S3);
    k_gcm<<<1,256,0,stream>>>(S3, wp0, gc);
    k_pool2<<<128,256,0,stream>>>(S3, p2);
    k_pool4<<<2400,256,0,stream>>>(PV1, p4);
    k_conv1<<<2,256,0,stream>>>(p2, wpt + 0*4096, p2c, 512,   1.0f/768.0f);
    k_conv1<<<16,256,0,stream>>>(S3, wpt + 1*4096, p3c, 4096, 1.0f/96.0f);
    k_conv1<<<75,256,0,stream>>>(p4, wpt + 2*4096, p4c, 19200, 1.0f/20.0f);

    // combine: Xout + padded bf16 x into PV0
    k_combine<<<GBR,256,0,stream>>>(PV1, gc, p2c, p3c, p4c, Xout, PV0);

    // head: conv3(x,wc1)+relu fused with tap-GEMM -> Tbuf (PV1); then gather-sum
    k_conv3h<<<GBR,256,0,stream>>>(PV0, wc1t, wt2, Tbuf);
    k_heads<<<GBR,256,0,stream>>>(Tbuf, bc, Cout);
}